// Round 5
// baseline (906.998 us; speedup 1.0000x reference)
//
#include <hip/hip_runtime.h>
#include <hip/hip_fp16.h>
#include <cmath>

// ---------------- problem constants ----------------
constexpr int IMH = 320, IMW = 320, NPIX = IMH * IMW, NC = 21;
constexpr int CP4 = 6;           // padded channels / 4  (24 values per row)
constexpr int DB = 5, DB1 = 6;   // bilateral lattice dim
constexpr int DS = 2, DS1 = 3;   // spatial lattice dim
constexpr int RB = NPIX * DB1;   // splat entries (bilateral) = 614400
constexpr int RS = NPIX * DS1;   // (spatial) = 307200
constexpr int TBS = 1 << 19;     // hash table slots (bilateral only)
constexpr int NBUCK = 1 << 16;   // bilateral sort buckets (c0,c1 low bytes)
constexpr int NW1 = (RB + RS) / 64;  // wave sums in the unified offset scan
// spatial dense grid: lattice coords are deterministic in (x,y) only.
// c0 in [-8, 298], c1 in [-194, 115]  ->  512x512 grid with offsets below.
constexpr int GS = 512, GN = GS * GS;
constexpr int C0OFF = 16, C1OFF = 200;

// Combined lattice-value buffer layout (static partition):
//   bilateral: row 0 = sink, point m -> row m+1           (rows [0, RB])
//   spatial:   row RB+1 = sink, point m -> row RB+2+m     (rows [RB+1, ...])
// spatial neighbor n=-1 maps to RB+2+(-1) = RB+1 = sink automatically.

// LESSONS (measured):
// r12-r14: hist fused into CAS loop = +45us; test-before-CAS = +8us/+36MB
//   FETCH; 4B epw packing does NOT cut scatter WRITE (64B sectors rule).
// r15: fill's atomicAdd removed via ranks captured in os_count.
// r16: ATOMIC-THROUGHPUT-BOUND build: WRITE_SIZE = count x 64B sectors,
//   ~16-19G atomics/s ceiling. Only fewer atomics help.
// r17: spatial lattice -> dense 512x512 grid (no atomics).
// r18: wave-agg os_count OK; blur row-per-thread REGRESSED: <200K threads
//   is latency-starved. TLP rule: >=400K threads for scattered kernels.
// r19: merged 16B {key,id} table (1 load/probe), 6x parallel neighbor
//   build, blur 3-chunk: 921->861us. fillBufferAligned rows = 256MiB
//   harness poison => ws_size = 256MiB (not ours, not in dur_us).
// r20 (this round): iteration phase (~75%): (a) gather 3-chunk/row
//   (187K->560K threads, r18 TLP rule); (b) blur pair-fusion (j=0,1) and
//   (j=3,4) via composed neighbor indices -> 9-pt stencil, 6->4 blur
//   dispatches/iter, one less fp16 rounding per pair.

#define EMPTY_KEY 0xFFFFFFFFFFFFFFFFULL

__device__ __forceinline__ unsigned long long mix64(unsigned long long x) {
    x ^= x >> 33; x *= 0xff51afd7ed558ccdULL;
    x ^= x >> 33; x *= 0xc4ceb9fe1a85ec53ULL;
    x ^= x >> 33; return x;
}

// fp16 pack helpers: uint2 = 4 halves; math in fp32, storage fp16.
__device__ __forceinline__ float4 u2f(uint2 u) {
    __half2 a = *reinterpret_cast<__half2*>(&u.x);
    __half2 b = *reinterpret_cast<__half2*>(&u.y);
    float2 fa = __half22float2(a), fb = __half22float2(b);
    return make_float4(fa.x, fa.y, fb.x, fb.y);
}
__device__ __forceinline__ uint2 f2u(float4 v) {
    __half2 a = __floats2half2_rn(v.x, v.y);
    __half2 b = __floats2half2_rn(v.z, v.w);
    uint2 u;
    u.x = *reinterpret_cast<unsigned*>(&a);
    u.y = *reinterpret_cast<unsigned*>(&b);
    return u;
}

__device__ __forceinline__ unsigned pack_ew(int pix, float w) {
    int w15 = (int)lrintf(fminf(fmaxf(w, 0.f), 1.f) * 32767.f);
    return ((unsigned)w15 << 17) | (unsigned)pix;
}
__device__ __forceinline__ void unpack_ew(unsigned e, int& pix, float& w) {
    pix = (int)(e & 0x1FFFFu);
    w = (float)(e >> 17) * (1.0f / 32767.0f);
}

// accumulate 8 fp16 channels (one uint4) into acc[0..7] with weight w.
__device__ __forceinline__ void acc8(float* acc, float w, uint4 q) {
    float4 v = u2f(make_uint2(q.x, q.y));
    acc[0] += w * v.x; acc[1] += w * v.y; acc[2] += w * v.z; acc[3] += w * v.w;
    v = u2f(make_uint2(q.z, q.w));
    acc[4] += w * v.x; acc[5] += w * v.y; acc[6] += w * v.z; acc[7] += w * v.w;
}

// blur core on one uint4 (8 fp16 channels): x + 0.5*(a+b), f32 math.
__device__ __forceinline__ uint4 blur8(uint4 xs, uint4 xa, uint4 xb) {
    float4 s0 = u2f(make_uint2(xs.x, xs.y)), s1 = u2f(make_uint2(xs.z, xs.w));
    float4 a0 = u2f(make_uint2(xa.x, xa.y)), a1 = u2f(make_uint2(xa.z, xa.w));
    float4 b0 = u2f(make_uint2(xb.x, xb.y)), b1 = u2f(make_uint2(xb.z, xb.w));
    s0.x += 0.5f * (a0.x + b0.x); s0.y += 0.5f * (a0.y + b0.y);
    s0.z += 0.5f * (a0.z + b0.z); s0.w += 0.5f * (a0.w + b0.w);
    s1.x += 0.5f * (a1.x + b1.x); s1.y += 0.5f * (a1.y + b1.y);
    s1.z += 0.5f * (a1.z + b1.z); s1.w += 0.5f * (a1.w + b1.w);
    uint2 lo = f2u(s0), hi = f2u(s1);
    return make_uint4(lo.x, lo.y, hi.x, hi.y);
}

__device__ __forceinline__ uint4 pack8(const float* acc) {
    uint2 lo = f2u(make_float4(acc[0], acc[1], acc[2], acc[3]));
    uint2 hi = f2u(make_float4(acc[4], acc[5], acc[6], acc[7]));
    return make_uint4(lo.x, lo.y, hi.x, hi.y);
}

// ---------------- permutohedral embedding (matches reference op-for-op, f32) ----------------
template<int D>
__device__ void perm_embed(const float* f, float* bary, unsigned long long* pk) {
    constexpr int D1 = D + 1;
    float cf[D];
    #pragma unroll
    for (int i = 0; i < D; i++) {
        double s = sqrt(2.0 / 3.0) * (double)D1 / sqrt((double)((i + 1) * (i + 2)));
        cf[i] = f[i] * (float)s;
    }
    float csum[D];
    float acc = 0.f;
    #pragma unroll
    for (int i = D - 1; i >= 0; i--) { acc += cf[i]; csum[i] = acc; }
    float el[D1];
    el[0] = csum[0];
    #pragma unroll
    for (int i = 1; i < D; i++) el[i] = csum[i] - (float)i * cf[i - 1];
    el[D] = -(float)D * cf[D - 1];
    const float down = 1.0f / (float)D1;
    float rem0[D1]; int rank[D1]; int ssum = 0;
    #pragma unroll
    for (int i = 0; i < D1; i++) {
        float rd = rintf(el[i] * down);
        rem0[i] = rd * (float)D1;
        ssum += (int)rd;
    }
    float diff[D1];
    #pragma unroll
    for (int i = 0; i < D1; i++) diff[i] = el[i] - rem0[i];
    #pragma unroll
    for (int i = 0; i < D1; i++) {
        int r = 0;
        #pragma unroll
        for (int j = 0; j < D1; j++)
            r += (diff[j] > diff[i]) || ((diff[j] == diff[i]) && (j < i));
        rank[i] = r + ssum;
    }
    #pragma unroll
    for (int i = 0; i < D1; i++) {
        if (rank[i] < 0)      { rank[i] += D1; rem0[i] += (float)D1; }
        else if (rank[i] > D) { rank[i] -= D1; rem0[i] -= (float)D1; }
    }
    float b[D + 2];
    #pragma unroll
    for (int i = 0; i < D + 2; i++) b[i] = 0.f;
    #pragma unroll
    for (int i = 0; i < D1; i++) b[D - rank[i]]     += (el[i] - rem0[i]) * down;
    #pragma unroll
    for (int i = 0; i < D1; i++) b[D + 1 - rank[i]] -= (el[i] - rem0[i]) * down;
    b[0] += 1.0f + b[D + 1];
    #pragma unroll
    for (int i = 0; i < D1; i++) bary[i] = b[i];
    int key0[D];
    #pragma unroll
    for (int i = 0; i < D; i++) key0[i] = (int)rintf(rem0[i]);
    #pragma unroll
    for (int r = 0; r < D1; r++) {
        unsigned long long p = 0;
        #pragma unroll
        for (int i = 0; i < D; i++) {
            int c = key0[i] + ((rank[i] < D1 - r) ? r : r - D1);
            p |= ((unsigned long long)((unsigned)(c + 2048) & 0xFFFu)) << (12 * i);
        }
        pk[r] = p;
    }
}

__device__ __forceinline__ int key_code(unsigned long long k) {
    int c0 = (int)(k & 0xFFFULL);
    int c1 = (int)((k >> 12) & 0xFFFULL);
    return ((c0 & 0xFF) << 8) | (c1 & 0xFF);
}

// ---------------- merged {key,id} hash table (16B entries) ----------------
__device__ __forceinline__ int hash_insert2(ulonglong2* hkid, int tmask, unsigned long long k) {
    int slot = (int)(mix64(k) & (unsigned long long)tmask);
    while (true) {
        unsigned long long prev = atomicCAS(&hkid[slot].x, EMPTY_KEY, k);
        if (prev == EMPTY_KEY || prev == k) return slot;
        slot = (slot + 1) & tmask;
    }
}
// one 16B load per probe: key match delivers id in the same transaction.
__device__ __forceinline__ int hash_lookup2(const ulonglong2* __restrict__ hkid,
                                            int tmask, unsigned long long k) {
    int slot = (int)(mix64(k) & (unsigned long long)tmask);
    while (true) {
        ulonglong2 e = hkid[slot];
        if (e.x == k) return (int)e.y;
        if (e.x == EMPTY_KEY) return -1;
        slot = (slot + 1) & tmask;
    }
}

// ---------------- build kernels ----------------
__global__ void build_both(const float* __restrict__ image, ulonglong2* hkid,
                           int* os, float* wsv, int* pres) {
    int idx = blockIdx.x * blockDim.x + threadIdx.x;
    if (idx < RB) {
        int i = idx / DB1;          // pixel
        int r = idx - i * DB1;      // simplex vertex rank
        int x = i % IMW, y = i / IMW;
        float f[DB];
        f[0] = (float)x / 80.0f;
        f[1] = (float)y / 80.0f;
        f[2] = image[i * 3 + 0] / 13.0f;
        f[3] = image[i * 3 + 1] / 13.0f;
        f[4] = image[i * 3 + 2] / 13.0f;
        float bary[DB1]; unsigned long long pk[DB1];
        perm_embed<DB>(f, bary, pk);
        float w = 0.f; unsigned long long k = 0;
        #pragma unroll
        for (int r2 = 0; r2 < DB1; r2++)
            if (r2 == r) { w = bary[r2]; k = pk[r2]; }   // static idx -> regs
        wsv[idx] = w;
        os[idx] = hash_insert2(hkid, TBS - 1, k);
    } else if (idx < RB + RS) {
        int t = idx - RB;
        int ip = t / DS1;
        int r = t - ip * DS1;
        int x = ip % IMW, y = ip / IMW;
        float f[DS];
        f[0] = (float)x / 3.0f;
        f[1] = (float)y / 3.0f;
        float bary[DS1]; unsigned long long pk[DS1];
        perm_embed<DS>(f, bary, pk);
        float w = 0.f; unsigned long long k = 0;
        #pragma unroll
        for (int r2 = 0; r2 < DS1; r2++)
            if (r2 == r) { w = bary[r2]; k = pk[r2]; }
        int c0 = (int)(k & 0xFFFULL) - 2048;
        int c1 = (int)((k >> 12) & 0xFFFULL) - 2048;
        int gid = (c0 + C0OFF) * GS + (c1 + C1OFF);
        wsv[idx] = w;
        os[idx] = gid;
        pres[gid] = 1;              // benign same-value race, no atomic
    }
}

// hist over bilateral table only
__global__ void hist_b(const ulonglong2* __restrict__ hkid, int* hist) {
    int s = blockIdx.x * blockDim.x + threadIdx.x;
    if (s >= TBS) return;
    unsigned long long k = hkid[s].x;
    if (k == EMPTY_KEY) return;
    atomicAdd(&hist[key_code(k)], 1);
}

// ---------------- barrier-free scan machinery ----------------
__global__ void scan_wave_partial(const int* __restrict__ count, int* incl, int* wsum, int n) {
    int idx = blockIdx.x * blockDim.x + threadIdx.x;
    int lane = threadIdx.x & 63;
    int v = (idx < n) ? count[idx] : 0;
    int s = v;
    #pragma unroll
    for (int d = 1; d < 64; d <<= 1) {
        int t = __shfl_up(s, d);
        if (lane >= d) s += t;
    }
    if (idx < n) incl[idx] = s;
    if (lane == 63) wsum[idx >> 6] = s;
}

__global__ void scan_partials_excl(int* w, int nw, int* total_out) {
    __shared__ int sh[256];
    __shared__ int run;
    if (threadIdx.x == 0) run = 0;
    __syncthreads();
    for (int basei = 0; basei < nw; basei += 256) {
        int idx = basei + threadIdx.x;
        int v = (idx < nw) ? w[idx] : 0;
        sh[threadIdx.x] = v;
        __syncthreads();
        for (int d = 1; d < 256; d <<= 1) {
            int t = (threadIdx.x >= d) ? sh[threadIdx.x - d] : 0;
            __syncthreads();
            sh[threadIdx.x] += t;
            __syncthreads();
        }
        int total = sh[255];
        if (idx < nw) w[idx] = run + sh[threadIdx.x] - v;
        __syncthreads();
        if (threadIdx.x == 0) run += total;
        __syncthreads();
    }
    if (total_out != nullptr && threadIdx.x == 0) *total_out = run;
}

__global__ void scan_finalize(int* off, const int* __restrict__ count,
                              const int* __restrict__ wsum, int n) {
    int idx = blockIdx.x * blockDim.x + threadIdx.x;
    if (idx < n) off[idx] = off[idx] - count[idx] + wsum[idx >> 6];
}

// ---------------- bucket-sorted compaction (bilateral) ----------------
__global__ void assign_b(ulonglong2* hkid, const int* __restrict__ histOff,
                         int* histFill, unsigned long long* uk_b) {
    int s = blockIdx.x * blockDim.x + threadIdx.x;
    if (s >= TBS) return;
    unsigned long long k = hkid[s].x;
    if (k == EMPTY_KEY) return;
    int code = key_code(k);
    int id = histOff[code] + atomicAdd(&histFill[code], 1);
    hkid[s].y = (unsigned long long)id;
    uk_b[id] = k;
}

// spatial neighbors via dense grid reads — no hashing, no atomics.
__global__ void spatial_neighbors(const int* __restrict__ pres, const int* __restrict__ gid2id,
                                  int* __restrict__ n1s, int* __restrict__ n2s) {
    int gid = blockIdx.x * blockDim.x + threadIdx.x;
    if (gid >= GN) return;
    if (!pres[gid]) return;
    int id = gid2id[gid];
    const int d1[3] = {  2 * GS - 1, -GS + 2, -GS - 1 };
    const int d2[3] = { -2 * GS + 1,  GS - 2,  GS + 1 };
    #pragma unroll
    for (int j = 0; j < 3; j++) {
        int g1 = gid + d1[j], g2 = gid + d2[j];
        n1s[j * RS + id] = pres[g1] ? gid2id[g1] : -1;
        n2s[j * RS + id] = pres[g2] ? gid2id[g2] : -1;
    }
}

// unified os remap + cntr histogram + per-entry rank capture (wave-agg atomics).
__global__ void os_count_both(int* os, const ulonglong2* __restrict__ hkid,
                              const int* __restrict__ gid2id, int* cntr, int* rnk) {
    int i = blockIdx.x * blockDim.x + threadIdx.x;
    int lane = threadIdx.x & 63;
    int idg;
    if (i < RB) {
        int id = (int)hkid[os[i]].y;
        os[i] = id;
        idg = id;
    } else {
        int id = gid2id[os[i]];
        os[i] = id;
        idg = RB + id;
    }
    // 64-lane equal-id mask
    unsigned long long m = 0;
    #pragma unroll
    for (int l = 0; l < 64; l++) {
        int o = __shfl(idg, l);
        m |= (unsigned long long)(o == idg) << l;
    }
    int rless  = __popcll(m & ((1ULL << lane) - 1ULL));
    int leader = __ffsll(m) - 1;
    int gcnt   = __popcll(m);
    int base = 0;
    if (lane == leader) base = atomicAdd(&cntr[idg], gcnt);
    base = __shfl(base, leader);
    rnk[i] = base + rless;
}

// bilateral neighbors, (j,m) parallel; XCD-chunk swizzle for L2 locality.
__global__ void build_neighbors_b(const unsigned long long* __restrict__ uk,
                                  const ulonglong2* __restrict__ hkid,
                                  const int* cnt, int* n1, int* n2) {
    int Mb = cnt[0];
    int tot = DB1 * Mb;
    int nb = gridDim.x;                    // multiple of 8
    int bid = blockIdx.x;
    int swz = (bid & 7) * (nb >> 3) + (bid >> 3);
    int stride = nb * blockDim.x;
    for (int t = swz * blockDim.x + threadIdx.x; t < tot; t += stride) {
        int j = t / Mb, m = t - j * Mb;
        unsigned long long k = uk[m];
        unsigned long long p1 = 0, p2 = 0;
        #pragma unroll
        for (int i = 0; i < DB; i++) {
            int c = (int)((k >> (12 * i)) & 0xFFFULL) - 2048;
            int a = c + ((i == j) ? DB : -1);
            int b = c + ((i == j) ? -DB : 1);
            p1 |= ((unsigned long long)((unsigned)(a + 2048) & 0xFFFu)) << (12 * i);
            p2 |= ((unsigned long long)((unsigned)(b + 2048) & 0xFFFu)) << (12 * i);
        }
        n1[j * RB + m] = hash_lookup2(hkid, TBS - 1, p1);
        n2[j * RB + m] = hash_lookup2(hkid, TBS - 1, p2);
    }
}

// r20: composed neighbor indices for fused blur pairs.
// bilateral: pair(0,1) -> comp[0..3]*RB; pair(3,4) -> comp[4..7]*RB.
// comp through missing neighbor (-1) stays -1 (sink value is 0).
__global__ void compose_b(const int* __restrict__ n1, const int* __restrict__ n2,
                          const int* cnt, int* __restrict__ comp) {
    int Mb = cnt[0];
    int stride = gridDim.x * blockDim.x;
    for (int m = blockIdx.x * blockDim.x + threadIdx.x; m < Mb; m += stride) {
        int a = n1[RB + m], b = n2[RB + m];
        comp[0 * RB + m] = (a < 0) ? -1 : n1[a];
        comp[1 * RB + m] = (a < 0) ? -1 : n2[a];
        comp[2 * RB + m] = (b < 0) ? -1 : n1[b];
        comp[3 * RB + m] = (b < 0) ? -1 : n2[b];
        int a2 = n1[4 * RB + m], b2 = n2[4 * RB + m];
        comp[4 * RB + m] = (a2 < 0) ? -1 : n1[3 * RB + a2];
        comp[5 * RB + m] = (a2 < 0) ? -1 : n2[3 * RB + a2];
        comp[6 * RB + m] = (b2 < 0) ? -1 : n1[3 * RB + b2];
        comp[7 * RB + m] = (b2 < 0) ? -1 : n2[3 * RB + b2];
    }
}
// spatial: pair(0,1) only -> comp[0..3]*RS.
__global__ void compose_s(const int* __restrict__ n1, const int* __restrict__ n2,
                          const int* cnt, int* __restrict__ comp) {
    int Ms = cnt[1];
    int stride = gridDim.x * blockDim.x;
    for (int m = blockIdx.x * blockDim.x + threadIdx.x; m < Ms; m += stride) {
        int a = n1[RS + m], b = n2[RS + m];
        comp[0 * RS + m] = (a < 0) ? -1 : n1[a];
        comp[1 * RS + m] = (a < 0) ? -1 : n2[a];
        comp[2 * RS + m] = (b < 0) ? -1 : n1[b];
        comp[3 * RS + m] = (b < 0) ? -1 : n2[b];
    }
}

// unified fill: pos derived from precomputed rank — NO atomics
__global__ void fill_both(const int* __restrict__ os, const float* __restrict__ wsv,
                          const int* __restrict__ off, const int* __restrict__ rnk,
                          unsigned* epw) {
    int idx = blockIdx.x * blockDim.x + threadIdx.x;
    if (idx >= RB + RS) return;
    int slot, pix;
    if (idx < RB) { slot = os[idx];        pix = idx / DB1; }
    else          { slot = RB + os[idx];   pix = (idx - RB) / DS1; }
    int pos = off[slot] + rnk[idx];
    epw[pos] = pack_ew(pix, wsv[idx]);
}

// ---------------- batched filter kernels (fp16 storage, fp32 math) ----------------
// r20: 3 chunk-threads per row (chunk-major) — TLP 3x; epw re-read per chunk
// is sequential/L2-hit; Qh reads stay 16B coalesced-ish.
__global__ void gather_both_h(const uint4* __restrict__ Qh4, const int* __restrict__ off,
                              const int* __restrict__ cntr, const unsigned* __restrict__ epw,
                              uint4* __restrict__ buf4, const int* cnt) {
    int Mb = cnt[0], Ms = cnt[1];
    int totB = Mb + 1;
    int totR = totB + Ms + 1;
    int tot = totR * 3;
    int stride = gridDim.x * blockDim.x;
    for (int idx = blockIdx.x * blockDim.x + threadIdx.x; idx < tot; idx += stride) {
        int c = idx / totR, r = idx - c * totR;
        int orow, slot;
        if (r < totB) { orow = r; slot = r - 1; }
        else { int t = r - totB; orow = RB + 1 + t; slot = t ? (RB + t - 1) : -1; }
        float acc[8];
        #pragma unroll
        for (int t2 = 0; t2 < 8; t2++) acc[t2] = 0.f;
        if (slot >= 0) {
            int s = off[slot], e = s + cntr[slot];
            for (int t = s; t < e; t++) {
                int pix; float w;
                unpack_ew(epw[t], pix, w);
                acc8(acc, w, Qh4[(size_t)pix * 3 + c]);
            }
        }
        buf4[(size_t)orow * 3 + c] = pack8(acc);
    }
}

// single-step blur (j=2 both chains), 3 chunks/row.
__global__ void blur_both_h(const uint4* __restrict__ in4, uint4* __restrict__ out4,
                            const int* __restrict__ n1b, const int* __restrict__ n2b,
                            const int* __restrict__ n1s, const int* __restrict__ n2s,
                            const int* cnt) {
    int Mb = cnt[0], Ms = cnt[1];
    int totB = (Mb + 1) * 3;
    int tot = totB + (Ms + 1) * 3;
    int stride = gridDim.x * blockDim.x;
    for (int idx = blockIdx.x * blockDim.x + threadIdx.x; idx < tot; idx += stride) {
        int r, c, orow, a1, a2;
        bool sink;
        if (idx < totB) {
            r = idx / 3; c = idx - r * 3;
            orow = r; sink = (r == 0);
            int m = r - 1;
            a1 = sink ? 0 : n1b[m] + 1;
            a2 = sink ? 0 : n2b[m] + 1;
        } else {
            int t = idx - totB;
            r = t / 3; c = t - r * 3;
            orow = RB + 1 + r; sink = (r == 0);
            int m = r - 1;
            a1 = sink ? 0 : RB + 2 + n1s[m];   // -1 -> sink RB+1
            a2 = sink ? 0 : RB + 2 + n2s[m];
        }
        size_t o = (size_t)orow * 3 + c;
        if (sink) { out4[o] = make_uint4(0u, 0u, 0u, 0u); continue; }
        out4[o] = blur8(in4[o], in4[(size_t)a1 * 3 + c], in4[(size_t)a2 * 3 + c]);
    }
}

// single-step bilateral blur (j=5), 3 chunks/row.
__global__ void blur_b_h(const uint4* __restrict__ in4, uint4* __restrict__ out4,
                         const int* __restrict__ n1, const int* __restrict__ n2,
                         const int* cnt) {
    int M = cnt[0];
    int tot = (M + 1) * 3;
    int stride = gridDim.x * blockDim.x;
    for (int idx = blockIdx.x * blockDim.x + threadIdx.x; idx < tot; idx += stride) {
        int r = idx / 3, c = idx - r * 3;
        size_t o = (size_t)r * 3 + c;
        if (r == 0) { out4[o] = make_uint4(0u, 0u, 0u, 0u); continue; }
        int m = r - 1;
        out4[o] = blur8(in4[o], in4[(size_t)(n1[m] + 1) * 3 + c],
                        in4[(size_t)(n2[m] + 1) * 3 + c]);
    }
}

// r20: fused pair blur (j=0 then j=1), both chains. 9-point stencil:
// out = x + 0.5(x@n1p + x@n2p + x@a + x@b) + 0.25(x@c1..c4), a=n1q, b=n2q.
__global__ void fused_blur_both_h(const uint4* __restrict__ in4, uint4* __restrict__ out4,
                                  const int* __restrict__ n1b, const int* __restrict__ n2b,
                                  const int* __restrict__ compb,
                                  const int* __restrict__ n1s, const int* __restrict__ n2s,
                                  const int* __restrict__ comps, const int* cnt) {
    int Mb = cnt[0], Ms = cnt[1];
    int totB = (Mb + 1) * 3;
    int tot = totB + (Ms + 1) * 3;
    int stride = gridDim.x * blockDim.x;
    for (int idx = blockIdx.x * blockDim.x + threadIdx.x; idx < tot; idx += stride) {
        int r, c, self = 0, i1 = 0, i2 = 0, ia = 0, ib = 0, ic1 = 0, ic2 = 0, ic3 = 0, ic4 = 0;
        bool sink;
        if (idx < totB) {
            r = idx / 3; c = idx - r * 3;
            sink = (r == 0);
            self = r;
            int m = r - 1;
            if (!sink) {
                i1 = n1b[m] + 1;             i2 = n2b[m] + 1;
                ia = n1b[RB + m] + 1;        ib = n2b[RB + m] + 1;
                ic1 = compb[m] + 1;          ic2 = compb[RB + m] + 1;
                ic3 = compb[2 * RB + m] + 1; ic4 = compb[3 * RB + m] + 1;
            }
        } else {
            int t = idx - totB;
            r = t / 3; c = t - r * 3;
            sink = (r == 0);
            self = RB + 1 + r;
            int m = r - 1;
            if (!sink) {
                i1 = RB + 2 + n1s[m];             i2 = RB + 2 + n2s[m];
                ia = RB + 2 + n1s[RS + m];        ib = RB + 2 + n2s[RS + m];
                ic1 = RB + 2 + comps[m];          ic2 = RB + 2 + comps[RS + m];
                ic3 = RB + 2 + comps[2 * RS + m]; ic4 = RB + 2 + comps[3 * RS + m];
            }
        }
        size_t o = (size_t)self * 3 + c;
        if (sink) { out4[o] = make_uint4(0u, 0u, 0u, 0u); continue; }
        float acc[8];
        #pragma unroll
        for (int t2 = 0; t2 < 8; t2++) acc[t2] = 0.f;
        acc8(acc, 1.0f,  in4[o]);
        acc8(acc, 0.5f,  in4[(size_t)i1 * 3 + c]);
        acc8(acc, 0.5f,  in4[(size_t)i2 * 3 + c]);
        acc8(acc, 0.5f,  in4[(size_t)ia * 3 + c]);
        acc8(acc, 0.5f,  in4[(size_t)ib * 3 + c]);
        acc8(acc, 0.25f, in4[(size_t)ic1 * 3 + c]);
        acc8(acc, 0.25f, in4[(size_t)ic2 * 3 + c]);
        acc8(acc, 0.25f, in4[(size_t)ic3 * 3 + c]);
        acc8(acc, 0.25f, in4[(size_t)ic4 * 3 + c]);
        out4[o] = pack8(acc);
    }
}

// fused pair blur (j=3 then j=4), bilateral only.
__global__ void fused_blur_b_h(const uint4* __restrict__ in4, uint4* __restrict__ out4,
                               const int* __restrict__ n1b, const int* __restrict__ n2b,
                               const int* __restrict__ compb, const int* cnt) {
    int M = cnt[0];
    int tot = (M + 1) * 3;
    int stride = gridDim.x * blockDim.x;
    for (int idx = blockIdx.x * blockDim.x + threadIdx.x; idx < tot; idx += stride) {
        int r = idx / 3, c = idx - r * 3;
        size_t o = (size_t)r * 3 + c;
        if (r == 0) { out4[o] = make_uint4(0u, 0u, 0u, 0u); continue; }
        int m = r - 1;
        int i1 = n1b[3 * RB + m] + 1,  i2 = n2b[3 * RB + m] + 1;
        int ia = n1b[4 * RB + m] + 1,  ib = n2b[4 * RB + m] + 1;
        int ic1 = compb[4 * RB + m] + 1, ic2 = compb[5 * RB + m] + 1;
        int ic3 = compb[6 * RB + m] + 1, ic4 = compb[7 * RB + m] + 1;
        float acc[8];
        #pragma unroll
        for (int t2 = 0; t2 < 8; t2++) acc[t2] = 0.f;
        acc8(acc, 1.0f,  in4[o]);
        acc8(acc, 0.5f,  in4[(size_t)i1 * 3 + c]);
        acc8(acc, 0.5f,  in4[(size_t)i2 * 3 + c]);
        acc8(acc, 0.5f,  in4[(size_t)ia * 3 + c]);
        acc8(acc, 0.5f,  in4[(size_t)ib * 3 + c]);
        acc8(acc, 0.25f, in4[(size_t)ic1 * 3 + c]);
        acc8(acc, 0.25f, in4[(size_t)ic2 * 3 + c]);
        acc8(acc, 0.25f, in4[(size_t)ic3 * 3 + c]);
        acc8(acc, 0.25f, in4[(size_t)ic4 * 3 + c]);
        out4[o] = pack8(acc);
    }
}

// ---- fp32 norm-chain versions (per-row threads) ----
__global__ void gather1_both(const int* __restrict__ off, const int* __restrict__ cntr,
                             const unsigned* __restrict__ epw, float* __restrict__ buf,
                             const int* cnt) {
    int Mb = cnt[0], Ms = cnt[1];
    int totB = Mb + 1;
    int tot = totB + Ms + 1;
    int stride = gridDim.x * blockDim.x;
    for (int r = blockIdx.x * blockDim.x + threadIdx.x; r < tot; r += stride) {
        int o, slot;
        if (r < totB) { o = r;              slot = r ? (r - 1) : -1; }
        else          { int t = r - totB; o = RB + 1 + t; slot = t ? (RB + t - 1) : -1; }
        float acc = 0.f;
        if (slot >= 0) {
            int s = off[slot], e = s + cntr[slot];
            for (int t = s; t < e; t++) acc += (float)(epw[t] >> 17) * (1.0f / 32767.0f);
        }
        buf[o] = acc;
    }
}

__global__ void blur1_both(const float* __restrict__ in, float* __restrict__ out,
                           const int* __restrict__ n1b, const int* __restrict__ n2b,
                           const int* __restrict__ n1s, const int* __restrict__ n2s,
                           const int* cnt) {
    int Mb = cnt[0], Ms = cnt[1];
    int totB = Mb + 1;
    int tot = totB + Ms + 1;
    int stride = gridDim.x * blockDim.x;
    for (int r = blockIdx.x * blockDim.x + threadIdx.x; r < tot; r += stride) {
        if (r < totB) {
            if (r == 0) { out[0] = 0.f; continue; }
            int m = r - 1;
            out[r] = in[r] + 0.5f * (in[n1b[m] + 1] + in[n2b[m] + 1]);
        } else {
            int t = r - totB;
            int o = RB + 1 + t;
            if (t == 0) { out[o] = 0.f; continue; }
            int m = t - 1;
            out[o] = in[o] + 0.5f * (in[RB + 2 + n1s[m]] + in[RB + 2 + n2s[m]]);
        }
    }
}

__global__ void blur1_b(const float* __restrict__ in, float* __restrict__ out,
                        const int* __restrict__ n1, const int* __restrict__ n2,
                        const int* cnt) {
    int M = cnt[0];
    int stride = gridDim.x * blockDim.x;
    for (int row = blockIdx.x * blockDim.x + threadIdx.x; row <= M; row += stride) {
        if (row == 0) { out[0] = 0.f; continue; }
        int m = row - 1;
        out[row] = in[row] + 0.5f * (in[n1[m] + 1] + in[n2[m] + 1]);
    }
}

__global__ void fused1_both(const float* __restrict__ in, float* __restrict__ out,
                            const int* __restrict__ n1b, const int* __restrict__ n2b,
                            const int* __restrict__ compb,
                            const int* __restrict__ n1s, const int* __restrict__ n2s,
                            const int* __restrict__ comps, const int* cnt) {
    int Mb = cnt[0], Ms = cnt[1];
    int totB = Mb + 1;
    int tot = totB + Ms + 1;
    int stride = gridDim.x * blockDim.x;
    for (int r = blockIdx.x * blockDim.x + threadIdx.x; r < tot; r += stride) {
        if (r < totB) {
            if (r == 0) { out[0] = 0.f; continue; }
            int m = r - 1;
            out[r] = in[r]
                + 0.5f * (in[n1b[m] + 1] + in[n2b[m] + 1]
                        + in[n1b[RB + m] + 1] + in[n2b[RB + m] + 1])
                + 0.25f * (in[compb[m] + 1] + in[compb[RB + m] + 1]
                         + in[compb[2 * RB + m] + 1] + in[compb[3 * RB + m] + 1]);
        } else {
            int t = r - totB;
            int o = RB + 1 + t;
            if (t == 0) { out[o] = 0.f; continue; }
            int m = t - 1;
            out[o] = in[o]
                + 0.5f * (in[RB + 2 + n1s[m]] + in[RB + 2 + n2s[m]]
                        + in[RB + 2 + n1s[RS + m]] + in[RB + 2 + n2s[RS + m]])
                + 0.25f * (in[RB + 2 + comps[m]] + in[RB + 2 + comps[RS + m]]
                         + in[RB + 2 + comps[2 * RS + m]] + in[RB + 2 + comps[3 * RS + m]]);
        }
    }
}

__global__ void fused1_b(const float* __restrict__ in, float* __restrict__ out,
                         const int* __restrict__ n1b, const int* __restrict__ n2b,
                         const int* __restrict__ compb, const int* cnt) {
    int M = cnt[0];
    int stride = gridDim.x * blockDim.x;
    for (int r = blockIdx.x * blockDim.x + threadIdx.x; r <= M; r += stride) {
        if (r == 0) { out[0] = 0.f; continue; }
        int m = r - 1;
        out[r] = in[r]
            + 0.5f * (in[n1b[3 * RB + m] + 1] + in[n2b[3 * RB + m] + 1]
                    + in[n1b[4 * RB + m] + 1] + in[n2b[4 * RB + m] + 1])
            + 0.25f * (in[compb[4 * RB + m] + 1] + in[compb[5 * RB + m] + 1]
                     + in[compb[6 * RB + m] + 1] + in[compb[7 * RB + m] + 1]);
    }
}

// both norms in one pass (bilateral final in bufB, spatial final in bufS)
__global__ void slice_norm_both(const float* __restrict__ bufB, const float* __restrict__ bufS,
                                const int* __restrict__ osw, const float* __restrict__ wsv,
                                float* __restrict__ nbv, float* __restrict__ nsv,
                                float alphaB, float alphaS) {
    int i = blockIdx.x * blockDim.x + threadIdx.x;
    if (i >= NPIX) return;
    float sb = 0.f;
    #pragma unroll
    for (int r = 0; r < DB1; r++)
        sb += wsv[i * DB1 + r] * bufB[osw[i * DB1 + r] + 1];
    float ss = 0.f;
    #pragma unroll
    for (int r = 0; r < DS1; r++)
        ss += wsv[RB + i * DS1 + r] * bufS[RB + 2 + osw[RB + i * DS1 + r]];
    nbv[i] = alphaB * sb + 1e-20f;
    nsv[i] = alphaS * ss + 1e-20f;
}

// fused: slice(bilateral)+slice(spatial)+normalize+softmax -> Q (fp32) + Qh (fp16)
__global__ void slice_update(const float* __restrict__ U,
                             const uint4* __restrict__ bufB4, const uint4* __restrict__ bufS4,
                             const int* __restrict__ osw, const float* __restrict__ wsv,
                             const float* __restrict__ nbv, const float* __restrict__ nsv,
                             float* __restrict__ Q, uint4* __restrict__ Qh4,
                             float alphaB, float alphaS, int use_msg) {
    int i = blockIdx.x * blockDim.x + threadIdx.x;
    if (i >= NPIX) return;
    float msg[24];
    #pragma unroll
    for (int t = 0; t < 24; t++) msg[t] = 0.f;
    if (use_msg) {
        float ib = 10.0f * alphaB / nbv[i];
        float is = 3.0f * alphaS / nsv[i];
        #pragma unroll
        for (int r = 0; r < DB1; r++) {
            float w = ib * wsv[i * DB1 + r];
            size_t base = (size_t)(osw[i * DB1 + r] + 1) * 3;
            uint4 q0 = bufB4[base], q1 = bufB4[base + 1], q2 = bufB4[base + 2];
            acc8(msg + 0,  w, q0);
            acc8(msg + 8,  w, q1);
            acc8(msg + 16, w, q2);
        }
        #pragma unroll
        for (int r = 0; r < DS1; r++) {
            float w = is * wsv[RB + i * DS1 + r];
            size_t base = (size_t)(RB + 2 + osw[RB + i * DS1 + r]) * 3;
            uint4 q0 = bufS4[base], q1 = bufS4[base + 1], q2 = bufS4[base + 2];
            acc8(msg + 0,  w, q0);
            acc8(msg + 8,  w, q1);
            acc8(msg + 16, w, q2);
        }
    }
    float mx = -1e30f;
    #pragma unroll
    for (int c = 0; c < NC; c++) {
        msg[c] = -U[i * NC + c] + msg[c];
        mx = fmaxf(mx, msg[c]);
    }
    float s = 0.f;
    #pragma unroll
    for (int c = 0; c < NC; c++) { float e = expf(msg[c] - mx); msg[c] = e; s += e; }
    float inv = 1.0f / s;
    #pragma unroll
    for (int c = 0; c < NC; c++) {
        msg[c] *= inv;
        Q[i * NC + c] = msg[c];
    }
    msg[21] = 0.f; msg[22] = 0.f; msg[23] = 0.f;
    #pragma unroll
    for (int t = 0; t < 3; t++) {
        uint2 lo = f2u(make_float4(msg[8*t+0], msg[8*t+1], msg[8*t+2], msg[8*t+3]));
        uint2 hi = f2u(make_float4(msg[8*t+4], msg[8*t+5], msg[8*t+6], msg[8*t+7]));
        Qh4[i * 3 + t] = make_uint4(lo.x, lo.y, hi.x, hi.y);
    }
}

// ---------------- host orchestration ----------------
extern "C" void kernel_launch(void* const* d_in, const int* in_sizes, int n_in,
                              void* d_out, int out_size, void* d_ws, size_t ws_size,
                              hipStream_t stream) {
    const float* U     = (const float*)d_in[0];
    const float* image = (const float*)d_in[1];
    float* Q = (float*)d_out;

    char* base = (char*)d_ws;
    size_t off = 0;
    auto alloc = [&](size_t bytes) -> void* {
        off = (off + 255) & ~(size_t)255;
        void* p = base + off; off += bytes; return p;
    };
    // unified per-entry arrays: [0,RB) bilateral, [RB,RB+RS) spatial
    int*   osw  = (int*)  alloc((size_t)(RB + RS) * 4);
    float* wsv  = (float*)alloc((size_t)(RB + RS) * 4);
    int*   rnk  = (int*)  alloc((size_t)(RB + RS) * 4);
    int*   n1_b = (int*)  alloc((size_t)DB1 * RB * 4);
    int*   n2_b = (int*)  alloc((size_t)DB1 * RB * 4);
    int*   n1_s = (int*)  alloc((size_t)DS1 * RS * 4);
    int*   n2_s = (int*)  alloc((size_t)DS1 * RS * 4);
    int*   comp_b = (int*)alloc((size_t)8 * RB * 4);   // fused pairs (0,1),(3,4)
    int*   comp_s = (int*)alloc((size_t)4 * RS * 4);   // fused pair (0,1)
    unsigned long long* uk_b = (unsigned long long*)alloc((size_t)RB * 8);
    ulonglong2* hkid = (ulonglong2*)alloc((size_t)TBS * 16);
    int*   gid2id = (int*)alloc((size_t)GN * 4);
    int*   cnt  = (int*)  alloc(256);   // [0]=M_b, [1]=M_s
    int*   histOff = (int*)alloc((size_t)NBUCK * 4);
    int*   wsums   = (int*)alloc((size_t)64 * 1024 * 4);
    int*   wsI     = (int*)alloc((size_t)16384 * 4);   // level-1 inclusive sums
    int*   ws2     = (int*)alloc((size_t)1024 * 4);    // level-2 sums
    int*   offv    = (int*)alloc((size_t)(RB + RS) * 4);
    // contiguous zero region: cntr | hist | histFill | pres
    char*  zreg  = (char*)alloc((size_t)(RB + RS) * 4 + (size_t)NBUCK * 8 + (size_t)GN * 4);
    int*   cntr     = (int*)zreg;
    int*   hist     = cntr + (RB + RS);
    int*   histFill = hist + NBUCK;
    int*   pres     = histFill + NBUCK;
    size_t zbytes = (size_t)(RB + RS) * 4 + (size_t)NBUCK * 8 + (size_t)GN * 4;
    unsigned* epw = (unsigned*)alloc((size_t)(RB + RS) * 4);   // packed 4B entries
    float* norm_b = (float*)alloc((size_t)NPIX * 4);
    float* norm_s = (float*)alloc((size_t)NPIX * 4);
    uint2* Qh   = (uint2*)alloc((size_t)NPIX * CP4 * 8);
    // combined lattice buffers: rows RB+RS+2 (bilateral [0,RB], spatial [RB+1,...])
    uint2* buf0 = (uint2*)alloc((size_t)(RB + RS + 2) * CP4 * 8);
    uint2* buf1 = (uint2*)alloc((size_t)(RB + RS + 2) * CP4 * 8);
    float* nbuf0 = (float*)alloc((size_t)(RB + RS + 2) * 4);
    float* nbuf1 = (float*)alloc((size_t)(RB + RS + 2) * 4);
    if (off > ws_size) return;

    const float ALPHA_B = (float)(1.0 / (1.0 + exp2(-(double)DB)));  // 32/33
    const float ALPHA_S = (float)(1.0 / (1.0 + exp2(-(double)DS)));  // 4/5

    constexpr int PGR = 2048;   // chunk-level gather/blur grids (grid-stride)

    // ---- 3 memsets ----
    hipMemsetAsync(cnt, 0, 16, stream);
    hipMemsetAsync(hkid, 0xFF, (size_t)TBS * 16, stream);
    hipMemsetAsync(zreg, 0, zbytes, stream);

    // ---- build both lattices ----
    build_both<<<(RB + RS) / 256, 256, 0, stream>>>(image, hkid, osw, wsv, pres);
    // bilateral compaction (bucket-sorted ids)
    hist_b<<<TBS / 256, 256, 0, stream>>>(hkid, hist);
    scan_wave_partial<<<NBUCK / 256, 256, 0, stream>>>(hist, histOff, wsums, NBUCK);
    scan_partials_excl<<<1, 256, 0, stream>>>(wsums, NBUCK / 64, cnt + 0);
    scan_finalize<<<NBUCK / 256, 256, 0, stream>>>(histOff, hist, wsums, NBUCK);
    assign_b<<<TBS / 256, 256, 0, stream>>>(hkid, histOff, histFill, uk_b);
    // spatial compaction (dense grid presence scan; ids row-major in (c0,c1))
    scan_wave_partial<<<GN / 256, 256, 0, stream>>>(pres, gid2id, wsums, GN);
    scan_partials_excl<<<1, 256, 0, stream>>>(wsums, GN / 64, cnt + 1);
    scan_finalize<<<GN / 256, 256, 0, stream>>>(gid2id, pres, wsums, GN);
    spatial_neighbors<<<GN / 256, 256, 0, stream>>>(pres, gid2id, n1_s, n2_s);
    compose_s<<<256, 256, 0, stream>>>(n1_s, n2_s, cnt, comp_s);
    os_count_both<<<(RB + RS) / 256, 256, 0, stream>>>(osw, hkid, gid2id, cntr, rnk);
    build_neighbors_b<<<2048, 256, 0, stream>>>(uk_b, hkid, cnt + 0, n1_b, n2_b);
    compose_b<<<1024, 256, 0, stream>>>(n1_b, n2_b, cnt, comp_b);
    // unified offset scan over RB+RS id slots — hierarchical
    scan_wave_partial<<<(RB + RS) / 256, 256, 0, stream>>>(cntr, offv, wsums, RB + RS);
    scan_wave_partial<<<(NW1 + 255) / 256, 256, 0, stream>>>(wsums, wsI, ws2, NW1);
    scan_partials_excl<<<1, 256, 0, stream>>>(ws2, (NW1 + 63) / 64, nullptr);
    scan_finalize<<<(NW1 + 255) / 256, 256, 0, stream>>>(wsI, wsums, ws2, NW1);
    scan_finalize<<<(RB + RS) / 256, 256, 0, stream>>>(offv, cntr, wsI, RB + RS);
    fill_both<<<(RB + RS + 255) / 256, 256, 0, stream>>>(osw, wsv, offv, rnk, epw);

    // ---- norm filters (C=1, fp32), fused-pair chain ----
    {
        gather1_both<<<1024, 256, 0, stream>>>(offv, cntr, epw, nbuf0, cnt);
        // pair (0,1) both chains
        fused1_both<<<1024, 256, 0, stream>>>(nbuf0, nbuf1, n1_b, n2_b, comp_b,
                                              n1_s, n2_s, comp_s, cnt);
        // j=2 both chains
        blur1_both<<<1024, 256, 0, stream>>>(nbuf1, nbuf0,
            n1_b + (size_t)2 * RB, n2_b + (size_t)2 * RB,
            n1_s + (size_t)2 * RS, n2_s + (size_t)2 * RS, cnt);
        // pair (3,4) bilateral
        fused1_b<<<1024, 256, 0, stream>>>(nbuf0, nbuf1, n1_b, n2_b, comp_b, cnt);
        // j=5 bilateral
        blur1_b<<<1024, 256, 0, stream>>>(nbuf1, nbuf0,
            n1_b + (size_t)5 * RB, n2_b + (size_t)5 * RB, cnt);
        // bilateral final in nbuf0; spatial final also in nbuf0 (written at j=2,
        // untouched by the bilateral-only passes).
        slice_norm_both<<<(NPIX + 255) / 256, 256, 0, stream>>>(
            nbuf0, nbuf0, osw, wsv, norm_b, norm_s, ALPHA_B, ALPHA_S);
    }

    // ---- Q0 = softmax(-U) ----
    slice_update<<<(NPIX + 255) / 256, 256, 0, stream>>>(
        U, (const uint4*)buf0, (const uint4*)buf0, osw, wsv, norm_b, norm_s,
        Q, (uint4*)Qh, ALPHA_B, ALPHA_S, 0);

    // ---- 5 mean-field iterations ----
    for (int it = 0; it < 5; it++) {
        gather_both_h<<<PGR, 256, 0, stream>>>((const uint4*)Qh, offv, cntr, epw,
                                               (uint4*)buf0, cnt);
        // pair (0,1) both chains: buf0 -> buf1
        fused_blur_both_h<<<PGR, 256, 0, stream>>>((const uint4*)buf0, (uint4*)buf1,
            n1_b, n2_b, comp_b, n1_s, n2_s, comp_s, cnt);
        // j=2 both chains: buf1 -> buf0 (spatial final lands in buf0)
        blur_both_h<<<PGR, 256, 0, stream>>>((const uint4*)buf1, (uint4*)buf0,
            n1_b + (size_t)2 * RB, n2_b + (size_t)2 * RB,
            n1_s + (size_t)2 * RS, n2_s + (size_t)2 * RS, cnt);
        // pair (3,4) bilateral: buf0 -> buf1 (bilateral rows only)
        fused_blur_b_h<<<PGR, 256, 0, stream>>>((const uint4*)buf0, (uint4*)buf1,
            n1_b, n2_b, comp_b, cnt);
        // j=5 bilateral: buf1 -> buf0 (bilateral rows only; spatial rows in buf0
        // keep the j=2 final)
        blur_b_h<<<PGR, 256, 0, stream>>>((const uint4*)buf1, (uint4*)buf0,
            n1_b + (size_t)5 * RB, n2_b + (size_t)5 * RB, cnt);
        // both finals in buf0
        slice_update<<<(NPIX + 255) / 256, 256, 0, stream>>>(
            U, (const uint4*)buf0, (const uint4*)buf0, osw, wsv, norm_b, norm_s,
            Q, (uint4*)Qh, ALPHA_B, ALPHA_S, 1);
    }
}

// Round 6
// 827.036 us; speedup vs baseline: 1.0967x; 1.0967x over previous
//
#include <hip/hip_runtime.h>
#include <hip/hip_fp16.h>
#include <cmath>

// ---------------- problem constants ----------------
constexpr int IMH = 320, IMW = 320, NPIX = IMH * IMW, NC = 21;
constexpr int CP4 = 6;           // padded channels / 4  (24 values per row)
constexpr int DB = 5, DB1 = 6;   // bilateral lattice dim
constexpr int DS = 2, DS1 = 3;   // spatial lattice dim
constexpr int RB = NPIX * DB1;   // splat entries (bilateral) = 614400
constexpr int RS = NPIX * DS1;   // (spatial) = 307200
constexpr int TBS = 1 << 19;     // hash table slots (bilateral only)
constexpr int NBUCK = 1 << 16;   // bilateral sort buckets (c0,c1 low bytes)
constexpr int NW1 = (RB + RS) / 64;  // wave sums in the unified offset scan
// spatial dense grid: lattice coords are deterministic in (x,y) only.
// c0 in [-8, 298], c1 in [-194, 115]  ->  512x512 grid with offsets below.
constexpr int GS = 512, GN = GS * GS;
constexpr int C0OFF = 16, C1OFF = 200;

// Combined lattice-value buffer layout (static partition):
//   bilateral: row 0 = sink, point m -> row m+1           (rows [0, RB])
//   spatial:   row RB+1 = sink, point m -> row RB+2+m     (rows [RB+1, ...])
// spatial neighbor n=-1 maps to RB+2+(-1) = RB+1 = sink automatically.

// LESSONS (measured):
// r12-r14: hist fused into CAS loop = +45us; test-before-CAS = +8us/+36MB
//   FETCH; 4B epw packing does NOT cut scatter WRITE (64B sectors rule).
// r15: fill's atomicAdd removed via ranks captured in os_count.
// r16: ATOMIC-THROUGHPUT-BOUND build: WRITE_SIZE = count x 64B sectors,
//   ~16-19G atomics/s ceiling. Only fewer atomics help.
// r17: spatial lattice -> dense 512x512 grid (no atomics).
// r18: wave-agg os_count atomics OK; blur row-per-thread REGRESSED: <200K
//   threads is latency-starved. TLP rule: >=400K threads for scattered krns.
// r19: merged 16B {key,id} table, 6x parallel neighbor build, blur
//   3-chunk: 921->861us (best). fillBufferAligned = harness ws poison.
// r20: REGRESSED 861->907. (a) gather 3-chunk split: FETCH 25.7->68MB —
//   splitting a 48B row across threads re-fetches 64B sectors (Qh 4.9MB
//   doesn't live in 4MB/XCD L2 between chunk visits). SECTOR RULE beats
//   TLP rule: a thread must consume WHOLE 48B rows. (b) fused 9-pt blur:
//   9 scattered reads vs 6 in L2-miss regime (buf 44MB >> L2) — no win.
// r21 (this round): revert to r19; gather TLP via PAIRED LANES per row
//   (entry-parity split, full-row reads per lane, shfl_xor combine,
//   even lane writes) — 2x TLP at r19's exact byte count.

#define EMPTY_KEY 0xFFFFFFFFFFFFFFFFULL

__device__ __forceinline__ unsigned long long mix64(unsigned long long x) {
    x ^= x >> 33; x *= 0xff51afd7ed558ccdULL;
    x ^= x >> 33; x *= 0xc4ceb9fe1a85ec53ULL;
    x ^= x >> 33; return x;
}

// fp16 pack helpers: uint2 = 4 halves; math in fp32, storage fp16.
__device__ __forceinline__ float4 u2f(uint2 u) {
    __half2 a = *reinterpret_cast<__half2*>(&u.x);
    __half2 b = *reinterpret_cast<__half2*>(&u.y);
    float2 fa = __half22float2(a), fb = __half22float2(b);
    return make_float4(fa.x, fa.y, fb.x, fb.y);
}
__device__ __forceinline__ uint2 f2u(float4 v) {
    __half2 a = __floats2half2_rn(v.x, v.y);
    __half2 b = __floats2half2_rn(v.z, v.w);
    uint2 u;
    u.x = *reinterpret_cast<unsigned*>(&a);
    u.y = *reinterpret_cast<unsigned*>(&b);
    return u;
}

__device__ __forceinline__ unsigned pack_ew(int pix, float w) {
    int w15 = (int)lrintf(fminf(fmaxf(w, 0.f), 1.f) * 32767.f);
    return ((unsigned)w15 << 17) | (unsigned)pix;
}
__device__ __forceinline__ void unpack_ew(unsigned e, int& pix, float& w) {
    pix = (int)(e & 0x1FFFFu);
    w = (float)(e >> 17) * (1.0f / 32767.0f);
}

// accumulate 8 fp16 channels (one uint4) into acc[0..7] with weight w.
__device__ __forceinline__ void acc8(float* acc, float w, uint4 q) {
    float4 v = u2f(make_uint2(q.x, q.y));
    acc[0] += w * v.x; acc[1] += w * v.y; acc[2] += w * v.z; acc[3] += w * v.w;
    v = u2f(make_uint2(q.z, q.w));
    acc[4] += w * v.x; acc[5] += w * v.y; acc[6] += w * v.z; acc[7] += w * v.w;
}

// blur core on one uint4 (8 fp16 channels): x + 0.5*(a+b), f32 math.
__device__ __forceinline__ uint4 blur8(uint4 xs, uint4 xa, uint4 xb) {
    float4 s0 = u2f(make_uint2(xs.x, xs.y)), s1 = u2f(make_uint2(xs.z, xs.w));
    float4 a0 = u2f(make_uint2(xa.x, xa.y)), a1 = u2f(make_uint2(xa.z, xa.w));
    float4 b0 = u2f(make_uint2(xb.x, xb.y)), b1 = u2f(make_uint2(xb.z, xb.w));
    s0.x += 0.5f * (a0.x + b0.x); s0.y += 0.5f * (a0.y + b0.y);
    s0.z += 0.5f * (a0.z + b0.z); s0.w += 0.5f * (a0.w + b0.w);
    s1.x += 0.5f * (a1.x + b1.x); s1.y += 0.5f * (a1.y + b1.y);
    s1.z += 0.5f * (a1.z + b1.z); s1.w += 0.5f * (a1.w + b1.w);
    uint2 lo = f2u(s0), hi = f2u(s1);
    return make_uint4(lo.x, lo.y, hi.x, hi.y);
}

// ---------------- permutohedral embedding (matches reference op-for-op, f32) ----------------
template<int D>
__device__ void perm_embed(const float* f, float* bary, unsigned long long* pk) {
    constexpr int D1 = D + 1;
    float cf[D];
    #pragma unroll
    for (int i = 0; i < D; i++) {
        double s = sqrt(2.0 / 3.0) * (double)D1 / sqrt((double)((i + 1) * (i + 2)));
        cf[i] = f[i] * (float)s;
    }
    float csum[D];
    float acc = 0.f;
    #pragma unroll
    for (int i = D - 1; i >= 0; i--) { acc += cf[i]; csum[i] = acc; }
    float el[D1];
    el[0] = csum[0];
    #pragma unroll
    for (int i = 1; i < D; i++) el[i] = csum[i] - (float)i * cf[i - 1];
    el[D] = -(float)D * cf[D - 1];
    const float down = 1.0f / (float)D1;
    float rem0[D1]; int rank[D1]; int ssum = 0;
    #pragma unroll
    for (int i = 0; i < D1; i++) {
        float rd = rintf(el[i] * down);
        rem0[i] = rd * (float)D1;
        ssum += (int)rd;
    }
    float diff[D1];
    #pragma unroll
    for (int i = 0; i < D1; i++) diff[i] = el[i] - rem0[i];
    #pragma unroll
    for (int i = 0; i < D1; i++) {
        int r = 0;
        #pragma unroll
        for (int j = 0; j < D1; j++)
            r += (diff[j] > diff[i]) || ((diff[j] == diff[i]) && (j < i));
        rank[i] = r + ssum;
    }
    #pragma unroll
    for (int i = 0; i < D1; i++) {
        if (rank[i] < 0)      { rank[i] += D1; rem0[i] += (float)D1; }
        else if (rank[i] > D) { rank[i] -= D1; rem0[i] -= (float)D1; }
    }
    float b[D + 2];
    #pragma unroll
    for (int i = 0; i < D + 2; i++) b[i] = 0.f;
    #pragma unroll
    for (int i = 0; i < D1; i++) b[D - rank[i]]     += (el[i] - rem0[i]) * down;
    #pragma unroll
    for (int i = 0; i < D1; i++) b[D + 1 - rank[i]] -= (el[i] - rem0[i]) * down;
    b[0] += 1.0f + b[D + 1];
    #pragma unroll
    for (int i = 0; i < D1; i++) bary[i] = b[i];
    int key0[D];
    #pragma unroll
    for (int i = 0; i < D; i++) key0[i] = (int)rintf(rem0[i]);
    #pragma unroll
    for (int r = 0; r < D1; r++) {
        unsigned long long p = 0;
        #pragma unroll
        for (int i = 0; i < D; i++) {
            int c = key0[i] + ((rank[i] < D1 - r) ? r : r - D1);
            p |= ((unsigned long long)((unsigned)(c + 2048) & 0xFFFu)) << (12 * i);
        }
        pk[r] = p;
    }
}

__device__ __forceinline__ int key_code(unsigned long long k) {
    int c0 = (int)(k & 0xFFFULL);
    int c1 = (int)((k >> 12) & 0xFFFULL);
    return ((c0 & 0xFF) << 8) | (c1 & 0xFF);
}

// ---------------- merged {key,id} hash table (16B entries) ----------------
__device__ __forceinline__ int hash_insert2(ulonglong2* hkid, int tmask, unsigned long long k) {
    int slot = (int)(mix64(k) & (unsigned long long)tmask);
    while (true) {
        unsigned long long prev = atomicCAS(&hkid[slot].x, EMPTY_KEY, k);
        if (prev == EMPTY_KEY || prev == k) return slot;
        slot = (slot + 1) & tmask;
    }
}
// one 16B load per probe: key match delivers id in the same transaction.
__device__ __forceinline__ int hash_lookup2(const ulonglong2* __restrict__ hkid,
                                            int tmask, unsigned long long k) {
    int slot = (int)(mix64(k) & (unsigned long long)tmask);
    while (true) {
        ulonglong2 e = hkid[slot];
        if (e.x == k) return (int)e.y;
        if (e.x == EMPTY_KEY) return -1;
        slot = (slot + 1) & tmask;
    }
}

// ---------------- build kernels ----------------
__global__ void build_both(const float* __restrict__ image, ulonglong2* hkid,
                           int* os, float* wsv, int* pres) {
    int idx = blockIdx.x * blockDim.x + threadIdx.x;
    if (idx < RB) {
        int i = idx / DB1;          // pixel
        int r = idx - i * DB1;      // simplex vertex rank
        int x = i % IMW, y = i / IMW;
        float f[DB];
        f[0] = (float)x / 80.0f;
        f[1] = (float)y / 80.0f;
        f[2] = image[i * 3 + 0] / 13.0f;
        f[3] = image[i * 3 + 1] / 13.0f;
        f[4] = image[i * 3 + 2] / 13.0f;
        float bary[DB1]; unsigned long long pk[DB1];
        perm_embed<DB>(f, bary, pk);
        float w = 0.f; unsigned long long k = 0;
        #pragma unroll
        for (int r2 = 0; r2 < DB1; r2++)
            if (r2 == r) { w = bary[r2]; k = pk[r2]; }   // static idx -> regs
        wsv[idx] = w;
        os[idx] = hash_insert2(hkid, TBS - 1, k);
    } else if (idx < RB + RS) {
        int t = idx - RB;
        int ip = t / DS1;
        int r = t - ip * DS1;
        int x = ip % IMW, y = ip / IMW;
        float f[DS];
        f[0] = (float)x / 3.0f;
        f[1] = (float)y / 3.0f;
        float bary[DS1]; unsigned long long pk[DS1];
        perm_embed<DS>(f, bary, pk);
        float w = 0.f; unsigned long long k = 0;
        #pragma unroll
        for (int r2 = 0; r2 < DS1; r2++)
            if (r2 == r) { w = bary[r2]; k = pk[r2]; }
        int c0 = (int)(k & 0xFFFULL) - 2048;
        int c1 = (int)((k >> 12) & 0xFFFULL) - 2048;
        int gid = (c0 + C0OFF) * GS + (c1 + C1OFF);
        wsv[idx] = w;
        os[idx] = gid;
        pres[gid] = 1;              // benign same-value race, no atomic
    }
}

// hist over bilateral table only
__global__ void hist_b(const ulonglong2* __restrict__ hkid, int* hist) {
    int s = blockIdx.x * blockDim.x + threadIdx.x;
    if (s >= TBS) return;
    unsigned long long k = hkid[s].x;
    if (k == EMPTY_KEY) return;
    atomicAdd(&hist[key_code(k)], 1);
}

// ---------------- barrier-free scan machinery ----------------
__global__ void scan_wave_partial(const int* __restrict__ count, int* incl, int* wsum, int n) {
    int idx = blockIdx.x * blockDim.x + threadIdx.x;
    int lane = threadIdx.x & 63;
    int v = (idx < n) ? count[idx] : 0;
    int s = v;
    #pragma unroll
    for (int d = 1; d < 64; d <<= 1) {
        int t = __shfl_up(s, d);
        if (lane >= d) s += t;
    }
    if (idx < n) incl[idx] = s;
    if (lane == 63) wsum[idx >> 6] = s;
}

__global__ void scan_partials_excl(int* w, int nw, int* total_out) {
    __shared__ int sh[256];
    __shared__ int run;
    if (threadIdx.x == 0) run = 0;
    __syncthreads();
    for (int basei = 0; basei < nw; basei += 256) {
        int idx = basei + threadIdx.x;
        int v = (idx < nw) ? w[idx] : 0;
        sh[threadIdx.x] = v;
        __syncthreads();
        for (int d = 1; d < 256; d <<= 1) {
            int t = (threadIdx.x >= d) ? sh[threadIdx.x - d] : 0;
            __syncthreads();
            sh[threadIdx.x] += t;
            __syncthreads();
        }
        int total = sh[255];
        if (idx < nw) w[idx] = run + sh[threadIdx.x] - v;
        __syncthreads();
        if (threadIdx.x == 0) run += total;
        __syncthreads();
    }
    if (total_out != nullptr && threadIdx.x == 0) *total_out = run;
}

__global__ void scan_finalize(int* off, const int* __restrict__ count,
                              const int* __restrict__ wsum, int n) {
    int idx = blockIdx.x * blockDim.x + threadIdx.x;
    if (idx < n) off[idx] = off[idx] - count[idx] + wsum[idx >> 6];
}

// ---------------- bucket-sorted compaction (bilateral) ----------------
__global__ void assign_b(ulonglong2* hkid, const int* __restrict__ histOff,
                         int* histFill, unsigned long long* uk_b) {
    int s = blockIdx.x * blockDim.x + threadIdx.x;
    if (s >= TBS) return;
    unsigned long long k = hkid[s].x;
    if (k == EMPTY_KEY) return;
    int code = key_code(k);
    int id = histOff[code] + atomicAdd(&histFill[code], 1);
    hkid[s].y = (unsigned long long)id;
    uk_b[id] = k;
}

// spatial neighbors via dense grid reads — no hashing, no atomics.
__global__ void spatial_neighbors(const int* __restrict__ pres, const int* __restrict__ gid2id,
                                  int* __restrict__ n1s, int* __restrict__ n2s) {
    int gid = blockIdx.x * blockDim.x + threadIdx.x;
    if (gid >= GN) return;
    if (!pres[gid]) return;
    int id = gid2id[gid];
    const int d1[3] = {  2 * GS - 1, -GS + 2, -GS - 1 };
    const int d2[3] = { -2 * GS + 1,  GS - 2,  GS + 1 };
    #pragma unroll
    for (int j = 0; j < 3; j++) {
        int g1 = gid + d1[j], g2 = gid + d2[j];
        n1s[j * RS + id] = pres[g1] ? gid2id[g1] : -1;
        n2s[j * RS + id] = pres[g2] ? gid2id[g2] : -1;
    }
}

// unified os remap + cntr histogram + per-entry rank capture (wave-agg atomics).
__global__ void os_count_both(int* os, const ulonglong2* __restrict__ hkid,
                              const int* __restrict__ gid2id, int* cntr, int* rnk) {
    int i = blockIdx.x * blockDim.x + threadIdx.x;
    int lane = threadIdx.x & 63;
    int idg;
    if (i < RB) {
        int id = (int)hkid[os[i]].y;
        os[i] = id;
        idg = id;
    } else {
        int id = gid2id[os[i]];
        os[i] = id;
        idg = RB + id;
    }
    // 64-lane equal-id mask
    unsigned long long m = 0;
    #pragma unroll
    for (int l = 0; l < 64; l++) {
        int o = __shfl(idg, l);
        m |= (unsigned long long)(o == idg) << l;
    }
    int rless  = __popcll(m & ((1ULL << lane) - 1ULL));
    int leader = __ffsll(m) - 1;
    int gcnt   = __popcll(m);
    int base = 0;
    if (lane == leader) base = atomicAdd(&cntr[idg], gcnt);
    base = __shfl(base, leader);
    rnk[i] = base + rless;
}

// bilateral neighbors, (j,m) parallel; XCD-chunk swizzle for L2 locality.
__global__ void build_neighbors_b(const unsigned long long* __restrict__ uk,
                                  const ulonglong2* __restrict__ hkid,
                                  const int* cnt, int* n1, int* n2) {
    int Mb = cnt[0];
    int tot = DB1 * Mb;
    int nb = gridDim.x;                    // multiple of 8
    int bid = blockIdx.x;
    int swz = (bid & 7) * (nb >> 3) + (bid >> 3);
    int stride = nb * blockDim.x;
    for (int t = swz * blockDim.x + threadIdx.x; t < tot; t += stride) {
        int j = t / Mb, m = t - j * Mb;
        unsigned long long k = uk[m];
        unsigned long long p1 = 0, p2 = 0;
        #pragma unroll
        for (int i = 0; i < DB; i++) {
            int c = (int)((k >> (12 * i)) & 0xFFFULL) - 2048;
            int a = c + ((i == j) ? DB : -1);
            int b = c + ((i == j) ? -DB : 1);
            p1 |= ((unsigned long long)((unsigned)(a + 2048) & 0xFFFu)) << (12 * i);
            p2 |= ((unsigned long long)((unsigned)(b + 2048) & 0xFFFu)) << (12 * i);
        }
        n1[j * RB + m] = hash_lookup2(hkid, TBS - 1, p1);
        n2[j * RB + m] = hash_lookup2(hkid, TBS - 1, p2);
    }
}

// unified fill: pos derived from precomputed rank — NO atomics
__global__ void fill_both(const int* __restrict__ os, const float* __restrict__ wsv,
                          const int* __restrict__ off, const int* __restrict__ rnk,
                          unsigned* epw) {
    int idx = blockIdx.x * blockDim.x + threadIdx.x;
    if (idx >= RB + RS) return;
    int slot, pix;
    if (idx < RB) { slot = os[idx];        pix = idx / DB1; }
    else          { slot = RB + os[idx];   pix = (idx - RB) / DS1; }
    int pos = off[slot] + rnk[idx];
    epw[pos] = pack_ew(pix, wsv[idx]);
}

// ---------------- batched filter kernels (fp16 storage, fp32 math) ----------------
// r21: paired-lane gather — lanes 2k/2k+1 share a row, split entries by
// parity. Each lane reads WHOLE 48B Qh rows (sector rule); every entry is
// read exactly once across the pair; combine via shfl_xor; even lane writes.
// 2x TLP at r19's exact byte count.
__global__ void gather_both_h(const uint4* __restrict__ Qh4, const int* __restrict__ off,
                              const int* __restrict__ cntr, const unsigned* __restrict__ epw,
                              uint4* __restrict__ buf4, const int* cnt) {
    int Mb = cnt[0], Ms = cnt[1];
    int totB = Mb + 1;
    int totR = totB + Ms + 1;
    int tot2 = totR * 2;
    int stride = gridDim.x * blockDim.x;
    for (int idx = blockIdx.x * blockDim.x + threadIdx.x; idx < tot2; idx += stride) {
        int r = idx >> 1, ph = idx & 1;   // pair (2r,2r+1) is always lane-adjacent
        int orow, slot;
        if (r < totB) { orow = r; slot = r - 1; }
        else { int t = r - totB; orow = RB + 1 + t; slot = t ? (RB + t - 1) : -1; }
        float acc[24];
        #pragma unroll
        for (int t = 0; t < 24; t++) acc[t] = 0.f;
        if (slot >= 0) {
            int s = off[slot], e = s + cntr[slot];
            for (int t = s + ph; t < e; t += 2) {
                int pix; float w;
                unpack_ew(epw[t], pix, w);
                const uint4* q = Qh4 + (size_t)pix * 3;
                uint4 q0 = q[0], q1 = q[1], q2 = q[2];
                acc8(acc + 0,  w, q0);
                acc8(acc + 8,  w, q1);
                acc8(acc + 16, w, q2);
            }
        }
        #pragma unroll
        for (int t = 0; t < 24; t++) acc[t] += __shfl_xor(acc[t], 1);
        if (ph == 0) {
            size_t b = (size_t)orow * 3;
            #pragma unroll
            for (int t = 0; t < 3; t++) {
                uint2 lo = f2u(make_float4(acc[8*t+0], acc[8*t+1], acc[8*t+2], acc[8*t+3]));
                uint2 hi = f2u(make_float4(acc[8*t+4], acc[8*t+5], acc[8*t+6], acc[8*t+7]));
                buf4[b + t] = make_uint4(lo.x, lo.y, hi.x, hi.y);
            }
        }
    }
}

// 3 uint4-chunks per row — vectorized IO AND ~550K threads (TLP rule).
__global__ void blur_both_h(const uint4* __restrict__ in4, uint4* __restrict__ out4,
                            const int* __restrict__ n1b, const int* __restrict__ n2b,
                            const int* __restrict__ n1s, const int* __restrict__ n2s,
                            const int* cnt) {
    int Mb = cnt[0], Ms = cnt[1];
    int totB = (Mb + 1) * 3;
    int tot = totB + (Ms + 1) * 3;
    int stride = gridDim.x * blockDim.x;
    for (int idx = blockIdx.x * blockDim.x + threadIdx.x; idx < tot; idx += stride) {
        int r, c, orow, a1, a2;
        bool sink;
        if (idx < totB) {
            r = idx / 3; c = idx - r * 3;
            orow = r; sink = (r == 0);
            int m = r - 1;
            a1 = sink ? 0 : n1b[m] + 1;
            a2 = sink ? 0 : n2b[m] + 1;
        } else {
            int t = idx - totB;
            r = t / 3; c = t - r * 3;
            orow = RB + 1 + r; sink = (r == 0);
            int m = r - 1;
            a1 = sink ? 0 : RB + 2 + n1s[m];   // -1 -> sink RB+1
            a2 = sink ? 0 : RB + 2 + n2s[m];
        }
        size_t o = (size_t)orow * 3 + c;
        if (sink) { out4[o] = make_uint4(0u, 0u, 0u, 0u); continue; }
        out4[o] = blur8(in4[o], in4[(size_t)a1 * 3 + c], in4[(size_t)a2 * 3 + c]);
    }
}

__global__ void blur_b_h(const uint4* __restrict__ in4, uint4* __restrict__ out4,
                         const int* __restrict__ n1, const int* __restrict__ n2,
                         const int* cnt) {
    int M = cnt[0];
    int tot = (M + 1) * 3;
    int stride = gridDim.x * blockDim.x;
    for (int idx = blockIdx.x * blockDim.x + threadIdx.x; idx < tot; idx += stride) {
        int r = idx / 3, c = idx - r * 3;
        size_t o = (size_t)r * 3 + c;
        if (r == 0) { out4[o] = make_uint4(0u, 0u, 0u, 0u); continue; }
        int m = r - 1;
        out4[o] = blur8(in4[o], in4[(size_t)(n1[m] + 1) * 3 + c],
                        in4[(size_t)(n2[m] + 1) * 3 + c]);
    }
}

// ---- fp32 norm-chain versions (per-row threads) ----
__global__ void gather1_both(const int* __restrict__ off, const int* __restrict__ cntr,
                             const unsigned* __restrict__ epw, float* __restrict__ buf,
                             const int* cnt) {
    int Mb = cnt[0], Ms = cnt[1];
    int totB = Mb + 1;
    int tot = totB + Ms + 1;
    int stride = gridDim.x * blockDim.x;
    for (int r = blockIdx.x * blockDim.x + threadIdx.x; r < tot; r += stride) {
        int o, slot;
        if (r < totB) { o = r;              slot = r ? (r - 1) : -1; }
        else          { int t = r - totB; o = RB + 1 + t; slot = t ? (RB + t - 1) : -1; }
        float acc = 0.f;
        if (slot >= 0) {
            int s = off[slot], e = s + cntr[slot];
            for (int t = s; t < e; t++) acc += (float)(epw[t] >> 17) * (1.0f / 32767.0f);
        }
        buf[o] = acc;
    }
}

__global__ void blur1_both(const float* __restrict__ in, float* __restrict__ out,
                           const int* __restrict__ n1b, const int* __restrict__ n2b,
                           const int* __restrict__ n1s, const int* __restrict__ n2s,
                           const int* cnt) {
    int Mb = cnt[0], Ms = cnt[1];
    int totB = Mb + 1;
    int tot = totB + Ms + 1;
    int stride = gridDim.x * blockDim.x;
    for (int r = blockIdx.x * blockDim.x + threadIdx.x; r < tot; r += stride) {
        if (r < totB) {
            if (r == 0) { out[0] = 0.f; continue; }
            int m = r - 1;
            out[r] = in[r] + 0.5f * (in[n1b[m] + 1] + in[n2b[m] + 1]);
        } else {
            int t = r - totB;
            int o = RB + 1 + t;
            if (t == 0) { out[o] = 0.f; continue; }
            int m = t - 1;
            out[o] = in[o] + 0.5f * (in[RB + 2 + n1s[m]] + in[RB + 2 + n2s[m]]);
        }
    }
}

__global__ void blur1_b(const float* __restrict__ in, float* __restrict__ out,
                        const int* __restrict__ n1, const int* __restrict__ n2,
                        const int* cnt) {
    int M = cnt[0];
    int stride = gridDim.x * blockDim.x;
    for (int row = blockIdx.x * blockDim.x + threadIdx.x; row <= M; row += stride) {
        if (row == 0) { out[0] = 0.f; continue; }
        int m = row - 1;
        out[row] = in[row] + 0.5f * (in[n1[m] + 1] + in[n2[m] + 1]);
    }
}

// both norms in one pass (bilateral final in bufB, spatial final in bufS)
__global__ void slice_norm_both(const float* __restrict__ bufB, const float* __restrict__ bufS,
                                const int* __restrict__ osw, const float* __restrict__ wsv,
                                float* __restrict__ nbv, float* __restrict__ nsv,
                                float alphaB, float alphaS) {
    int i = blockIdx.x * blockDim.x + threadIdx.x;
    if (i >= NPIX) return;
    float sb = 0.f;
    #pragma unroll
    for (int r = 0; r < DB1; r++)
        sb += wsv[i * DB1 + r] * bufB[osw[i * DB1 + r] + 1];
    float ss = 0.f;
    #pragma unroll
    for (int r = 0; r < DS1; r++)
        ss += wsv[RB + i * DS1 + r] * bufS[RB + 2 + osw[RB + i * DS1 + r]];
    nbv[i] = alphaB * sb + 1e-20f;
    nsv[i] = alphaS * ss + 1e-20f;
}

// fused: slice(bilateral)+slice(spatial)+normalize+softmax -> Q (fp32) + Qh (fp16)
__global__ void slice_update(const float* __restrict__ U,
                             const uint4* __restrict__ bufB4, const uint4* __restrict__ bufS4,
                             const int* __restrict__ osw, const float* __restrict__ wsv,
                             const float* __restrict__ nbv, const float* __restrict__ nsv,
                             float* __restrict__ Q, uint4* __restrict__ Qh4,
                             float alphaB, float alphaS, int use_msg) {
    int i = blockIdx.x * blockDim.x + threadIdx.x;
    if (i >= NPIX) return;
    float msg[24];
    #pragma unroll
    for (int t = 0; t < 24; t++) msg[t] = 0.f;
    if (use_msg) {
        float ib = 10.0f * alphaB / nbv[i];
        float is = 3.0f * alphaS / nsv[i];
        #pragma unroll
        for (int r = 0; r < DB1; r++) {
            float w = ib * wsv[i * DB1 + r];
            size_t base = (size_t)(osw[i * DB1 + r] + 1) * 3;
            uint4 q0 = bufB4[base], q1 = bufB4[base + 1], q2 = bufB4[base + 2];
            acc8(msg + 0,  w, q0);
            acc8(msg + 8,  w, q1);
            acc8(msg + 16, w, q2);
        }
        #pragma unroll
        for (int r = 0; r < DS1; r++) {
            float w = is * wsv[RB + i * DS1 + r];
            size_t base = (size_t)(RB + 2 + osw[RB + i * DS1 + r]) * 3;
            uint4 q0 = bufS4[base], q1 = bufS4[base + 1], q2 = bufS4[base + 2];
            acc8(msg + 0,  w, q0);
            acc8(msg + 8,  w, q1);
            acc8(msg + 16, w, q2);
        }
    }
    float mx = -1e30f;
    #pragma unroll
    for (int c = 0; c < NC; c++) {
        msg[c] = -U[i * NC + c] + msg[c];
        mx = fmaxf(mx, msg[c]);
    }
    float s = 0.f;
    #pragma unroll
    for (int c = 0; c < NC; c++) { float e = expf(msg[c] - mx); msg[c] = e; s += e; }
    float inv = 1.0f / s;
    #pragma unroll
    for (int c = 0; c < NC; c++) {
        msg[c] *= inv;
        Q[i * NC + c] = msg[c];
    }
    msg[21] = 0.f; msg[22] = 0.f; msg[23] = 0.f;
    #pragma unroll
    for (int t = 0; t < 3; t++) {
        uint2 lo = f2u(make_float4(msg[8*t+0], msg[8*t+1], msg[8*t+2], msg[8*t+3]));
        uint2 hi = f2u(make_float4(msg[8*t+4], msg[8*t+5], msg[8*t+6], msg[8*t+7]));
        Qh4[i * 3 + t] = make_uint4(lo.x, lo.y, hi.x, hi.y);
    }
}

// ---------------- host orchestration ----------------
extern "C" void kernel_launch(void* const* d_in, const int* in_sizes, int n_in,
                              void* d_out, int out_size, void* d_ws, size_t ws_size,
                              hipStream_t stream) {
    const float* U     = (const float*)d_in[0];
    const float* image = (const float*)d_in[1];
    float* Q = (float*)d_out;

    char* base = (char*)d_ws;
    size_t off = 0;
    auto alloc = [&](size_t bytes) -> void* {
        off = (off + 255) & ~(size_t)255;
        void* p = base + off; off += bytes; return p;
    };
    // unified per-entry arrays: [0,RB) bilateral, [RB,RB+RS) spatial
    int*   osw  = (int*)  alloc((size_t)(RB + RS) * 4);
    float* wsv  = (float*)alloc((size_t)(RB + RS) * 4);
    int*   rnk  = (int*)  alloc((size_t)(RB + RS) * 4);
    int*   n1_b = (int*)  alloc((size_t)DB1 * RB * 4);
    int*   n2_b = (int*)  alloc((size_t)DB1 * RB * 4);
    int*   n1_s = (int*)  alloc((size_t)DS1 * RS * 4);
    int*   n2_s = (int*)  alloc((size_t)DS1 * RS * 4);
    unsigned long long* uk_b = (unsigned long long*)alloc((size_t)RB * 8);
    ulonglong2* hkid = (ulonglong2*)alloc((size_t)TBS * 16);
    int*   gid2id = (int*)alloc((size_t)GN * 4);
    int*   cnt  = (int*)  alloc(256);   // [0]=M_b, [1]=M_s
    int*   histOff = (int*)alloc((size_t)NBUCK * 4);
    int*   wsums   = (int*)alloc((size_t)64 * 1024 * 4);
    int*   wsI     = (int*)alloc((size_t)16384 * 4);   // level-1 inclusive sums
    int*   ws2     = (int*)alloc((size_t)1024 * 4);    // level-2 sums
    int*   offv    = (int*)alloc((size_t)(RB + RS) * 4);
    // contiguous zero region: cntr | hist | histFill | pres
    char*  zreg  = (char*)alloc((size_t)(RB + RS) * 4 + (size_t)NBUCK * 8 + (size_t)GN * 4);
    int*   cntr     = (int*)zreg;
    int*   hist     = cntr + (RB + RS);
    int*   histFill = hist + NBUCK;
    int*   pres     = histFill + NBUCK;
    size_t zbytes = (size_t)(RB + RS) * 4 + (size_t)NBUCK * 8 + (size_t)GN * 4;
    unsigned* epw = (unsigned*)alloc((size_t)(RB + RS) * 4);   // packed 4B entries
    float* norm_b = (float*)alloc((size_t)NPIX * 4);
    float* norm_s = (float*)alloc((size_t)NPIX * 4);
    uint2* Qh   = (uint2*)alloc((size_t)NPIX * CP4 * 8);
    // combined lattice buffers: rows RB+RS+2 (bilateral [0,RB], spatial [RB+1,...])
    uint2* buf0 = (uint2*)alloc((size_t)(RB + RS + 2) * CP4 * 8);
    uint2* buf1 = (uint2*)alloc((size_t)(RB + RS + 2) * CP4 * 8);
    float* nbuf0 = (float*)alloc((size_t)(RB + RS + 2) * 4);
    float* nbuf1 = (float*)alloc((size_t)(RB + RS + 2) * 4);
    if (off > ws_size) return;

    const float ALPHA_B = (float)(1.0 / (1.0 + exp2(-(double)DB)));  // 32/33
    const float ALPHA_S = (float)(1.0 / (1.0 + exp2(-(double)DS)));  // 4/5

    constexpr int PGR = 2048;   // gather/blur grids (grid-stride)

    // ---- 3 memsets ----
    hipMemsetAsync(cnt, 0, 16, stream);
    hipMemsetAsync(hkid, 0xFF, (size_t)TBS * 16, stream);
    hipMemsetAsync(zreg, 0, zbytes, stream);

    // ---- build both lattices ----
    build_both<<<(RB + RS) / 256, 256, 0, stream>>>(image, hkid, osw, wsv, pres);
    // bilateral compaction (bucket-sorted ids)
    hist_b<<<TBS / 256, 256, 0, stream>>>(hkid, hist);
    scan_wave_partial<<<NBUCK / 256, 256, 0, stream>>>(hist, histOff, wsums, NBUCK);
    scan_partials_excl<<<1, 256, 0, stream>>>(wsums, NBUCK / 64, cnt + 0);
    scan_finalize<<<NBUCK / 256, 256, 0, stream>>>(histOff, hist, wsums, NBUCK);
    assign_b<<<TBS / 256, 256, 0, stream>>>(hkid, histOff, histFill, uk_b);
    // spatial compaction (dense grid presence scan; ids row-major in (c0,c1))
    scan_wave_partial<<<GN / 256, 256, 0, stream>>>(pres, gid2id, wsums, GN);
    scan_partials_excl<<<1, 256, 0, stream>>>(wsums, GN / 64, cnt + 1);
    scan_finalize<<<GN / 256, 256, 0, stream>>>(gid2id, pres, wsums, GN);
    spatial_neighbors<<<GN / 256, 256, 0, stream>>>(pres, gid2id, n1_s, n2_s);
    os_count_both<<<(RB + RS) / 256, 256, 0, stream>>>(osw, hkid, gid2id, cntr, rnk);
    build_neighbors_b<<<2048, 256, 0, stream>>>(uk_b, hkid, cnt + 0, n1_b, n2_b);
    // unified offset scan over RB+RS id slots — hierarchical
    scan_wave_partial<<<(RB + RS) / 256, 256, 0, stream>>>(cntr, offv, wsums, RB + RS);
    scan_wave_partial<<<(NW1 + 255) / 256, 256, 0, stream>>>(wsums, wsI, ws2, NW1);
    scan_partials_excl<<<1, 256, 0, stream>>>(ws2, (NW1 + 63) / 64, nullptr);
    scan_finalize<<<(NW1 + 255) / 256, 256, 0, stream>>>(wsI, wsums, ws2, NW1);
    scan_finalize<<<(RB + RS) / 256, 256, 0, stream>>>(offv, cntr, wsI, RB + RS);
    fill_both<<<(RB + RS + 255) / 256, 256, 0, stream>>>(osw, wsv, offv, rnk, epw);

    // ---- norm filters (C=1, fp32), batched ----
    {
        gather1_both<<<1024, 256, 0, stream>>>(offv, cntr, epw, nbuf0, cnt);
        float* a = nbuf0; float* b = nbuf1;
        for (int j = 0; j < DS1; j++) {   // j=0..2: both chains
            blur1_both<<<1024, 256, 0, stream>>>(a, b,
                n1_b + (size_t)j * RB, n2_b + (size_t)j * RB,
                n1_s + (size_t)j * RS, n2_s + (size_t)j * RS, cnt);
            float* t = a; a = b; b = t;
        }
        // j=3..5: bilateral only — writes only rows [0,Mb]; spatial final stays in nbuf1.
        for (int j = DS1; j < DB1; j++) {
            blur1_b<<<1024, 256, 0, stream>>>(a, b, n1_b + (size_t)j * RB, n2_b + (size_t)j * RB, cnt);
            float* t = a; a = b; b = t;
        }
        // bilateral final in nbuf0 (6 swaps), spatial final in nbuf1 (3 swaps)
        slice_norm_both<<<(NPIX + 255) / 256, 256, 0, stream>>>(
            nbuf0, nbuf1, osw, wsv, norm_b, norm_s, ALPHA_B, ALPHA_S);
    }

    // ---- Q0 = softmax(-U) ----
    slice_update<<<(NPIX + 255) / 256, 256, 0, stream>>>(
        U, (const uint4*)buf0, (const uint4*)buf1, osw, wsv, norm_b, norm_s,
        Q, (uint4*)Qh, ALPHA_B, ALPHA_S, 0);

    // ---- 5 mean-field iterations ----
    for (int it = 0; it < 5; it++) {
        gather_both_h<<<PGR, 256, 0, stream>>>((const uint4*)Qh, offv, cntr, epw,
                                               (uint4*)buf0, cnt);
        uint2* a = buf0; uint2* b = buf1;
        for (int j = 0; j < DS1; j++) {   // j=0..2: both chains in one launch
            blur_both_h<<<PGR, 256, 0, stream>>>((const uint4*)a, (uint4*)b,
                n1_b + (size_t)j * RB, n2_b + (size_t)j * RB,
                n1_s + (size_t)j * RS, n2_s + (size_t)j * RS, cnt);
            uint2* t = a; a = b; b = t;
        }
        for (int j = DS1; j < DB1; j++) { // j=3..5: bilateral only
            blur_b_h<<<PGR, 256, 0, stream>>>((const uint4*)a, (uint4*)b,
                n1_b + (size_t)j * RB, n2_b + (size_t)j * RB, cnt);
            uint2* t = a; a = b; b = t;
        }
        // bilateral final in buf0, spatial final in buf1
        slice_update<<<(NPIX + 255) / 256, 256, 0, stream>>>(
            U, (const uint4*)buf0, (const uint4*)buf1, osw, wsv, norm_b, norm_s,
            Q, (uint4*)Qh, ALPHA_B, ALPHA_S, 1);
    }
}

// Round 7
// 758.555 us; speedup vs baseline: 1.1957x; 1.0903x over previous
//
#include <hip/hip_runtime.h>
#include <hip/hip_fp16.h>
#include <cmath>

// ---------------- problem constants ----------------
constexpr int IMH = 320, IMW = 320, NPIX = IMH * IMW, NC = 21;
constexpr int CP4 = 6;           // padded channels / 4  (24 values per row)
constexpr int DB = 5, DB1 = 6;   // bilateral lattice dim
constexpr int DS = 2, DS1 = 3;   // spatial lattice dim
constexpr int RB = NPIX * DB1;   // splat entries (bilateral) = 614400
constexpr int RS = NPIX * DS1;   // (spatial) = 307200
constexpr int TBS = 1 << 19;     // hash table slots (bilateral only)
constexpr int NBUCK = 1 << 16;   // bilateral sort buckets (c0,c1 low bytes)
constexpr int NW1 = (RB + RS) / 64;  // wave sums in the unified offset scan
// spatial dense grid: lattice coords are deterministic in (x,y) only.
// c0 in [-8, 298], c1 in [-194, 115]  ->  512x512 grid with offsets below.
constexpr int GS = 512, GN = GS * GS;
constexpr int C0OFF = 16, C1OFF = 200;

// Combined lattice-value buffer layout (static partition):
//   bilateral: row 0 = sink, point m -> row m+1           (rows [0, RB])
//   spatial:   row RB+1 = sink, point m -> row RB+2+m     (rows [RB+1, ...])
// spatial neighbor n=-1 maps to RB+2+(-1) = RB+1 = sink automatically.

// LESSONS (measured):
// r12-r14: hist fused into CAS loop = +45us; test-before-CAS = +8us/+36MB
//   FETCH; 4B epw packing does NOT cut scatter WRITE (64B sectors rule).
// r15: fill's atomicAdd removed via ranks captured in os_count.
// r16: ATOMIC-THROUGHPUT-BOUND build: WRITE_SIZE = count x 64B sectors,
//   ~16-19G atomics/s ceiling. Only fewer atomics help.
// r17: spatial lattice -> dense 512x512 grid (no atomics).
// r18: wave-agg os_count atomics OK; blur row-per-thread REGRESSED: <200K
//   threads is latency-starved. TLP rule: >=400K threads for scattered krns.
// r19: merged 16B {key,id} table, 6x parallel neighbor build, blur
//   3-chunk: 921->861us. fillBufferAligned = harness ws poison (256MiB).
// r20: REGRESSED 861->907. gather 3-chunk split: FETCH 25.7->68MB —
//   SECTOR RULE beats TLP rule: a thread must consume WHOLE 48B rows.
//   Fused 9-pt blur: no win in L2-miss regime.
// r21: paired-lane gather (entry-parity split, full-row reads, shfl_xor
//   combine): 907->827us (best). No single kernel >42us left.
// r22 (this round): XCD chunked swizzle (T1) on gather/blur/slice_update.
//   Active lattice set ~8.6MB (180K rows x 48B) vs 4MB per-XCD L2;
//   bucket-sorted ids put blur neighbors within +-150KB of self. Chunked
//   swizzle gives each XCD two contiguous ~1MB windows -> neighbor reads
//   become XCD-local L2 hits. Pure index remap, no semantic change.

#define EMPTY_KEY 0xFFFFFFFFFFFFFFFFULL

__device__ __forceinline__ unsigned long long mix64(unsigned long long x) {
    x ^= x >> 33; x *= 0xff51afd7ed558ccdULL;
    x ^= x >> 33; x *= 0xc4ceb9fe1a85ec53ULL;
    x ^= x >> 33; return x;
}

// fp16 pack helpers: uint2 = 4 halves; math in fp32, storage fp16.
__device__ __forceinline__ float4 u2f(uint2 u) {
    __half2 a = *reinterpret_cast<__half2*>(&u.x);
    __half2 b = *reinterpret_cast<__half2*>(&u.y);
    float2 fa = __half22float2(a), fb = __half22float2(b);
    return make_float4(fa.x, fa.y, fb.x, fb.y);
}
__device__ __forceinline__ uint2 f2u(float4 v) {
    __half2 a = __floats2half2_rn(v.x, v.y);
    __half2 b = __floats2half2_rn(v.z, v.w);
    uint2 u;
    u.x = *reinterpret_cast<unsigned*>(&a);
    u.y = *reinterpret_cast<unsigned*>(&b);
    return u;
}

__device__ __forceinline__ unsigned pack_ew(int pix, float w) {
    int w15 = (int)lrintf(fminf(fmaxf(w, 0.f), 1.f) * 32767.f);
    return ((unsigned)w15 << 17) | (unsigned)pix;
}
__device__ __forceinline__ void unpack_ew(unsigned e, int& pix, float& w) {
    pix = (int)(e & 0x1FFFFu);
    w = (float)(e >> 17) * (1.0f / 32767.0f);
}

// accumulate 8 fp16 channels (one uint4) into acc[0..7] with weight w.
__device__ __forceinline__ void acc8(float* acc, float w, uint4 q) {
    float4 v = u2f(make_uint2(q.x, q.y));
    acc[0] += w * v.x; acc[1] += w * v.y; acc[2] += w * v.z; acc[3] += w * v.w;
    v = u2f(make_uint2(q.z, q.w));
    acc[4] += w * v.x; acc[5] += w * v.y; acc[6] += w * v.z; acc[7] += w * v.w;
}

// blur core on one uint4 (8 fp16 channels): x + 0.5*(a+b), f32 math.
__device__ __forceinline__ uint4 blur8(uint4 xs, uint4 xa, uint4 xb) {
    float4 s0 = u2f(make_uint2(xs.x, xs.y)), s1 = u2f(make_uint2(xs.z, xs.w));
    float4 a0 = u2f(make_uint2(xa.x, xa.y)), a1 = u2f(make_uint2(xa.z, xa.w));
    float4 b0 = u2f(make_uint2(xb.x, xb.y)), b1 = u2f(make_uint2(xb.z, xb.w));
    s0.x += 0.5f * (a0.x + b0.x); s0.y += 0.5f * (a0.y + b0.y);
    s0.z += 0.5f * (a0.z + b0.z); s0.w += 0.5f * (a0.w + b0.w);
    s1.x += 0.5f * (a1.x + b1.x); s1.y += 0.5f * (a1.y + b1.y);
    s1.z += 0.5f * (a1.z + b1.z); s1.w += 0.5f * (a1.w + b1.w);
    uint2 lo = f2u(s0), hi = f2u(s1);
    return make_uint4(lo.x, lo.y, hi.x, hi.y);
}

// chunked XCD swizzle: block bid -> swb so blocks on one XCD are contiguous.
// requires gridDim.x % 8 == 0 (bijective).
__device__ __forceinline__ int swz8(int bid, int nb) {
    return (bid & 7) * (nb >> 3) + (bid >> 3);
}

// ---------------- permutohedral embedding (matches reference op-for-op, f32) ----------------
template<int D>
__device__ void perm_embed(const float* f, float* bary, unsigned long long* pk) {
    constexpr int D1 = D + 1;
    float cf[D];
    #pragma unroll
    for (int i = 0; i < D; i++) {
        double s = sqrt(2.0 / 3.0) * (double)D1 / sqrt((double)((i + 1) * (i + 2)));
        cf[i] = f[i] * (float)s;
    }
    float csum[D];
    float acc = 0.f;
    #pragma unroll
    for (int i = D - 1; i >= 0; i--) { acc += cf[i]; csum[i] = acc; }
    float el[D1];
    el[0] = csum[0];
    #pragma unroll
    for (int i = 1; i < D; i++) el[i] = csum[i] - (float)i * cf[i - 1];
    el[D] = -(float)D * cf[D - 1];
    const float down = 1.0f / (float)D1;
    float rem0[D1]; int rank[D1]; int ssum = 0;
    #pragma unroll
    for (int i = 0; i < D1; i++) {
        float rd = rintf(el[i] * down);
        rem0[i] = rd * (float)D1;
        ssum += (int)rd;
    }
    float diff[D1];
    #pragma unroll
    for (int i = 0; i < D1; i++) diff[i] = el[i] - rem0[i];
    #pragma unroll
    for (int i = 0; i < D1; i++) {
        int r = 0;
        #pragma unroll
        for (int j = 0; j < D1; j++)
            r += (diff[j] > diff[i]) || ((diff[j] == diff[i]) && (j < i));
        rank[i] = r + ssum;
    }
    #pragma unroll
    for (int i = 0; i < D1; i++) {
        if (rank[i] < 0)      { rank[i] += D1; rem0[i] += (float)D1; }
        else if (rank[i] > D) { rank[i] -= D1; rem0[i] -= (float)D1; }
    }
    float b[D + 2];
    #pragma unroll
    for (int i = 0; i < D + 2; i++) b[i] = 0.f;
    #pragma unroll
    for (int i = 0; i < D1; i++) b[D - rank[i]]     += (el[i] - rem0[i]) * down;
    #pragma unroll
    for (int i = 0; i < D1; i++) b[D + 1 - rank[i]] -= (el[i] - rem0[i]) * down;
    b[0] += 1.0f + b[D + 1];
    #pragma unroll
    for (int i = 0; i < D1; i++) bary[i] = b[i];
    int key0[D];
    #pragma unroll
    for (int i = 0; i < D; i++) key0[i] = (int)rintf(rem0[i]);
    #pragma unroll
    for (int r = 0; r < D1; r++) {
        unsigned long long p = 0;
        #pragma unroll
        for (int i = 0; i < D; i++) {
            int c = key0[i] + ((rank[i] < D1 - r) ? r : r - D1);
            p |= ((unsigned long long)((unsigned)(c + 2048) & 0xFFFu)) << (12 * i);
        }
        pk[r] = p;
    }
}

__device__ __forceinline__ int key_code(unsigned long long k) {
    int c0 = (int)(k & 0xFFFULL);
    int c1 = (int)((k >> 12) & 0xFFFULL);
    return ((c0 & 0xFF) << 8) | (c1 & 0xFF);
}

// ---------------- merged {key,id} hash table (16B entries) ----------------
__device__ __forceinline__ int hash_insert2(ulonglong2* hkid, int tmask, unsigned long long k) {
    int slot = (int)(mix64(k) & (unsigned long long)tmask);
    while (true) {
        unsigned long long prev = atomicCAS(&hkid[slot].x, EMPTY_KEY, k);
        if (prev == EMPTY_KEY || prev == k) return slot;
        slot = (slot + 1) & tmask;
    }
}
// one 16B load per probe: key match delivers id in the same transaction.
__device__ __forceinline__ int hash_lookup2(const ulonglong2* __restrict__ hkid,
                                            int tmask, unsigned long long k) {
    int slot = (int)(mix64(k) & (unsigned long long)tmask);
    while (true) {
        ulonglong2 e = hkid[slot];
        if (e.x == k) return (int)e.y;
        if (e.x == EMPTY_KEY) return -1;
        slot = (slot + 1) & tmask;
    }
}

// ---------------- build kernels ----------------
__global__ void build_both(const float* __restrict__ image, ulonglong2* hkid,
                           int* os, float* wsv, int* pres) {
    int idx = blockIdx.x * blockDim.x + threadIdx.x;
    if (idx < RB) {
        int i = idx / DB1;          // pixel
        int r = idx - i * DB1;      // simplex vertex rank
        int x = i % IMW, y = i / IMW;
        float f[DB];
        f[0] = (float)x / 80.0f;
        f[1] = (float)y / 80.0f;
        f[2] = image[i * 3 + 0] / 13.0f;
        f[3] = image[i * 3 + 1] / 13.0f;
        f[4] = image[i * 3 + 2] / 13.0f;
        float bary[DB1]; unsigned long long pk[DB1];
        perm_embed<DB>(f, bary, pk);
        float w = 0.f; unsigned long long k = 0;
        #pragma unroll
        for (int r2 = 0; r2 < DB1; r2++)
            if (r2 == r) { w = bary[r2]; k = pk[r2]; }   // static idx -> regs
        wsv[idx] = w;
        os[idx] = hash_insert2(hkid, TBS - 1, k);
    } else if (idx < RB + RS) {
        int t = idx - RB;
        int ip = t / DS1;
        int r = t - ip * DS1;
        int x = ip % IMW, y = ip / IMW;
        float f[DS];
        f[0] = (float)x / 3.0f;
        f[1] = (float)y / 3.0f;
        float bary[DS1]; unsigned long long pk[DS1];
        perm_embed<DS>(f, bary, pk);
        float w = 0.f; unsigned long long k = 0;
        #pragma unroll
        for (int r2 = 0; r2 < DS1; r2++)
            if (r2 == r) { w = bary[r2]; k = pk[r2]; }
        int c0 = (int)(k & 0xFFFULL) - 2048;
        int c1 = (int)((k >> 12) & 0xFFFULL) - 2048;
        int gid = (c0 + C0OFF) * GS + (c1 + C1OFF);
        wsv[idx] = w;
        os[idx] = gid;
        pres[gid] = 1;              // benign same-value race, no atomic
    }
}

// hist over bilateral table only
__global__ void hist_b(const ulonglong2* __restrict__ hkid, int* hist) {
    int s = blockIdx.x * blockDim.x + threadIdx.x;
    if (s >= TBS) return;
    unsigned long long k = hkid[s].x;
    if (k == EMPTY_KEY) return;
    atomicAdd(&hist[key_code(k)], 1);
}

// ---------------- barrier-free scan machinery ----------------
__global__ void scan_wave_partial(const int* __restrict__ count, int* incl, int* wsum, int n) {
    int idx = blockIdx.x * blockDim.x + threadIdx.x;
    int lane = threadIdx.x & 63;
    int v = (idx < n) ? count[idx] : 0;
    int s = v;
    #pragma unroll
    for (int d = 1; d < 64; d <<= 1) {
        int t = __shfl_up(s, d);
        if (lane >= d) s += t;
    }
    if (idx < n) incl[idx] = s;
    if (lane == 63) wsum[idx >> 6] = s;
}

__global__ void scan_partials_excl(int* w, int nw, int* total_out) {
    __shared__ int sh[256];
    __shared__ int run;
    if (threadIdx.x == 0) run = 0;
    __syncthreads();
    for (int basei = 0; basei < nw; basei += 256) {
        int idx = basei + threadIdx.x;
        int v = (idx < nw) ? w[idx] : 0;
        sh[threadIdx.x] = v;
        __syncthreads();
        for (int d = 1; d < 256; d <<= 1) {
            int t = (threadIdx.x >= d) ? sh[threadIdx.x - d] : 0;
            __syncthreads();
            sh[threadIdx.x] += t;
            __syncthreads();
        }
        int total = sh[255];
        if (idx < nw) w[idx] = run + sh[threadIdx.x] - v;
        __syncthreads();
        if (threadIdx.x == 0) run += total;
        __syncthreads();
    }
    if (total_out != nullptr && threadIdx.x == 0) *total_out = run;
}

__global__ void scan_finalize(int* off, const int* __restrict__ count,
                              const int* __restrict__ wsum, int n) {
    int idx = blockIdx.x * blockDim.x + threadIdx.x;
    if (idx < n) off[idx] = off[idx] - count[idx] + wsum[idx >> 6];
}

// ---------------- bucket-sorted compaction (bilateral) ----------------
__global__ void assign_b(ulonglong2* hkid, const int* __restrict__ histOff,
                         int* histFill, unsigned long long* uk_b) {
    int s = blockIdx.x * blockDim.x + threadIdx.x;
    if (s >= TBS) return;
    unsigned long long k = hkid[s].x;
    if (k == EMPTY_KEY) return;
    int code = key_code(k);
    int id = histOff[code] + atomicAdd(&histFill[code], 1);
    hkid[s].y = (unsigned long long)id;
    uk_b[id] = k;
}

// spatial neighbors via dense grid reads — no hashing, no atomics.
__global__ void spatial_neighbors(const int* __restrict__ pres, const int* __restrict__ gid2id,
                                  int* __restrict__ n1s, int* __restrict__ n2s) {
    int gid = blockIdx.x * blockDim.x + threadIdx.x;
    if (gid >= GN) return;
    if (!pres[gid]) return;
    int id = gid2id[gid];
    const int d1[3] = {  2 * GS - 1, -GS + 2, -GS - 1 };
    const int d2[3] = { -2 * GS + 1,  GS - 2,  GS + 1 };
    #pragma unroll
    for (int j = 0; j < 3; j++) {
        int g1 = gid + d1[j], g2 = gid + d2[j];
        n1s[j * RS + id] = pres[g1] ? gid2id[g1] : -1;
        n2s[j * RS + id] = pres[g2] ? gid2id[g2] : -1;
    }
}

// unified os remap + cntr histogram + per-entry rank capture (wave-agg atomics).
__global__ void os_count_both(int* os, const ulonglong2* __restrict__ hkid,
                              const int* __restrict__ gid2id, int* cntr, int* rnk) {
    int i = blockIdx.x * blockDim.x + threadIdx.x;
    int lane = threadIdx.x & 63;
    int idg;
    if (i < RB) {
        int id = (int)hkid[os[i]].y;
        os[i] = id;
        idg = id;
    } else {
        int id = gid2id[os[i]];
        os[i] = id;
        idg = RB + id;
    }
    // 64-lane equal-id mask
    unsigned long long m = 0;
    #pragma unroll
    for (int l = 0; l < 64; l++) {
        int o = __shfl(idg, l);
        m |= (unsigned long long)(o == idg) << l;
    }
    int rless  = __popcll(m & ((1ULL << lane) - 1ULL));
    int leader = __ffsll(m) - 1;
    int gcnt   = __popcll(m);
    int base = 0;
    if (lane == leader) base = atomicAdd(&cntr[idg], gcnt);
    base = __shfl(base, leader);
    rnk[i] = base + rless;
}

// bilateral neighbors, (j,m) parallel; XCD-chunk swizzle for L2 locality.
__global__ void build_neighbors_b(const unsigned long long* __restrict__ uk,
                                  const ulonglong2* __restrict__ hkid,
                                  const int* cnt, int* n1, int* n2) {
    int Mb = cnt[0];
    int tot = DB1 * Mb;
    int nb = gridDim.x;                    // multiple of 8
    int swb = swz8(blockIdx.x, nb);
    int stride = nb * blockDim.x;
    for (int t = swb * blockDim.x + threadIdx.x; t < tot; t += stride) {
        int j = t / Mb, m = t - j * Mb;
        unsigned long long k = uk[m];
        unsigned long long p1 = 0, p2 = 0;
        #pragma unroll
        for (int i = 0; i < DB; i++) {
            int c = (int)((k >> (12 * i)) & 0xFFFULL) - 2048;
            int a = c + ((i == j) ? DB : -1);
            int b = c + ((i == j) ? -DB : 1);
            p1 |= ((unsigned long long)((unsigned)(a + 2048) & 0xFFFu)) << (12 * i);
            p2 |= ((unsigned long long)((unsigned)(b + 2048) & 0xFFFu)) << (12 * i);
        }
        n1[j * RB + m] = hash_lookup2(hkid, TBS - 1, p1);
        n2[j * RB + m] = hash_lookup2(hkid, TBS - 1, p2);
    }
}

// unified fill: pos derived from precomputed rank — NO atomics
__global__ void fill_both(const int* __restrict__ os, const float* __restrict__ wsv,
                          const int* __restrict__ off, const int* __restrict__ rnk,
                          unsigned* epw) {
    int idx = blockIdx.x * blockDim.x + threadIdx.x;
    if (idx >= RB + RS) return;
    int slot, pix;
    if (idx < RB) { slot = os[idx];        pix = idx / DB1; }
    else          { slot = RB + os[idx];   pix = (idx - RB) / DS1; }
    int pos = off[slot] + rnk[idx];
    epw[pos] = pack_ew(pix, wsv[idx]);
}

// ---------------- batched filter kernels (fp16 storage, fp32 math) ----------------
// r21 paired-lane gather + r22 XCD swizzle. Pairing: idx parity == lane
// parity (block-contiguous layout preserved under swizzled grid-stride).
__global__ void gather_both_h(const uint4* __restrict__ Qh4, const int* __restrict__ off,
                              const int* __restrict__ cntr, const unsigned* __restrict__ epw,
                              uint4* __restrict__ buf4, const int* cnt) {
    int Mb = cnt[0], Ms = cnt[1];
    int totB = Mb + 1;
    int totR = totB + Ms + 1;
    int tot2 = totR * 2;
    int nb = gridDim.x;
    int swb = swz8(blockIdx.x, nb);
    int stride = nb * blockDim.x;
    for (int idx = swb * blockDim.x + threadIdx.x; idx < tot2; idx += stride) {
        int r = idx >> 1, ph = idx & 1;   // pair (2r,2r+1) is always lane-adjacent
        int orow, slot;
        if (r < totB) { orow = r; slot = r - 1; }
        else { int t = r - totB; orow = RB + 1 + t; slot = t ? (RB + t - 1) : -1; }
        float acc[24];
        #pragma unroll
        for (int t = 0; t < 24; t++) acc[t] = 0.f;
        if (slot >= 0) {
            int s = off[slot], e = s + cntr[slot];
            for (int t = s + ph; t < e; t += 2) {
                int pix; float w;
                unpack_ew(epw[t], pix, w);
                const uint4* q = Qh4 + (size_t)pix * 3;
                uint4 q0 = q[0], q1 = q[1], q2 = q[2];
                acc8(acc + 0,  w, q0);
                acc8(acc + 8,  w, q1);
                acc8(acc + 16, w, q2);
            }
        }
        #pragma unroll
        for (int t = 0; t < 24; t++) acc[t] += __shfl_xor(acc[t], 1);
        if (ph == 0) {
            size_t b = (size_t)orow * 3;
            #pragma unroll
            for (int t = 0; t < 3; t++) {
                uint2 lo = f2u(make_float4(acc[8*t+0], acc[8*t+1], acc[8*t+2], acc[8*t+3]));
                uint2 hi = f2u(make_float4(acc[8*t+4], acc[8*t+5], acc[8*t+6], acc[8*t+7]));
                buf4[b + t] = make_uint4(lo.x, lo.y, hi.x, hi.y);
            }
        }
    }
}

// 3 uint4-chunks per row + XCD swizzle.
__global__ void blur_both_h(const uint4* __restrict__ in4, uint4* __restrict__ out4,
                            const int* __restrict__ n1b, const int* __restrict__ n2b,
                            const int* __restrict__ n1s, const int* __restrict__ n2s,
                            const int* cnt) {
    int Mb = cnt[0], Ms = cnt[1];
    int totB = (Mb + 1) * 3;
    int tot = totB + (Ms + 1) * 3;
    int nb = gridDim.x;
    int swb = swz8(blockIdx.x, nb);
    int stride = nb * blockDim.x;
    for (int idx = swb * blockDim.x + threadIdx.x; idx < tot; idx += stride) {
        int r, c, orow, a1, a2;
        bool sink;
        if (idx < totB) {
            r = idx / 3; c = idx - r * 3;
            orow = r; sink = (r == 0);
            int m = r - 1;
            a1 = sink ? 0 : n1b[m] + 1;
            a2 = sink ? 0 : n2b[m] + 1;
        } else {
            int t = idx - totB;
            r = t / 3; c = t - r * 3;
            orow = RB + 1 + r; sink = (r == 0);
            int m = r - 1;
            a1 = sink ? 0 : RB + 2 + n1s[m];   // -1 -> sink RB+1
            a2 = sink ? 0 : RB + 2 + n2s[m];
        }
        size_t o = (size_t)orow * 3 + c;
        if (sink) { out4[o] = make_uint4(0u, 0u, 0u, 0u); continue; }
        out4[o] = blur8(in4[o], in4[(size_t)a1 * 3 + c], in4[(size_t)a2 * 3 + c]);
    }
}

__global__ void blur_b_h(const uint4* __restrict__ in4, uint4* __restrict__ out4,
                         const int* __restrict__ n1, const int* __restrict__ n2,
                         const int* cnt) {
    int M = cnt[0];
    int tot = (M + 1) * 3;
    int nb = gridDim.x;
    int swb = swz8(blockIdx.x, nb);
    int stride = nb * blockDim.x;
    for (int idx = swb * blockDim.x + threadIdx.x; idx < tot; idx += stride) {
        int r = idx / 3, c = idx - r * 3;
        size_t o = (size_t)r * 3 + c;
        if (r == 0) { out4[o] = make_uint4(0u, 0u, 0u, 0u); continue; }
        int m = r - 1;
        out4[o] = blur8(in4[o], in4[(size_t)(n1[m] + 1) * 3 + c],
                        in4[(size_t)(n2[m] + 1) * 3 + c]);
    }
}

// ---- fp32 norm-chain versions (per-row threads) ----
__global__ void gather1_both(const int* __restrict__ off, const int* __restrict__ cntr,
                             const unsigned* __restrict__ epw, float* __restrict__ buf,
                             const int* cnt) {
    int Mb = cnt[0], Ms = cnt[1];
    int totB = Mb + 1;
    int tot = totB + Ms + 1;
    int stride = gridDim.x * blockDim.x;
    for (int r = blockIdx.x * blockDim.x + threadIdx.x; r < tot; r += stride) {
        int o, slot;
        if (r < totB) { o = r;              slot = r ? (r - 1) : -1; }
        else          { int t = r - totB; o = RB + 1 + t; slot = t ? (RB + t - 1) : -1; }
        float acc = 0.f;
        if (slot >= 0) {
            int s = off[slot], e = s + cntr[slot];
            for (int t = s; t < e; t++) acc += (float)(epw[t] >> 17) * (1.0f / 32767.0f);
        }
        buf[o] = acc;
    }
}

__global__ void blur1_both(const float* __restrict__ in, float* __restrict__ out,
                           const int* __restrict__ n1b, const int* __restrict__ n2b,
                           const int* __restrict__ n1s, const int* __restrict__ n2s,
                           const int* cnt) {
    int Mb = cnt[0], Ms = cnt[1];
    int totB = Mb + 1;
    int tot = totB + Ms + 1;
    int stride = gridDim.x * blockDim.x;
    for (int r = blockIdx.x * blockDim.x + threadIdx.x; r < tot; r += stride) {
        if (r < totB) {
            if (r == 0) { out[0] = 0.f; continue; }
            int m = r - 1;
            out[r] = in[r] + 0.5f * (in[n1b[m] + 1] + in[n2b[m] + 1]);
        } else {
            int t = r - totB;
            int o = RB + 1 + t;
            if (t == 0) { out[o] = 0.f; continue; }
            int m = t - 1;
            out[o] = in[o] + 0.5f * (in[RB + 2 + n1s[m]] + in[RB + 2 + n2s[m]]);
        }
    }
}

__global__ void blur1_b(const float* __restrict__ in, float* __restrict__ out,
                        const int* __restrict__ n1, const int* __restrict__ n2,
                        const int* cnt) {
    int M = cnt[0];
    int stride = gridDim.x * blockDim.x;
    for (int row = blockIdx.x * blockDim.x + threadIdx.x; row <= M; row += stride) {
        if (row == 0) { out[0] = 0.f; continue; }
        int m = row - 1;
        out[row] = in[row] + 0.5f * (in[n1[m] + 1] + in[n2[m] + 1]);
    }
}

// both norms in one pass (bilateral final in bufB, spatial final in bufS)
__global__ void slice_norm_both(const float* __restrict__ bufB, const float* __restrict__ bufS,
                                const int* __restrict__ osw, const float* __restrict__ wsv,
                                float* __restrict__ nbv, float* __restrict__ nsv,
                                float alphaB, float alphaS) {
    int i = blockIdx.x * blockDim.x + threadIdx.x;
    if (i >= NPIX) return;
    float sb = 0.f;
    #pragma unroll
    for (int r = 0; r < DB1; r++)
        sb += wsv[i * DB1 + r] * bufB[osw[i * DB1 + r] + 1];
    float ss = 0.f;
    #pragma unroll
    for (int r = 0; r < DS1; r++)
        ss += wsv[RB + i * DS1 + r] * bufS[RB + 2 + osw[RB + i * DS1 + r]];
    nbv[i] = alphaB * sb + 1e-20f;
    nsv[i] = alphaS * ss + 1e-20f;
}

// fused: slice(bilateral)+slice(spatial)+normalize+softmax -> Q (fp32) + Qh (fp16)
// r22: bijective block remap so contiguous pixel ranges stay on one XCD.
__global__ void slice_update(const float* __restrict__ U,
                             const uint4* __restrict__ bufB4, const uint4* __restrict__ bufS4,
                             const int* __restrict__ osw, const float* __restrict__ wsv,
                             const float* __restrict__ nbv, const float* __restrict__ nsv,
                             float* __restrict__ Q, uint4* __restrict__ Qh4,
                             float alphaB, float alphaS, int use_msg) {
    int swb = swz8(blockIdx.x, (int)gridDim.x);
    int i = swb * blockDim.x + threadIdx.x;
    if (i >= NPIX) return;
    float msg[24];
    #pragma unroll
    for (int t = 0; t < 24; t++) msg[t] = 0.f;
    if (use_msg) {
        float ib = 10.0f * alphaB / nbv[i];
        float is = 3.0f * alphaS / nsv[i];
        #pragma unroll
        for (int r = 0; r < DB1; r++) {
            float w = ib * wsv[i * DB1 + r];
            size_t base = (size_t)(osw[i * DB1 + r] + 1) * 3;
            uint4 q0 = bufB4[base], q1 = bufB4[base + 1], q2 = bufB4[base + 2];
            acc8(msg + 0,  w, q0);
            acc8(msg + 8,  w, q1);
            acc8(msg + 16, w, q2);
        }
        #pragma unroll
        for (int r = 0; r < DS1; r++) {
            float w = is * wsv[RB + i * DS1 + r];
            size_t base = (size_t)(RB + 2 + osw[RB + i * DS1 + r]) * 3;
            uint4 q0 = bufS4[base], q1 = bufS4[base + 1], q2 = bufS4[base + 2];
            acc8(msg + 0,  w, q0);
            acc8(msg + 8,  w, q1);
            acc8(msg + 16, w, q2);
        }
    }
    float mx = -1e30f;
    #pragma unroll
    for (int c = 0; c < NC; c++) {
        msg[c] = -U[i * NC + c] + msg[c];
        mx = fmaxf(mx, msg[c]);
    }
    float s = 0.f;
    #pragma unroll
    for (int c = 0; c < NC; c++) { float e = expf(msg[c] - mx); msg[c] = e; s += e; }
    float inv = 1.0f / s;
    #pragma unroll
    for (int c = 0; c < NC; c++) {
        msg[c] *= inv;
        Q[i * NC + c] = msg[c];
    }
    msg[21] = 0.f; msg[22] = 0.f; msg[23] = 0.f;
    #pragma unroll
    for (int t = 0; t < 3; t++) {
        uint2 lo = f2u(make_float4(msg[8*t+0], msg[8*t+1], msg[8*t+2], msg[8*t+3]));
        uint2 hi = f2u(make_float4(msg[8*t+4], msg[8*t+5], msg[8*t+6], msg[8*t+7]));
        Qh4[i * 3 + t] = make_uint4(lo.x, lo.y, hi.x, hi.y);
    }
}

// ---------------- host orchestration ----------------
extern "C" void kernel_launch(void* const* d_in, const int* in_sizes, int n_in,
                              void* d_out, int out_size, void* d_ws, size_t ws_size,
                              hipStream_t stream) {
    const float* U     = (const float*)d_in[0];
    const float* image = (const float*)d_in[1];
    float* Q = (float*)d_out;

    char* base = (char*)d_ws;
    size_t off = 0;
    auto alloc = [&](size_t bytes) -> void* {
        off = (off + 255) & ~(size_t)255;
        void* p = base + off; off += bytes; return p;
    };
    // unified per-entry arrays: [0,RB) bilateral, [RB,RB+RS) spatial
    int*   osw  = (int*)  alloc((size_t)(RB + RS) * 4);
    float* wsv  = (float*)alloc((size_t)(RB + RS) * 4);
    int*   rnk  = (int*)  alloc((size_t)(RB + RS) * 4);
    int*   n1_b = (int*)  alloc((size_t)DB1 * RB * 4);
    int*   n2_b = (int*)  alloc((size_t)DB1 * RB * 4);
    int*   n1_s = (int*)  alloc((size_t)DS1 * RS * 4);
    int*   n2_s = (int*)  alloc((size_t)DS1 * RS * 4);
    unsigned long long* uk_b = (unsigned long long*)alloc((size_t)RB * 8);
    ulonglong2* hkid = (ulonglong2*)alloc((size_t)TBS * 16);
    int*   gid2id = (int*)alloc((size_t)GN * 4);
    int*   cnt  = (int*)  alloc(256);   // [0]=M_b, [1]=M_s
    int*   histOff = (int*)alloc((size_t)NBUCK * 4);
    int*   wsums   = (int*)alloc((size_t)64 * 1024 * 4);
    int*   wsI     = (int*)alloc((size_t)16384 * 4);   // level-1 inclusive sums
    int*   ws2     = (int*)alloc((size_t)1024 * 4);    // level-2 sums
    int*   offv    = (int*)alloc((size_t)(RB + RS) * 4);
    // contiguous zero region: cntr | hist | histFill | pres
    char*  zreg  = (char*)alloc((size_t)(RB + RS) * 4 + (size_t)NBUCK * 8 + (size_t)GN * 4);
    int*   cntr     = (int*)zreg;
    int*   hist     = cntr + (RB + RS);
    int*   histFill = hist + NBUCK;
    int*   pres     = histFill + NBUCK;
    size_t zbytes = (size_t)(RB + RS) * 4 + (size_t)NBUCK * 8 + (size_t)GN * 4;
    unsigned* epw = (unsigned*)alloc((size_t)(RB + RS) * 4);   // packed 4B entries
    float* norm_b = (float*)alloc((size_t)NPIX * 4);
    float* norm_s = (float*)alloc((size_t)NPIX * 4);
    uint2* Qh   = (uint2*)alloc((size_t)NPIX * CP4 * 8);
    // combined lattice buffers: rows RB+RS+2 (bilateral [0,RB], spatial [RB+1,...])
    uint2* buf0 = (uint2*)alloc((size_t)(RB + RS + 2) * CP4 * 8);
    uint2* buf1 = (uint2*)alloc((size_t)(RB + RS + 2) * CP4 * 8);
    float* nbuf0 = (float*)alloc((size_t)(RB + RS + 2) * 4);
    float* nbuf1 = (float*)alloc((size_t)(RB + RS + 2) * 4);
    if (off > ws_size) return;

    const float ALPHA_B = (float)(1.0 / (1.0 + exp2(-(double)DB)));  // 32/33
    const float ALPHA_S = (float)(1.0 / (1.0 + exp2(-(double)DS)));  // 4/5

    constexpr int PGR = 2048;   // gather/blur grids (grid-stride, %8==0)

    // ---- 3 memsets ----
    hipMemsetAsync(cnt, 0, 16, stream);
    hipMemsetAsync(hkid, 0xFF, (size_t)TBS * 16, stream);
    hipMemsetAsync(zreg, 0, zbytes, stream);

    // ---- build both lattices ----
    build_both<<<(RB + RS) / 256, 256, 0, stream>>>(image, hkid, osw, wsv, pres);
    // bilateral compaction (bucket-sorted ids)
    hist_b<<<TBS / 256, 256, 0, stream>>>(hkid, hist);
    scan_wave_partial<<<NBUCK / 256, 256, 0, stream>>>(hist, histOff, wsums, NBUCK);
    scan_partials_excl<<<1, 256, 0, stream>>>(wsums, NBUCK / 64, cnt + 0);
    scan_finalize<<<NBUCK / 256, 256, 0, stream>>>(histOff, hist, wsums, NBUCK);
    assign_b<<<TBS / 256, 256, 0, stream>>>(hkid, histOff, histFill, uk_b);
    // spatial compaction (dense grid presence scan; ids row-major in (c0,c1))
    scan_wave_partial<<<GN / 256, 256, 0, stream>>>(pres, gid2id, wsums, GN);
    scan_partials_excl<<<1, 256, 0, stream>>>(wsums, GN / 64, cnt + 1);
    scan_finalize<<<GN / 256, 256, 0, stream>>>(gid2id, pres, wsums, GN);
    spatial_neighbors<<<GN / 256, 256, 0, stream>>>(pres, gid2id, n1_s, n2_s);
    os_count_both<<<(RB + RS) / 256, 256, 0, stream>>>(osw, hkid, gid2id, cntr, rnk);
    build_neighbors_b<<<2048, 256, 0, stream>>>(uk_b, hkid, cnt + 0, n1_b, n2_b);
    // unified offset scan over RB+RS id slots — hierarchical
    scan_wave_partial<<<(RB + RS) / 256, 256, 0, stream>>>(cntr, offv, wsums, RB + RS);
    scan_wave_partial<<<(NW1 + 255) / 256, 256, 0, stream>>>(wsums, wsI, ws2, NW1);
    scan_partials_excl<<<1, 256, 0, stream>>>(ws2, (NW1 + 63) / 64, nullptr);
    scan_finalize<<<(NW1 + 255) / 256, 256, 0, stream>>>(wsI, wsums, ws2, NW1);
    scan_finalize<<<(RB + RS) / 256, 256, 0, stream>>>(offv, cntr, wsI, RB + RS);
    fill_both<<<(RB + RS + 255) / 256, 256, 0, stream>>>(osw, wsv, offv, rnk, epw);

    // ---- norm filters (C=1, fp32), batched ----
    {
        gather1_both<<<1024, 256, 0, stream>>>(offv, cntr, epw, nbuf0, cnt);
        float* a = nbuf0; float* b = nbuf1;
        for (int j = 0; j < DS1; j++) {   // j=0..2: both chains
            blur1_both<<<1024, 256, 0, stream>>>(a, b,
                n1_b + (size_t)j * RB, n2_b + (size_t)j * RB,
                n1_s + (size_t)j * RS, n2_s + (size_t)j * RS, cnt);
            float* t = a; a = b; b = t;
        }
        // j=3..5: bilateral only — writes only rows [0,Mb]; spatial final stays in nbuf1.
        for (int j = DS1; j < DB1; j++) {
            blur1_b<<<1024, 256, 0, stream>>>(a, b, n1_b + (size_t)j * RB, n2_b + (size_t)j * RB, cnt);
            float* t = a; a = b; b = t;
        }
        // bilateral final in nbuf0 (6 swaps), spatial final in nbuf1 (3 swaps)
        slice_norm_both<<<(NPIX + 255) / 256, 256, 0, stream>>>(
            nbuf0, nbuf1, osw, wsv, norm_b, norm_s, ALPHA_B, ALPHA_S);
    }

    // ---- Q0 = softmax(-U) ----
    slice_update<<<(NPIX + 255) / 256, 256, 0, stream>>>(
        U, (const uint4*)buf0, (const uint4*)buf1, osw, wsv, norm_b, norm_s,
        Q, (uint4*)Qh, ALPHA_B, ALPHA_S, 0);

    // ---- 5 mean-field iterations ----
    for (int it = 0; it < 5; it++) {
        gather_both_h<<<PGR, 256, 0, stream>>>((const uint4*)Qh, offv, cntr, epw,
                                               (uint4*)buf0, cnt);
        uint2* a = buf0; uint2* b = buf1;
        for (int j = 0; j < DS1; j++) {   // j=0..2: both chains in one launch
            blur_both_h<<<PGR, 256, 0, stream>>>((const uint4*)a, (uint4*)b,
                n1_b + (size_t)j * RB, n2_b + (size_t)j * RB,
                n1_s + (size_t)j * RS, n2_s + (size_t)j * RS, cnt);
            uint2* t = a; a = b; b = t;
        }
        for (int j = DS1; j < DB1; j++) { // j=3..5: bilateral only
            blur_b_h<<<PGR, 256, 0, stream>>>((const uint4*)a, (uint4*)b,
                n1_b + (size_t)j * RB, n2_b + (size_t)j * RB, cnt);
            uint2* t = a; a = b; b = t;
        }
        // bilateral final in buf0, spatial final in buf1
        slice_update<<<(NPIX + 255) / 256, 256, 0, stream>>>(
            U, (const uint4*)buf0, (const uint4*)buf1, osw, wsv, norm_b, norm_s,
            Q, (uint4*)Qh, ALPHA_B, ALPHA_S, 1);
    }
}

// Round 8
// 735.950 us; speedup vs baseline: 1.2324x; 1.0307x over previous
//
#include <hip/hip_runtime.h>
#include <hip/hip_fp16.h>
#include <cmath>

// ---------------- problem constants ----------------
constexpr int IMH = 320, IMW = 320, NPIX = IMH * IMW, NC = 21;
constexpr int CP4 = 6;           // padded channels / 4  (24 values per row)
constexpr int DB = 5, DB1 = 6;   // bilateral lattice dim
constexpr int DS = 2, DS1 = 3;   // spatial lattice dim
constexpr int RB = NPIX * DB1;   // splat entries (bilateral) = 614400
constexpr int RS = NPIX * DS1;   // (spatial) = 307200
constexpr int TBS = 1 << 19;     // hash table slots (bilateral only)
constexpr int NBUCK = 1 << 16;   // bilateral sort buckets (c0,c1 low bytes)
constexpr int NW1 = (RB + RS) / 64;  // wave sums in the unified offset scan
// spatial dense grid: lattice coords are deterministic in (x,y) only.
// c0 in [-8, 298], c1 in [-194, 115]  ->  512x512 grid with offsets below.
constexpr int GS = 512, GN = GS * GS;
constexpr int C0OFF = 16, C1OFF = 200;

// Combined lattice-value buffer layout (static partition):
//   bilateral: row 0 = sink, point m -> row m+1           (rows [0, RB])
//   spatial:   row RB+1 = sink, point m -> row RB+2+m     (rows [RB+1, ...])
// spatial neighbor n=-1 maps to RB+2+(-1) = RB+1 = sink automatically.

// LESSONS (measured):
// r12-r14: hist fused into CAS loop = +45us; test-before-CAS = +8us/+36MB
//   FETCH; 4B epw packing does NOT cut scatter WRITE (64B sectors rule).
// r15: fill's atomicAdd removed via ranks captured in os_count.
// r16: ATOMIC-THROUGHPUT-BOUND build: ~16-19G atomics/s ceiling (64B RMW
//   sectors). Only fewer atomics help.
// r17: spatial lattice -> dense 512x512 grid (no atomics).
// r18: blur row-per-thread REGRESSED: <200K threads latency-starved.
//   TLP rule: >=400K threads for scattered kernels.
// r19: merged 16B {key,id} table, 6x parallel neighbor build: ->861us.
// r20: gather 3-chunk split REGRESSED: SECTOR RULE beats TLP rule — a
//   thread must consume WHOLE 48B rows. Fused 9-pt blur: no win in
//   L2-MISS regime (no swizzle, buf >> L2).
// r21: paired-lane gather (entry-parity split, full-row reads, shfl_xor
//   combine): ->827us.
// r22: XCD chunked swizzle (T1) on gather/blur/slice: ->758us. Working
//   set 8.6MB -> per-XCD ~1.1MB contiguous windows fit 4MB L2; neighbor
//   reads become XCD-local hits.
// r23 (this round): (a) RETRY pair-fusion under the L2-HIT regime r22
//   created — fused 9-pt stencil's extra reads are now L2 hits while
//   fusion deletes a full intermediate pass per pair (2 pairs/iter + 2
//   norm passes). Isolated test fusion never got. (b) slice_update Q
//   (fp32, 8.6MB) written 6x but only final observable -> write_q flag.

#define EMPTY_KEY 0xFFFFFFFFFFFFFFFFULL

__device__ __forceinline__ unsigned long long mix64(unsigned long long x) {
    x ^= x >> 33; x *= 0xff51afd7ed558ccdULL;
    x ^= x >> 33; x *= 0xc4ceb9fe1a85ec53ULL;
    x ^= x >> 33; return x;
}

// fp16 pack helpers: uint2 = 4 halves; math in fp32, storage fp16.
__device__ __forceinline__ float4 u2f(uint2 u) {
    __half2 a = *reinterpret_cast<__half2*>(&u.x);
    __half2 b = *reinterpret_cast<__half2*>(&u.y);
    float2 fa = __half22float2(a), fb = __half22float2(b);
    return make_float4(fa.x, fa.y, fb.x, fb.y);
}
__device__ __forceinline__ uint2 f2u(float4 v) {
    __half2 a = __floats2half2_rn(v.x, v.y);
    __half2 b = __floats2half2_rn(v.z, v.w);
    uint2 u;
    u.x = *reinterpret_cast<unsigned*>(&a);
    u.y = *reinterpret_cast<unsigned*>(&b);
    return u;
}

__device__ __forceinline__ unsigned pack_ew(int pix, float w) {
    int w15 = (int)lrintf(fminf(fmaxf(w, 0.f), 1.f) * 32767.f);
    return ((unsigned)w15 << 17) | (unsigned)pix;
}
__device__ __forceinline__ void unpack_ew(unsigned e, int& pix, float& w) {
    pix = (int)(e & 0x1FFFFu);
    w = (float)(e >> 17) * (1.0f / 32767.0f);
}

// accumulate 8 fp16 channels (one uint4) into acc[0..7] with weight w.
__device__ __forceinline__ void acc8(float* acc, float w, uint4 q) {
    float4 v = u2f(make_uint2(q.x, q.y));
    acc[0] += w * v.x; acc[1] += w * v.y; acc[2] += w * v.z; acc[3] += w * v.w;
    v = u2f(make_uint2(q.z, q.w));
    acc[4] += w * v.x; acc[5] += w * v.y; acc[6] += w * v.z; acc[7] += w * v.w;
}

// blur core on one uint4 (8 fp16 channels): x + 0.5*(a+b), f32 math.
__device__ __forceinline__ uint4 blur8(uint4 xs, uint4 xa, uint4 xb) {
    float4 s0 = u2f(make_uint2(xs.x, xs.y)), s1 = u2f(make_uint2(xs.z, xs.w));
    float4 a0 = u2f(make_uint2(xa.x, xa.y)), a1 = u2f(make_uint2(xa.z, xa.w));
    float4 b0 = u2f(make_uint2(xb.x, xb.y)), b1 = u2f(make_uint2(xb.z, xb.w));
    s0.x += 0.5f * (a0.x + b0.x); s0.y += 0.5f * (a0.y + b0.y);
    s0.z += 0.5f * (a0.z + b0.z); s0.w += 0.5f * (a0.w + b0.w);
    s1.x += 0.5f * (a1.x + b1.x); s1.y += 0.5f * (a1.y + b1.y);
    s1.z += 0.5f * (a1.z + b1.z); s1.w += 0.5f * (a1.w + b1.w);
    uint2 lo = f2u(s0), hi = f2u(s1);
    return make_uint4(lo.x, lo.y, hi.x, hi.y);
}

__device__ __forceinline__ uint4 pack8(const float* acc) {
    uint2 lo = f2u(make_float4(acc[0], acc[1], acc[2], acc[3]));
    uint2 hi = f2u(make_float4(acc[4], acc[5], acc[6], acc[7]));
    return make_uint4(lo.x, lo.y, hi.x, hi.y);
}

// chunked XCD swizzle: block bid -> swb so blocks on one XCD are contiguous.
// requires gridDim.x % 8 == 0 (bijective).
__device__ __forceinline__ int swz8(int bid, int nb) {
    return (bid & 7) * (nb >> 3) + (bid >> 3);
}

// ---------------- permutohedral embedding (matches reference op-for-op, f32) ----------------
template<int D>
__device__ void perm_embed(const float* f, float* bary, unsigned long long* pk) {
    constexpr int D1 = D + 1;
    float cf[D];
    #pragma unroll
    for (int i = 0; i < D; i++) {
        double s = sqrt(2.0 / 3.0) * (double)D1 / sqrt((double)((i + 1) * (i + 2)));
        cf[i] = f[i] * (float)s;
    }
    float csum[D];
    float acc = 0.f;
    #pragma unroll
    for (int i = D - 1; i >= 0; i--) { acc += cf[i]; csum[i] = acc; }
    float el[D1];
    el[0] = csum[0];
    #pragma unroll
    for (int i = 1; i < D; i++) el[i] = csum[i] - (float)i * cf[i - 1];
    el[D] = -(float)D * cf[D - 1];
    const float down = 1.0f / (float)D1;
    float rem0[D1]; int rank[D1]; int ssum = 0;
    #pragma unroll
    for (int i = 0; i < D1; i++) {
        float rd = rintf(el[i] * down);
        rem0[i] = rd * (float)D1;
        ssum += (int)rd;
    }
    float diff[D1];
    #pragma unroll
    for (int i = 0; i < D1; i++) diff[i] = el[i] - rem0[i];
    #pragma unroll
    for (int i = 0; i < D1; i++) {
        int r = 0;
        #pragma unroll
        for (int j = 0; j < D1; j++)
            r += (diff[j] > diff[i]) || ((diff[j] == diff[i]) && (j < i));
        rank[i] = r + ssum;
    }
    #pragma unroll
    for (int i = 0; i < D1; i++) {
        if (rank[i] < 0)      { rank[i] += D1; rem0[i] += (float)D1; }
        else if (rank[i] > D) { rank[i] -= D1; rem0[i] -= (float)D1; }
    }
    float b[D + 2];
    #pragma unroll
    for (int i = 0; i < D + 2; i++) b[i] = 0.f;
    #pragma unroll
    for (int i = 0; i < D1; i++) b[D - rank[i]]     += (el[i] - rem0[i]) * down;
    #pragma unroll
    for (int i = 0; i < D1; i++) b[D + 1 - rank[i]] -= (el[i] - rem0[i]) * down;
    b[0] += 1.0f + b[D + 1];
    #pragma unroll
    for (int i = 0; i < D1; i++) bary[i] = b[i];
    int key0[D];
    #pragma unroll
    for (int i = 0; i < D; i++) key0[i] = (int)rintf(rem0[i]);
    #pragma unroll
    for (int r = 0; r < D1; r++) {
        unsigned long long p = 0;
        #pragma unroll
        for (int i = 0; i < D; i++) {
            int c = key0[i] + ((rank[i] < D1 - r) ? r : r - D1);
            p |= ((unsigned long long)((unsigned)(c + 2048) & 0xFFFu)) << (12 * i);
        }
        pk[r] = p;
    }
}

__device__ __forceinline__ int key_code(unsigned long long k) {
    int c0 = (int)(k & 0xFFFULL);
    int c1 = (int)((k >> 12) & 0xFFFULL);
    return ((c0 & 0xFF) << 8) | (c1 & 0xFF);
}

// ---------------- merged {key,id} hash table (16B entries) ----------------
__device__ __forceinline__ int hash_insert2(ulonglong2* hkid, int tmask, unsigned long long k) {
    int slot = (int)(mix64(k) & (unsigned long long)tmask);
    while (true) {
        unsigned long long prev = atomicCAS(&hkid[slot].x, EMPTY_KEY, k);
        if (prev == EMPTY_KEY || prev == k) return slot;
        slot = (slot + 1) & tmask;
    }
}
// one 16B load per probe: key match delivers id in the same transaction.
__device__ __forceinline__ int hash_lookup2(const ulonglong2* __restrict__ hkid,
                                            int tmask, unsigned long long k) {
    int slot = (int)(mix64(k) & (unsigned long long)tmask);
    while (true) {
        ulonglong2 e = hkid[slot];
        if (e.x == k) return (int)e.y;
        if (e.x == EMPTY_KEY) return -1;
        slot = (slot + 1) & tmask;
    }
}

// ---------------- build kernels ----------------
__global__ void build_both(const float* __restrict__ image, ulonglong2* hkid,
                           int* os, float* wsv, int* pres) {
    int idx = blockIdx.x * blockDim.x + threadIdx.x;
    if (idx < RB) {
        int i = idx / DB1;          // pixel
        int r = idx - i * DB1;      // simplex vertex rank
        int x = i % IMW, y = i / IMW;
        float f[DB];
        f[0] = (float)x / 80.0f;
        f[1] = (float)y / 80.0f;
        f[2] = image[i * 3 + 0] / 13.0f;
        f[3] = image[i * 3 + 1] / 13.0f;
        f[4] = image[i * 3 + 2] / 13.0f;
        float bary[DB1]; unsigned long long pk[DB1];
        perm_embed<DB>(f, bary, pk);
        float w = 0.f; unsigned long long k = 0;
        #pragma unroll
        for (int r2 = 0; r2 < DB1; r2++)
            if (r2 == r) { w = bary[r2]; k = pk[r2]; }   // static idx -> regs
        wsv[idx] = w;
        os[idx] = hash_insert2(hkid, TBS - 1, k);
    } else if (idx < RB + RS) {
        int t = idx - RB;
        int ip = t / DS1;
        int r = t - ip * DS1;
        int x = ip % IMW, y = ip / IMW;
        float f[DS];
        f[0] = (float)x / 3.0f;
        f[1] = (float)y / 3.0f;
        float bary[DS1]; unsigned long long pk[DS1];
        perm_embed<DS>(f, bary, pk);
        float w = 0.f; unsigned long long k = 0;
        #pragma unroll
        for (int r2 = 0; r2 < DS1; r2++)
            if (r2 == r) { w = bary[r2]; k = pk[r2]; }
        int c0 = (int)(k & 0xFFFULL) - 2048;
        int c1 = (int)((k >> 12) & 0xFFFULL) - 2048;
        int gid = (c0 + C0OFF) * GS + (c1 + C1OFF);
        wsv[idx] = w;
        os[idx] = gid;
        pres[gid] = 1;              // benign same-value race, no atomic
    }
}

// hist over bilateral table only
__global__ void hist_b(const ulonglong2* __restrict__ hkid, int* hist) {
    int s = blockIdx.x * blockDim.x + threadIdx.x;
    if (s >= TBS) return;
    unsigned long long k = hkid[s].x;
    if (k == EMPTY_KEY) return;
    atomicAdd(&hist[key_code(k)], 1);
}

// ---------------- barrier-free scan machinery ----------------
__global__ void scan_wave_partial(const int* __restrict__ count, int* incl, int* wsum, int n) {
    int idx = blockIdx.x * blockDim.x + threadIdx.x;
    int lane = threadIdx.x & 63;
    int v = (idx < n) ? count[idx] : 0;
    int s = v;
    #pragma unroll
    for (int d = 1; d < 64; d <<= 1) {
        int t = __shfl_up(s, d);
        if (lane >= d) s += t;
    }
    if (idx < n) incl[idx] = s;
    if (lane == 63) wsum[idx >> 6] = s;
}

__global__ void scan_partials_excl(int* w, int nw, int* total_out) {
    __shared__ int sh[256];
    __shared__ int run;
    if (threadIdx.x == 0) run = 0;
    __syncthreads();
    for (int basei = 0; basei < nw; basei += 256) {
        int idx = basei + threadIdx.x;
        int v = (idx < nw) ? w[idx] : 0;
        sh[threadIdx.x] = v;
        __syncthreads();
        for (int d = 1; d < 256; d <<= 1) {
            int t = (threadIdx.x >= d) ? sh[threadIdx.x - d] : 0;
            __syncthreads();
            sh[threadIdx.x] += t;
            __syncthreads();
        }
        int total = sh[255];
        if (idx < nw) w[idx] = run + sh[threadIdx.x] - v;
        __syncthreads();
        if (threadIdx.x == 0) run += total;
        __syncthreads();
    }
    if (total_out != nullptr && threadIdx.x == 0) *total_out = run;
}

__global__ void scan_finalize(int* off, const int* __restrict__ count,
                              const int* __restrict__ wsum, int n) {
    int idx = blockIdx.x * blockDim.x + threadIdx.x;
    if (idx < n) off[idx] = off[idx] - count[idx] + wsum[idx >> 6];
}

// ---------------- bucket-sorted compaction (bilateral) ----------------
__global__ void assign_b(ulonglong2* hkid, const int* __restrict__ histOff,
                         int* histFill, unsigned long long* uk_b) {
    int s = blockIdx.x * blockDim.x + threadIdx.x;
    if (s >= TBS) return;
    unsigned long long k = hkid[s].x;
    if (k == EMPTY_KEY) return;
    int code = key_code(k);
    int id = histOff[code] + atomicAdd(&histFill[code], 1);
    hkid[s].y = (unsigned long long)id;
    uk_b[id] = k;
}

// spatial neighbors via dense grid reads — no hashing, no atomics.
__global__ void spatial_neighbors(const int* __restrict__ pres, const int* __restrict__ gid2id,
                                  int* __restrict__ n1s, int* __restrict__ n2s) {
    int gid = blockIdx.x * blockDim.x + threadIdx.x;
    if (gid >= GN) return;
    if (!pres[gid]) return;
    int id = gid2id[gid];
    const int d1[3] = {  2 * GS - 1, -GS + 2, -GS - 1 };
    const int d2[3] = { -2 * GS + 1,  GS - 2,  GS + 1 };
    #pragma unroll
    for (int j = 0; j < 3; j++) {
        int g1 = gid + d1[j], g2 = gid + d2[j];
        n1s[j * RS + id] = pres[g1] ? gid2id[g1] : -1;
        n2s[j * RS + id] = pres[g2] ? gid2id[g2] : -1;
    }
}

// unified os remap + cntr histogram + per-entry rank capture (wave-agg atomics).
__global__ void os_count_both(int* os, const ulonglong2* __restrict__ hkid,
                              const int* __restrict__ gid2id, int* cntr, int* rnk) {
    int i = blockIdx.x * blockDim.x + threadIdx.x;
    int lane = threadIdx.x & 63;
    int idg;
    if (i < RB) {
        int id = (int)hkid[os[i]].y;
        os[i] = id;
        idg = id;
    } else {
        int id = gid2id[os[i]];
        os[i] = id;
        idg = RB + id;
    }
    // 64-lane equal-id mask
    unsigned long long m = 0;
    #pragma unroll
    for (int l = 0; l < 64; l++) {
        int o = __shfl(idg, l);
        m |= (unsigned long long)(o == idg) << l;
    }
    int rless  = __popcll(m & ((1ULL << lane) - 1ULL));
    int leader = __ffsll(m) - 1;
    int gcnt   = __popcll(m);
    int base = 0;
    if (lane == leader) base = atomicAdd(&cntr[idg], gcnt);
    base = __shfl(base, leader);
    rnk[i] = base + rless;
}

// bilateral neighbors, (j,m) parallel; XCD-chunk swizzle for L2 locality.
__global__ void build_neighbors_b(const unsigned long long* __restrict__ uk,
                                  const ulonglong2* __restrict__ hkid,
                                  const int* cnt, int* n1, int* n2) {
    int Mb = cnt[0];
    int tot = DB1 * Mb;
    int nb = gridDim.x;                    // multiple of 8
    int swb = swz8(blockIdx.x, nb);
    int stride = nb * blockDim.x;
    for (int t = swb * blockDim.x + threadIdx.x; t < tot; t += stride) {
        int j = t / Mb, m = t - j * Mb;
        unsigned long long k = uk[m];
        unsigned long long p1 = 0, p2 = 0;
        #pragma unroll
        for (int i = 0; i < DB; i++) {
            int c = (int)((k >> (12 * i)) & 0xFFFULL) - 2048;
            int a = c + ((i == j) ? DB : -1);
            int b = c + ((i == j) ? -DB : 1);
            p1 |= ((unsigned long long)((unsigned)(a + 2048) & 0xFFFu)) << (12 * i);
            p2 |= ((unsigned long long)((unsigned)(b + 2048) & 0xFFFu)) << (12 * i);
        }
        n1[j * RB + m] = hash_lookup2(hkid, TBS - 1, p1);
        n2[j * RB + m] = hash_lookup2(hkid, TBS - 1, p2);
    }
}

// composed neighbor indices for fused blur pairs.
// bilateral: pair(0,1) -> comp[0..3]*RB; pair(3,4) -> comp[4..7]*RB.
// comp through missing neighbor (-1) stays -1 (sink value is 0).
__global__ void compose_b(const int* __restrict__ n1, const int* __restrict__ n2,
                          const int* cnt, int* __restrict__ comp) {
    int Mb = cnt[0];
    int stride = gridDim.x * blockDim.x;
    for (int m = blockIdx.x * blockDim.x + threadIdx.x; m < Mb; m += stride) {
        int a = n1[RB + m], b = n2[RB + m];
        comp[0 * RB + m] = (a < 0) ? -1 : n1[a];
        comp[1 * RB + m] = (a < 0) ? -1 : n2[a];
        comp[2 * RB + m] = (b < 0) ? -1 : n1[b];
        comp[3 * RB + m] = (b < 0) ? -1 : n2[b];
        int a2 = n1[4 * RB + m], b2 = n2[4 * RB + m];
        comp[4 * RB + m] = (a2 < 0) ? -1 : n1[3 * RB + a2];
        comp[5 * RB + m] = (a2 < 0) ? -1 : n2[3 * RB + a2];
        comp[6 * RB + m] = (b2 < 0) ? -1 : n1[3 * RB + b2];
        comp[7 * RB + m] = (b2 < 0) ? -1 : n2[3 * RB + b2];
    }
}
// spatial: pair(0,1) only -> comp[0..3]*RS.
__global__ void compose_s(const int* __restrict__ n1, const int* __restrict__ n2,
                          const int* cnt, int* __restrict__ comp) {
    int Ms = cnt[1];
    int stride = gridDim.x * blockDim.x;
    for (int m = blockIdx.x * blockDim.x + threadIdx.x; m < Ms; m += stride) {
        int a = n1[RS + m], b = n2[RS + m];
        comp[0 * RS + m] = (a < 0) ? -1 : n1[a];
        comp[1 * RS + m] = (a < 0) ? -1 : n2[a];
        comp[2 * RS + m] = (b < 0) ? -1 : n1[b];
        comp[3 * RS + m] = (b < 0) ? -1 : n2[b];
    }
}

// unified fill: pos derived from precomputed rank — NO atomics
__global__ void fill_both(const int* __restrict__ os, const float* __restrict__ wsv,
                          const int* __restrict__ off, const int* __restrict__ rnk,
                          unsigned* epw) {
    int idx = blockIdx.x * blockDim.x + threadIdx.x;
    if (idx >= RB + RS) return;
    int slot, pix;
    if (idx < RB) { slot = os[idx];        pix = idx / DB1; }
    else          { slot = RB + os[idx];   pix = (idx - RB) / DS1; }
    int pos = off[slot] + rnk[idx];
    epw[pos] = pack_ew(pix, wsv[idx]);
}

// ---------------- batched filter kernels (fp16 storage, fp32 math) ----------------
// paired-lane gather + XCD swizzle. Pairing: idx parity == lane parity.
__global__ void gather_both_h(const uint4* __restrict__ Qh4, const int* __restrict__ off,
                              const int* __restrict__ cntr, const unsigned* __restrict__ epw,
                              uint4* __restrict__ buf4, const int* cnt) {
    int Mb = cnt[0], Ms = cnt[1];
    int totB = Mb + 1;
    int totR = totB + Ms + 1;
    int tot2 = totR * 2;
    int nb = gridDim.x;
    int swb = swz8(blockIdx.x, nb);
    int stride = nb * blockDim.x;
    for (int idx = swb * blockDim.x + threadIdx.x; idx < tot2; idx += stride) {
        int r = idx >> 1, ph = idx & 1;   // pair (2r,2r+1) is always lane-adjacent
        int orow, slot;
        if (r < totB) { orow = r; slot = r - 1; }
        else { int t = r - totB; orow = RB + 1 + t; slot = t ? (RB + t - 1) : -1; }
        float acc[24];
        #pragma unroll
        for (int t = 0; t < 24; t++) acc[t] = 0.f;
        if (slot >= 0) {
            int s = off[slot], e = s + cntr[slot];
            for (int t = s + ph; t < e; t += 2) {
                int pix; float w;
                unpack_ew(epw[t], pix, w);
                const uint4* q = Qh4 + (size_t)pix * 3;
                uint4 q0 = q[0], q1 = q[1], q2 = q[2];
                acc8(acc + 0,  w, q0);
                acc8(acc + 8,  w, q1);
                acc8(acc + 16, w, q2);
            }
        }
        #pragma unroll
        for (int t = 0; t < 24; t++) acc[t] += __shfl_xor(acc[t], 1);
        if (ph == 0) {
            size_t b = (size_t)orow * 3;
            #pragma unroll
            for (int t = 0; t < 3; t++)
                buf4[b + t] = pack8(acc + 8 * t);
        }
    }
}

// single-step blur (j=2 both chains), 3 chunks/row + XCD swizzle.
__global__ void blur_both_h(const uint4* __restrict__ in4, uint4* __restrict__ out4,
                            const int* __restrict__ n1b, const int* __restrict__ n2b,
                            const int* __restrict__ n1s, const int* __restrict__ n2s,
                            const int* cnt) {
    int Mb = cnt[0], Ms = cnt[1];
    int totB = (Mb + 1) * 3;
    int tot = totB + (Ms + 1) * 3;
    int nb = gridDim.x;
    int swb = swz8(blockIdx.x, nb);
    int stride = nb * blockDim.x;
    for (int idx = swb * blockDim.x + threadIdx.x; idx < tot; idx += stride) {
        int r, c, orow, a1, a2;
        bool sink;
        if (idx < totB) {
            r = idx / 3; c = idx - r * 3;
            orow = r; sink = (r == 0);
            int m = r - 1;
            a1 = sink ? 0 : n1b[m] + 1;
            a2 = sink ? 0 : n2b[m] + 1;
        } else {
            int t = idx - totB;
            r = t / 3; c = t - r * 3;
            orow = RB + 1 + r; sink = (r == 0);
            int m = r - 1;
            a1 = sink ? 0 : RB + 2 + n1s[m];   // -1 -> sink RB+1
            a2 = sink ? 0 : RB + 2 + n2s[m];
        }
        size_t o = (size_t)orow * 3 + c;
        if (sink) { out4[o] = make_uint4(0u, 0u, 0u, 0u); continue; }
        out4[o] = blur8(in4[o], in4[(size_t)a1 * 3 + c], in4[(size_t)a2 * 3 + c]);
    }
}

// single-step bilateral blur (j=5), 3 chunks/row + XCD swizzle.
__global__ void blur_b_h(const uint4* __restrict__ in4, uint4* __restrict__ out4,
                         const int* __restrict__ n1, const int* __restrict__ n2,
                         const int* cnt) {
    int M = cnt[0];
    int tot = (M + 1) * 3;
    int nb = gridDim.x;
    int swb = swz8(blockIdx.x, nb);
    int stride = nb * blockDim.x;
    for (int idx = swb * blockDim.x + threadIdx.x; idx < tot; idx += stride) {
        int r = idx / 3, c = idx - r * 3;
        size_t o = (size_t)r * 3 + c;
        if (r == 0) { out4[o] = make_uint4(0u, 0u, 0u, 0u); continue; }
        int m = r - 1;
        out4[o] = blur8(in4[o], in4[(size_t)(n1[m] + 1) * 3 + c],
                        in4[(size_t)(n2[m] + 1) * 3 + c]);
    }
}

// fused pair blur (j=0 then j=1), both chains, XCD swizzle. 9-point stencil:
// out = x + 0.5(x@n1p + x@n2p + x@a + x@b) + 0.25(x@c1..c4), a=n1q, b=n2q.
__global__ void fused_blur_both_h(const uint4* __restrict__ in4, uint4* __restrict__ out4,
                                  const int* __restrict__ n1b, const int* __restrict__ n2b,
                                  const int* __restrict__ compb,
                                  const int* __restrict__ n1s, const int* __restrict__ n2s,
                                  const int* __restrict__ comps, const int* cnt) {
    int Mb = cnt[0], Ms = cnt[1];
    int totB = (Mb + 1) * 3;
    int tot = totB + (Ms + 1) * 3;
    int nb = gridDim.x;
    int swb = swz8(blockIdx.x, nb);
    int stride = nb * blockDim.x;
    for (int idx = swb * blockDim.x + threadIdx.x; idx < tot; idx += stride) {
        int r, c, self = 0, i1 = 0, i2 = 0, ia = 0, ib = 0, ic1 = 0, ic2 = 0, ic3 = 0, ic4 = 0;
        bool sink;
        if (idx < totB) {
            r = idx / 3; c = idx - r * 3;
            sink = (r == 0);
            self = r;
            int m = r - 1;
            if (!sink) {
                i1 = n1b[m] + 1;             i2 = n2b[m] + 1;
                ia = n1b[RB + m] + 1;        ib = n2b[RB + m] + 1;
                ic1 = compb[m] + 1;          ic2 = compb[RB + m] + 1;
                ic3 = compb[2 * RB + m] + 1; ic4 = compb[3 * RB + m] + 1;
            }
        } else {
            int t = idx - totB;
            r = t / 3; c = t - r * 3;
            sink = (r == 0);
            self = RB + 1 + r;
            int m = r - 1;
            if (!sink) {
                i1 = RB + 2 + n1s[m];             i2 = RB + 2 + n2s[m];
                ia = RB + 2 + n1s[RS + m];        ib = RB + 2 + n2s[RS + m];
                ic1 = RB + 2 + comps[m];          ic2 = RB + 2 + comps[RS + m];
                ic3 = RB + 2 + comps[2 * RS + m]; ic4 = RB + 2 + comps[3 * RS + m];
            }
        }
        size_t o = (size_t)self * 3 + c;
        if (sink) { out4[o] = make_uint4(0u, 0u, 0u, 0u); continue; }
        float acc[8];
        #pragma unroll
        for (int t2 = 0; t2 < 8; t2++) acc[t2] = 0.f;
        acc8(acc, 1.0f,  in4[o]);
        acc8(acc, 0.5f,  in4[(size_t)i1 * 3 + c]);
        acc8(acc, 0.5f,  in4[(size_t)i2 * 3 + c]);
        acc8(acc, 0.5f,  in4[(size_t)ia * 3 + c]);
        acc8(acc, 0.5f,  in4[(size_t)ib * 3 + c]);
        acc8(acc, 0.25f, in4[(size_t)ic1 * 3 + c]);
        acc8(acc, 0.25f, in4[(size_t)ic2 * 3 + c]);
        acc8(acc, 0.25f, in4[(size_t)ic3 * 3 + c]);
        acc8(acc, 0.25f, in4[(size_t)ic4 * 3 + c]);
        out4[o] = pack8(acc);
    }
}

// fused pair blur (j=3 then j=4), bilateral only, XCD swizzle.
__global__ void fused_blur_b_h(const uint4* __restrict__ in4, uint4* __restrict__ out4,
                               const int* __restrict__ n1b, const int* __restrict__ n2b,
                               const int* __restrict__ compb, const int* cnt) {
    int M = cnt[0];
    int tot = (M + 1) * 3;
    int nb = gridDim.x;
    int swb = swz8(blockIdx.x, nb);
    int stride = nb * blockDim.x;
    for (int idx = swb * blockDim.x + threadIdx.x; idx < tot; idx += stride) {
        int r = idx / 3, c = idx - r * 3;
        size_t o = (size_t)r * 3 + c;
        if (r == 0) { out4[o] = make_uint4(0u, 0u, 0u, 0u); continue; }
        int m = r - 1;
        int i1 = n1b[3 * RB + m] + 1,  i2 = n2b[3 * RB + m] + 1;
        int ia = n1b[4 * RB + m] + 1,  ib = n2b[4 * RB + m] + 1;
        int ic1 = compb[4 * RB + m] + 1, ic2 = compb[5 * RB + m] + 1;
        int ic3 = compb[6 * RB + m] + 1, ic4 = compb[7 * RB + m] + 1;
        float acc[8];
        #pragma unroll
        for (int t2 = 0; t2 < 8; t2++) acc[t2] = 0.f;
        acc8(acc, 1.0f,  in4[o]);
        acc8(acc, 0.5f,  in4[(size_t)i1 * 3 + c]);
        acc8(acc, 0.5f,  in4[(size_t)i2 * 3 + c]);
        acc8(acc, 0.5f,  in4[(size_t)ia * 3 + c]);
        acc8(acc, 0.5f,  in4[(size_t)ib * 3 + c]);
        acc8(acc, 0.25f, in4[(size_t)ic1 * 3 + c]);
        acc8(acc, 0.25f, in4[(size_t)ic2 * 3 + c]);
        acc8(acc, 0.25f, in4[(size_t)ic3 * 3 + c]);
        acc8(acc, 0.25f, in4[(size_t)ic4 * 3 + c]);
        out4[o] = pack8(acc);
    }
}

// ---- fp32 norm-chain versions (per-row threads) ----
__global__ void gather1_both(const int* __restrict__ off, const int* __restrict__ cntr,
                             const unsigned* __restrict__ epw, float* __restrict__ buf,
                             const int* cnt) {
    int Mb = cnt[0], Ms = cnt[1];
    int totB = Mb + 1;
    int tot = totB + Ms + 1;
    int stride = gridDim.x * blockDim.x;
    for (int r = blockIdx.x * blockDim.x + threadIdx.x; r < tot; r += stride) {
        int o, slot;
        if (r < totB) { o = r;              slot = r ? (r - 1) : -1; }
        else          { int t = r - totB; o = RB + 1 + t; slot = t ? (RB + t - 1) : -1; }
        float acc = 0.f;
        if (slot >= 0) {
            int s = off[slot], e = s + cntr[slot];
            for (int t = s; t < e; t++) acc += (float)(epw[t] >> 17) * (1.0f / 32767.0f);
        }
        buf[o] = acc;
    }
}

__global__ void blur1_both(const float* __restrict__ in, float* __restrict__ out,
                           const int* __restrict__ n1b, const int* __restrict__ n2b,
                           const int* __restrict__ n1s, const int* __restrict__ n2s,
                           const int* cnt) {
    int Mb = cnt[0], Ms = cnt[1];
    int totB = Mb + 1;
    int tot = totB + Ms + 1;
    int stride = gridDim.x * blockDim.x;
    for (int r = blockIdx.x * blockDim.x + threadIdx.x; r < tot; r += stride) {
        if (r < totB) {
            if (r == 0) { out[0] = 0.f; continue; }
            int m = r - 1;
            out[r] = in[r] + 0.5f * (in[n1b[m] + 1] + in[n2b[m] + 1]);
        } else {
            int t = r - totB;
            int o = RB + 1 + t;
            if (t == 0) { out[o] = 0.f; continue; }
            int m = t - 1;
            out[o] = in[o] + 0.5f * (in[RB + 2 + n1s[m]] + in[RB + 2 + n2s[m]]);
        }
    }
}

__global__ void blur1_b(const float* __restrict__ in, float* __restrict__ out,
                        const int* __restrict__ n1, const int* __restrict__ n2,
                        const int* cnt) {
    int M = cnt[0];
    int stride = gridDim.x * blockDim.x;
    for (int row = blockIdx.x * blockDim.x + threadIdx.x; row <= M; row += stride) {
        if (row == 0) { out[0] = 0.f; continue; }
        int m = row - 1;
        out[row] = in[row] + 0.5f * (in[n1[m] + 1] + in[n2[m] + 1]);
    }
}

__global__ void fused1_both(const float* __restrict__ in, float* __restrict__ out,
                            const int* __restrict__ n1b, const int* __restrict__ n2b,
                            const int* __restrict__ compb,
                            const int* __restrict__ n1s, const int* __restrict__ n2s,
                            const int* __restrict__ comps, const int* cnt) {
    int Mb = cnt[0], Ms = cnt[1];
    int totB = Mb + 1;
    int tot = totB + Ms + 1;
    int stride = gridDim.x * blockDim.x;
    for (int r = blockIdx.x * blockDim.x + threadIdx.x; r < tot; r += stride) {
        if (r < totB) {
            if (r == 0) { out[0] = 0.f; continue; }
            int m = r - 1;
            out[r] = in[r]
                + 0.5f * (in[n1b[m] + 1] + in[n2b[m] + 1]
                        + in[n1b[RB + m] + 1] + in[n2b[RB + m] + 1])
                + 0.25f * (in[compb[m] + 1] + in[compb[RB + m] + 1]
                         + in[compb[2 * RB + m] + 1] + in[compb[3 * RB + m] + 1]);
        } else {
            int t = r - totB;
            int o = RB + 1 + t;
            if (t == 0) { out[o] = 0.f; continue; }
            int m = t - 1;
            out[o] = in[o]
                + 0.5f * (in[RB + 2 + n1s[m]] + in[RB + 2 + n2s[m]]
                        + in[RB + 2 + n1s[RS + m]] + in[RB + 2 + n2s[RS + m]])
                + 0.25f * (in[RB + 2 + comps[m]] + in[RB + 2 + comps[RS + m]]
                         + in[RB + 2 + comps[2 * RS + m]] + in[RB + 2 + comps[3 * RS + m]]);
        }
    }
}

__global__ void fused1_b(const float* __restrict__ in, float* __restrict__ out,
                         const int* __restrict__ n1b, const int* __restrict__ n2b,
                         const int* __restrict__ compb, const int* cnt) {
    int M = cnt[0];
    int stride = gridDim.x * blockDim.x;
    for (int r = blockIdx.x * blockDim.x + threadIdx.x; r <= M; r += stride) {
        if (r == 0) { out[0] = 0.f; continue; }
        int m = r - 1;
        out[r] = in[r]
            + 0.5f * (in[n1b[3 * RB + m] + 1] + in[n2b[3 * RB + m] + 1]
                    + in[n1b[4 * RB + m] + 1] + in[n2b[4 * RB + m] + 1])
            + 0.25f * (in[compb[4 * RB + m] + 1] + in[compb[5 * RB + m] + 1]
                     + in[compb[6 * RB + m] + 1] + in[compb[7 * RB + m] + 1]);
    }
}

// both norms in one pass (bilateral final in bufB, spatial final in bufS)
__global__ void slice_norm_both(const float* __restrict__ bufB, const float* __restrict__ bufS,
                                const int* __restrict__ osw, const float* __restrict__ wsv,
                                float* __restrict__ nbv, float* __restrict__ nsv,
                                float alphaB, float alphaS) {
    int i = blockIdx.x * blockDim.x + threadIdx.x;
    if (i >= NPIX) return;
    float sb = 0.f;
    #pragma unroll
    for (int r = 0; r < DB1; r++)
        sb += wsv[i * DB1 + r] * bufB[osw[i * DB1 + r] + 1];
    float ss = 0.f;
    #pragma unroll
    for (int r = 0; r < DS1; r++)
        ss += wsv[RB + i * DS1 + r] * bufS[RB + 2 + osw[RB + i * DS1 + r]];
    nbv[i] = alphaB * sb + 1e-20f;
    nsv[i] = alphaS * ss + 1e-20f;
}

// fused: slice(bilateral)+slice(spatial)+normalize+softmax -> Q (fp32) + Qh (fp16)
// bijective block remap so contiguous pixel ranges stay on one XCD.
// write_q: Q fp32 store only observable on the final iteration.
__global__ void slice_update(const float* __restrict__ U,
                             const uint4* __restrict__ bufB4, const uint4* __restrict__ bufS4,
                             const int* __restrict__ osw, const float* __restrict__ wsv,
                             const float* __restrict__ nbv, const float* __restrict__ nsv,
                             float* __restrict__ Q, uint4* __restrict__ Qh4,
                             float alphaB, float alphaS, int use_msg, int write_q) {
    int swb = swz8(blockIdx.x, (int)gridDim.x);
    int i = swb * blockDim.x + threadIdx.x;
    if (i >= NPIX) return;
    float msg[24];
    #pragma unroll
    for (int t = 0; t < 24; t++) msg[t] = 0.f;
    if (use_msg) {
        float ib = 10.0f * alphaB / nbv[i];
        float is = 3.0f * alphaS / nsv[i];
        #pragma unroll
        for (int r = 0; r < DB1; r++) {
            float w = ib * wsv[i * DB1 + r];
            size_t base = (size_t)(osw[i * DB1 + r] + 1) * 3;
            uint4 q0 = bufB4[base], q1 = bufB4[base + 1], q2 = bufB4[base + 2];
            acc8(msg + 0,  w, q0);
            acc8(msg + 8,  w, q1);
            acc8(msg + 16, w, q2);
        }
        #pragma unroll
        for (int r = 0; r < DS1; r++) {
            float w = is * wsv[RB + i * DS1 + r];
            size_t base = (size_t)(RB + 2 + osw[RB + i * DS1 + r]) * 3;
            uint4 q0 = bufS4[base], q1 = bufS4[base + 1], q2 = bufS4[base + 2];
            acc8(msg + 0,  w, q0);
            acc8(msg + 8,  w, q1);
            acc8(msg + 16, w, q2);
        }
    }
    float mx = -1e30f;
    #pragma unroll
    for (int c = 0; c < NC; c++) {
        msg[c] = -U[i * NC + c] + msg[c];
        mx = fmaxf(mx, msg[c]);
    }
    float s = 0.f;
    #pragma unroll
    for (int c = 0; c < NC; c++) { float e = expf(msg[c] - mx); msg[c] = e; s += e; }
    float inv = 1.0f / s;
    #pragma unroll
    for (int c = 0; c < NC; c++) msg[c] *= inv;
    if (write_q) {
        #pragma unroll
        for (int c = 0; c < NC; c++) Q[i * NC + c] = msg[c];
    }
    msg[21] = 0.f; msg[22] = 0.f; msg[23] = 0.f;
    #pragma unroll
    for (int t = 0; t < 3; t++)
        Qh4[i * 3 + t] = pack8(msg + 8 * t);
}

// ---------------- host orchestration ----------------
extern "C" void kernel_launch(void* const* d_in, const int* in_sizes, int n_in,
                              void* d_out, int out_size, void* d_ws, size_t ws_size,
                              hipStream_t stream) {
    const float* U     = (const float*)d_in[0];
    const float* image = (const float*)d_in[1];
    float* Q = (float*)d_out;

    char* base = (char*)d_ws;
    size_t off = 0;
    auto alloc = [&](size_t bytes) -> void* {
        off = (off + 255) & ~(size_t)255;
        void* p = base + off; off += bytes; return p;
    };
    // unified per-entry arrays: [0,RB) bilateral, [RB,RB+RS) spatial
    int*   osw  = (int*)  alloc((size_t)(RB + RS) * 4);
    float* wsv  = (float*)alloc((size_t)(RB + RS) * 4);
    int*   rnk  = (int*)  alloc((size_t)(RB + RS) * 4);
    int*   n1_b = (int*)  alloc((size_t)DB1 * RB * 4);
    int*   n2_b = (int*)  alloc((size_t)DB1 * RB * 4);
    int*   n1_s = (int*)  alloc((size_t)DS1 * RS * 4);
    int*   n2_s = (int*)  alloc((size_t)DS1 * RS * 4);
    int*   comp_b = (int*)alloc((size_t)8 * RB * 4);   // fused pairs (0,1),(3,4)
    int*   comp_s = (int*)alloc((size_t)4 * RS * 4);   // fused pair (0,1)
    unsigned long long* uk_b = (unsigned long long*)alloc((size_t)RB * 8);
    ulonglong2* hkid = (ulonglong2*)alloc((size_t)TBS * 16);
    int*   gid2id = (int*)alloc((size_t)GN * 4);
    int*   cnt  = (int*)  alloc(256);   // [0]=M_b, [1]=M_s
    int*   histOff = (int*)alloc((size_t)NBUCK * 4);
    int*   wsums   = (int*)alloc((size_t)64 * 1024 * 4);
    int*   wsI     = (int*)alloc((size_t)16384 * 4);   // level-1 inclusive sums
    int*   ws2     = (int*)alloc((size_t)1024 * 4);    // level-2 sums
    int*   offv    = (int*)alloc((size_t)(RB + RS) * 4);
    // contiguous zero region: cntr | hist | histFill | pres
    char*  zreg  = (char*)alloc((size_t)(RB + RS) * 4 + (size_t)NBUCK * 8 + (size_t)GN * 4);
    int*   cntr     = (int*)zreg;
    int*   hist     = cntr + (RB + RS);
    int*   histFill = hist + NBUCK;
    int*   pres     = histFill + NBUCK;
    size_t zbytes = (size_t)(RB + RS) * 4 + (size_t)NBUCK * 8 + (size_t)GN * 4;
    unsigned* epw = (unsigned*)alloc((size_t)(RB + RS) * 4);   // packed 4B entries
    float* norm_b = (float*)alloc((size_t)NPIX * 4);
    float* norm_s = (float*)alloc((size_t)NPIX * 4);
    uint2* Qh   = (uint2*)alloc((size_t)NPIX * CP4 * 8);
    // combined lattice buffers: rows RB+RS+2 (bilateral [0,RB], spatial [RB+1,...])
    uint2* buf0 = (uint2*)alloc((size_t)(RB + RS + 2) * CP4 * 8);
    uint2* buf1 = (uint2*)alloc((size_t)(RB + RS + 2) * CP4 * 8);
    float* nbuf0 = (float*)alloc((size_t)(RB + RS + 2) * 4);
    float* nbuf1 = (float*)alloc((size_t)(RB + RS + 2) * 4);
    if (off > ws_size) return;

    const float ALPHA_B = (float)(1.0 / (1.0 + exp2(-(double)DB)));  // 32/33
    const float ALPHA_S = (float)(1.0 / (1.0 + exp2(-(double)DS)));  // 4/5

    constexpr int PGR = 2048;   // gather/blur grids (grid-stride, %8==0)

    // ---- 3 memsets ----
    hipMemsetAsync(cnt, 0, 16, stream);
    hipMemsetAsync(hkid, 0xFF, (size_t)TBS * 16, stream);
    hipMemsetAsync(zreg, 0, zbytes, stream);

    // ---- build both lattices ----
    build_both<<<(RB + RS) / 256, 256, 0, stream>>>(image, hkid, osw, wsv, pres);
    // bilateral compaction (bucket-sorted ids)
    hist_b<<<TBS / 256, 256, 0, stream>>>(hkid, hist);
    scan_wave_partial<<<NBUCK / 256, 256, 0, stream>>>(hist, histOff, wsums, NBUCK);
    scan_partials_excl<<<1, 256, 0, stream>>>(wsums, NBUCK / 64, cnt + 0);
    scan_finalize<<<NBUCK / 256, 256, 0, stream>>>(histOff, hist, wsums, NBUCK);
    assign_b<<<TBS / 256, 256, 0, stream>>>(hkid, histOff, histFill, uk_b);
    // spatial compaction (dense grid presence scan; ids row-major in (c0,c1))
    scan_wave_partial<<<GN / 256, 256, 0, stream>>>(pres, gid2id, wsums, GN);
    scan_partials_excl<<<1, 256, 0, stream>>>(wsums, GN / 64, cnt + 1);
    scan_finalize<<<GN / 256, 256, 0, stream>>>(gid2id, pres, wsums, GN);
    spatial_neighbors<<<GN / 256, 256, 0, stream>>>(pres, gid2id, n1_s, n2_s);
    compose_s<<<256, 256, 0, stream>>>(n1_s, n2_s, cnt, comp_s);
    os_count_both<<<(RB + RS) / 256, 256, 0, stream>>>(osw, hkid, gid2id, cntr, rnk);
    build_neighbors_b<<<2048, 256, 0, stream>>>(uk_b, hkid, cnt + 0, n1_b, n2_b);
    compose_b<<<1024, 256, 0, stream>>>(n1_b, n2_b, cnt, comp_b);
    // unified offset scan over RB+RS id slots — hierarchical
    scan_wave_partial<<<(RB + RS) / 256, 256, 0, stream>>>(cntr, offv, wsums, RB + RS);
    scan_wave_partial<<<(NW1 + 255) / 256, 256, 0, stream>>>(wsums, wsI, ws2, NW1);
    scan_partials_excl<<<1, 256, 0, stream>>>(ws2, (NW1 + 63) / 64, nullptr);
    scan_finalize<<<(NW1 + 255) / 256, 256, 0, stream>>>(wsI, wsums, ws2, NW1);
    scan_finalize<<<(RB + RS) / 256, 256, 0, stream>>>(offv, cntr, wsI, RB + RS);
    fill_both<<<(RB + RS + 255) / 256, 256, 0, stream>>>(osw, wsv, offv, rnk, epw);

    // ---- norm filters (C=1, fp32), fused-pair chain ----
    {
        gather1_both<<<1024, 256, 0, stream>>>(offv, cntr, epw, nbuf0, cnt);
        // pair (0,1) both chains
        fused1_both<<<1024, 256, 0, stream>>>(nbuf0, nbuf1, n1_b, n2_b, comp_b,
                                              n1_s, n2_s, comp_s, cnt);
        // j=2 both chains (spatial final lands in nbuf0)
        blur1_both<<<1024, 256, 0, stream>>>(nbuf1, nbuf0,
            n1_b + (size_t)2 * RB, n2_b + (size_t)2 * RB,
            n1_s + (size_t)2 * RS, n2_s + (size_t)2 * RS, cnt);
        // pair (3,4) bilateral
        fused1_b<<<1024, 256, 0, stream>>>(nbuf0, nbuf1, n1_b, n2_b, comp_b, cnt);
        // j=5 bilateral (bilateral final lands in nbuf0; spatial rows untouched)
        blur1_b<<<1024, 256, 0, stream>>>(nbuf1, nbuf0,
            n1_b + (size_t)5 * RB, n2_b + (size_t)5 * RB, cnt);
        slice_norm_both<<<(NPIX + 255) / 256, 256, 0, stream>>>(
            nbuf0, nbuf0, osw, wsv, norm_b, norm_s, ALPHA_B, ALPHA_S);
    }

    // ---- Q0 = softmax(-U) (Q write dead — overwritten by final iteration) ----
    slice_update<<<(NPIX + 255) / 256, 256, 0, stream>>>(
        U, (const uint4*)buf0, (const uint4*)buf1, osw, wsv, norm_b, norm_s,
        Q, (uint4*)Qh, ALPHA_B, ALPHA_S, 0, 0);

    // ---- 5 mean-field iterations (fused-pair blur chain) ----
    for (int it = 0; it < 5; it++) {
        gather_both_h<<<PGR, 256, 0, stream>>>((const uint4*)Qh, offv, cntr, epw,
                                               (uint4*)buf0, cnt);
        // pair (0,1) both chains: buf0 -> buf1
        fused_blur_both_h<<<PGR, 256, 0, stream>>>((const uint4*)buf0, (uint4*)buf1,
            n1_b, n2_b, comp_b, n1_s, n2_s, comp_s, cnt);
        // j=2 both chains: buf1 -> buf0 (spatial final lands in buf0)
        blur_both_h<<<PGR, 256, 0, stream>>>((const uint4*)buf1, (uint4*)buf0,
            n1_b + (size_t)2 * RB, n2_b + (size_t)2 * RB,
            n1_s + (size_t)2 * RS, n2_s + (size_t)2 * RS, cnt);
        // pair (3,4) bilateral: buf0 -> buf1 (bilateral rows only)
        fused_blur_b_h<<<PGR, 256, 0, stream>>>((const uint4*)buf0, (uint4*)buf1,
            n1_b, n2_b, comp_b, cnt);
        // j=5 bilateral: buf1 -> buf0 (spatial rows in buf0 keep the j=2 final)
        blur_b_h<<<PGR, 256, 0, stream>>>((const uint4*)buf1, (uint4*)buf0,
            n1_b + (size_t)5 * RB, n2_b + (size_t)5 * RB, cnt);
        // both finals in buf0; Q written only on the last iteration
        slice_update<<<(NPIX + 255) / 256, 256, 0, stream>>>(
            U, (const uint4*)buf0, (const uint4*)buf0, osw, wsv, norm_b, norm_s,
            Q, (uint4*)Qh, ALPHA_B, ALPHA_S, 1, (it == 4) ? 1 : 0);
    }
}

// Round 9
// 717.380 us; speedup vs baseline: 1.2643x; 1.0259x over previous
//
#include <hip/hip_runtime.h>
#include <hip/hip_fp16.h>
#include <cmath>

// ---------------- problem constants ----------------
constexpr int IMH = 320, IMW = 320, NPIX = IMH * IMW, NC = 21;
constexpr int CP4 = 6;           // padded channels / 4  (24 values per row)
constexpr int DB = 5, DB1 = 6;   // bilateral lattice dim
constexpr int DS = 2, DS1 = 3;   // spatial lattice dim
constexpr int RB = NPIX * DB1;   // splat entries (bilateral) = 614400
constexpr int RS = NPIX * DS1;   // (spatial) = 307200
constexpr int TBS = 1 << 19;     // hash table slots (bilateral only)
constexpr int NBUCK = 1 << 16;   // bilateral sort buckets (c0,c1 low bytes)
constexpr int NW1 = (RB + RS) / 64;  // wave sums in the unified offset scan
// spatial dense grid: lattice coords are deterministic in (x,y) only.
// c0 in [-8, 298], c1 in [-194, 115]  ->  512x512 grid with offsets below.
constexpr int GS = 512, GN = GS * GS;
constexpr int C0OFF = 16, C1OFF = 200;

// Combined lattice-value buffer layout (static partition):
//   bilateral: row 0 = sink, point m -> row m+1           (rows [0, RB])
//   spatial:   row RB+1 = sink, point m -> row RB+2+m     (rows [RB+1, ...])
// spatial neighbor n=-1 maps to RB+2+(-1) = RB+1 = sink automatically.

// LESSONS (measured):
// r12-r14: hist fused into CAS loop = +45us; test-before-CAS = +8us/+36MB
//   FETCH; 4B epw packing does NOT cut scatter WRITE (64B sectors rule).
// r15: fill's atomicAdd removed via ranks captured in os_count.
// r16: ATOMIC-THROUGHPUT-BOUND build: ~16-19G atomics/s ceiling (64B RMW
//   sectors). Only fewer atomics help.
// r17: spatial lattice -> dense 512x512 grid (no atomics).
// r18: blur row-per-thread REGRESSED: <200K threads latency-starved.
//   TLP rule: >=400K threads for scattered kernels.
// r19: merged 16B {key,id} table, 6x parallel neighbor build: ->861us.
// r20: gather 3-chunk split REGRESSED: SECTOR RULE beats TLP rule — a
//   thread must consume WHOLE 48B rows. Fused 9-pt blur: null in
//   L2-MISS regime (no swizzle, buf >> L2).
// r21: paired-lane gather (entry-parity split, full-row reads, shfl_xor
//   combine): ->827us.
// r22: XCD chunked swizzle on gather/blur/slice: ->758us. Working set
//   8.6MB -> per-XCD ~1.1MB contiguous windows fit 4MB L2.
// r23: pair-fusion RETRY under L2-hit regime: ->736us (+write_q skip).
//   Fusion is regime-dependent: null at L2-miss, real win at L2-hit.
// r24 (this round): complete the pairing — bilateral (0,1),(2,3),(4,5)
//   all fused (3 passes, was 4); spatial single j2 rides inside the
//   bilateral fused(2,3) dispatch. 6->5 dispatches/iter; norm 5->4.

#define EMPTY_KEY 0xFFFFFFFFFFFFFFFFULL

__device__ __forceinline__ unsigned long long mix64(unsigned long long x) {
    x ^= x >> 33; x *= 0xff51afd7ed558ccdULL;
    x ^= x >> 33; x *= 0xc4ceb9fe1a85ec53ULL;
    x ^= x >> 33; return x;
}

// fp16 pack helpers: uint2 = 4 halves; math in fp32, storage fp16.
__device__ __forceinline__ float4 u2f(uint2 u) {
    __half2 a = *reinterpret_cast<__half2*>(&u.x);
    __half2 b = *reinterpret_cast<__half2*>(&u.y);
    float2 fa = __half22float2(a), fb = __half22float2(b);
    return make_float4(fa.x, fa.y, fb.x, fb.y);
}
__device__ __forceinline__ uint2 f2u(float4 v) {
    __half2 a = __floats2half2_rn(v.x, v.y);
    __half2 b = __floats2half2_rn(v.z, v.w);
    uint2 u;
    u.x = *reinterpret_cast<unsigned*>(&a);
    u.y = *reinterpret_cast<unsigned*>(&b);
    return u;
}

__device__ __forceinline__ unsigned pack_ew(int pix, float w) {
    int w15 = (int)lrintf(fminf(fmaxf(w, 0.f), 1.f) * 32767.f);
    return ((unsigned)w15 << 17) | (unsigned)pix;
}
__device__ __forceinline__ void unpack_ew(unsigned e, int& pix, float& w) {
    pix = (int)(e & 0x1FFFFu);
    w = (float)(e >> 17) * (1.0f / 32767.0f);
}

// accumulate 8 fp16 channels (one uint4) into acc[0..7] with weight w.
__device__ __forceinline__ void acc8(float* acc, float w, uint4 q) {
    float4 v = u2f(make_uint2(q.x, q.y));
    acc[0] += w * v.x; acc[1] += w * v.y; acc[2] += w * v.z; acc[3] += w * v.w;
    v = u2f(make_uint2(q.z, q.w));
    acc[4] += w * v.x; acc[5] += w * v.y; acc[6] += w * v.z; acc[7] += w * v.w;
}

// blur core on one uint4 (8 fp16 channels): x + 0.5*(a+b), f32 math.
__device__ __forceinline__ uint4 blur8(uint4 xs, uint4 xa, uint4 xb) {
    float4 s0 = u2f(make_uint2(xs.x, xs.y)), s1 = u2f(make_uint2(xs.z, xs.w));
    float4 a0 = u2f(make_uint2(xa.x, xa.y)), a1 = u2f(make_uint2(xa.z, xa.w));
    float4 b0 = u2f(make_uint2(xb.x, xb.y)), b1 = u2f(make_uint2(xb.z, xb.w));
    s0.x += 0.5f * (a0.x + b0.x); s0.y += 0.5f * (a0.y + b0.y);
    s0.z += 0.5f * (a0.z + b0.z); s0.w += 0.5f * (a0.w + b0.w);
    s1.x += 0.5f * (a1.x + b1.x); s1.y += 0.5f * (a1.y + b1.y);
    s1.z += 0.5f * (a1.z + b1.z); s1.w += 0.5f * (a1.w + b1.w);
    uint2 lo = f2u(s0), hi = f2u(s1);
    return make_uint4(lo.x, lo.y, hi.x, hi.y);
}

__device__ __forceinline__ uint4 pack8(const float* acc) {
    uint2 lo = f2u(make_float4(acc[0], acc[1], acc[2], acc[3]));
    uint2 hi = f2u(make_float4(acc[4], acc[5], acc[6], acc[7]));
    return make_uint4(lo.x, lo.y, hi.x, hi.y);
}

// chunked XCD swizzle: block bid -> swb so blocks on one XCD are contiguous.
// requires gridDim.x % 8 == 0 (bijective).
__device__ __forceinline__ int swz8(int bid, int nb) {
    return (bid & 7) * (nb >> 3) + (bid >> 3);
}

// ---------------- permutohedral embedding (matches reference op-for-op, f32) ----------------
template<int D>
__device__ void perm_embed(const float* f, float* bary, unsigned long long* pk) {
    constexpr int D1 = D + 1;
    float cf[D];
    #pragma unroll
    for (int i = 0; i < D; i++) {
        double s = sqrt(2.0 / 3.0) * (double)D1 / sqrt((double)((i + 1) * (i + 2)));
        cf[i] = f[i] * (float)s;
    }
    float csum[D];
    float acc = 0.f;
    #pragma unroll
    for (int i = D - 1; i >= 0; i--) { acc += cf[i]; csum[i] = acc; }
    float el[D1];
    el[0] = csum[0];
    #pragma unroll
    for (int i = 1; i < D; i++) el[i] = csum[i] - (float)i * cf[i - 1];
    el[D] = -(float)D * cf[D - 1];
    const float down = 1.0f / (float)D1;
    float rem0[D1]; int rank[D1]; int ssum = 0;
    #pragma unroll
    for (int i = 0; i < D1; i++) {
        float rd = rintf(el[i] * down);
        rem0[i] = rd * (float)D1;
        ssum += (int)rd;
    }
    float diff[D1];
    #pragma unroll
    for (int i = 0; i < D1; i++) diff[i] = el[i] - rem0[i];
    #pragma unroll
    for (int i = 0; i < D1; i++) {
        int r = 0;
        #pragma unroll
        for (int j = 0; j < D1; j++)
            r += (diff[j] > diff[i]) || ((diff[j] == diff[i]) && (j < i));
        rank[i] = r + ssum;
    }
    #pragma unroll
    for (int i = 0; i < D1; i++) {
        if (rank[i] < 0)      { rank[i] += D1; rem0[i] += (float)D1; }
        else if (rank[i] > D) { rank[i] -= D1; rem0[i] -= (float)D1; }
    }
    float b[D + 2];
    #pragma unroll
    for (int i = 0; i < D + 2; i++) b[i] = 0.f;
    #pragma unroll
    for (int i = 0; i < D1; i++) b[D - rank[i]]     += (el[i] - rem0[i]) * down;
    #pragma unroll
    for (int i = 0; i < D1; i++) b[D + 1 - rank[i]] -= (el[i] - rem0[i]) * down;
    b[0] += 1.0f + b[D + 1];
    #pragma unroll
    for (int i = 0; i < D1; i++) bary[i] = b[i];
    int key0[D];
    #pragma unroll
    for (int i = 0; i < D; i++) key0[i] = (int)rintf(rem0[i]);
    #pragma unroll
    for (int r = 0; r < D1; r++) {
        unsigned long long p = 0;
        #pragma unroll
        for (int i = 0; i < D; i++) {
            int c = key0[i] + ((rank[i] < D1 - r) ? r : r - D1);
            p |= ((unsigned long long)((unsigned)(c + 2048) & 0xFFFu)) << (12 * i);
        }
        pk[r] = p;
    }
}

__device__ __forceinline__ int key_code(unsigned long long k) {
    int c0 = (int)(k & 0xFFFULL);
    int c1 = (int)((k >> 12) & 0xFFFULL);
    return ((c0 & 0xFF) << 8) | (c1 & 0xFF);
}

// ---------------- merged {key,id} hash table (16B entries) ----------------
__device__ __forceinline__ int hash_insert2(ulonglong2* hkid, int tmask, unsigned long long k) {
    int slot = (int)(mix64(k) & (unsigned long long)tmask);
    while (true) {
        unsigned long long prev = atomicCAS(&hkid[slot].x, EMPTY_KEY, k);
        if (prev == EMPTY_KEY || prev == k) return slot;
        slot = (slot + 1) & tmask;
    }
}
// one 16B load per probe: key match delivers id in the same transaction.
__device__ __forceinline__ int hash_lookup2(const ulonglong2* __restrict__ hkid,
                                            int tmask, unsigned long long k) {
    int slot = (int)(mix64(k) & (unsigned long long)tmask);
    while (true) {
        ulonglong2 e = hkid[slot];
        if (e.x == k) return (int)e.y;
        if (e.x == EMPTY_KEY) return -1;
        slot = (slot + 1) & tmask;
    }
}

// ---------------- build kernels ----------------
__global__ void build_both(const float* __restrict__ image, ulonglong2* hkid,
                           int* os, float* wsv, int* pres) {
    int idx = blockIdx.x * blockDim.x + threadIdx.x;
    if (idx < RB) {
        int i = idx / DB1;          // pixel
        int r = idx - i * DB1;      // simplex vertex rank
        int x = i % IMW, y = i / IMW;
        float f[DB];
        f[0] = (float)x / 80.0f;
        f[1] = (float)y / 80.0f;
        f[2] = image[i * 3 + 0] / 13.0f;
        f[3] = image[i * 3 + 1] / 13.0f;
        f[4] = image[i * 3 + 2] / 13.0f;
        float bary[DB1]; unsigned long long pk[DB1];
        perm_embed<DB>(f, bary, pk);
        float w = 0.f; unsigned long long k = 0;
        #pragma unroll
        for (int r2 = 0; r2 < DB1; r2++)
            if (r2 == r) { w = bary[r2]; k = pk[r2]; }   // static idx -> regs
        wsv[idx] = w;
        os[idx] = hash_insert2(hkid, TBS - 1, k);
    } else if (idx < RB + RS) {
        int t = idx - RB;
        int ip = t / DS1;
        int r = t - ip * DS1;
        int x = ip % IMW, y = ip / IMW;
        float f[DS];
        f[0] = (float)x / 3.0f;
        f[1] = (float)y / 3.0f;
        float bary[DS1]; unsigned long long pk[DS1];
        perm_embed<DS>(f, bary, pk);
        float w = 0.f; unsigned long long k = 0;
        #pragma unroll
        for (int r2 = 0; r2 < DS1; r2++)
            if (r2 == r) { w = bary[r2]; k = pk[r2]; }
        int c0 = (int)(k & 0xFFFULL) - 2048;
        int c1 = (int)((k >> 12) & 0xFFFULL) - 2048;
        int gid = (c0 + C0OFF) * GS + (c1 + C1OFF);
        wsv[idx] = w;
        os[idx] = gid;
        pres[gid] = 1;              // benign same-value race, no atomic
    }
}

// hist over bilateral table only
__global__ void hist_b(const ulonglong2* __restrict__ hkid, int* hist) {
    int s = blockIdx.x * blockDim.x + threadIdx.x;
    if (s >= TBS) return;
    unsigned long long k = hkid[s].x;
    if (k == EMPTY_KEY) return;
    atomicAdd(&hist[key_code(k)], 1);
}

// ---------------- barrier-free scan machinery ----------------
__global__ void scan_wave_partial(const int* __restrict__ count, int* incl, int* wsum, int n) {
    int idx = blockIdx.x * blockDim.x + threadIdx.x;
    int lane = threadIdx.x & 63;
    int v = (idx < n) ? count[idx] : 0;
    int s = v;
    #pragma unroll
    for (int d = 1; d < 64; d <<= 1) {
        int t = __shfl_up(s, d);
        if (lane >= d) s += t;
    }
    if (idx < n) incl[idx] = s;
    if (lane == 63) wsum[idx >> 6] = s;
}

__global__ void scan_partials_excl(int* w, int nw, int* total_out) {
    __shared__ int sh[256];
    __shared__ int run;
    if (threadIdx.x == 0) run = 0;
    __syncthreads();
    for (int basei = 0; basei < nw; basei += 256) {
        int idx = basei + threadIdx.x;
        int v = (idx < nw) ? w[idx] : 0;
        sh[threadIdx.x] = v;
        __syncthreads();
        for (int d = 1; d < 256; d <<= 1) {
            int t = (threadIdx.x >= d) ? sh[threadIdx.x - d] : 0;
            __syncthreads();
            sh[threadIdx.x] += t;
            __syncthreads();
        }
        int total = sh[255];
        if (idx < nw) w[idx] = run + sh[threadIdx.x] - v;
        __syncthreads();
        if (threadIdx.x == 0) run += total;
        __syncthreads();
    }
    if (total_out != nullptr && threadIdx.x == 0) *total_out = run;
}

__global__ void scan_finalize(int* off, const int* __restrict__ count,
                              const int* __restrict__ wsum, int n) {
    int idx = blockIdx.x * blockDim.x + threadIdx.x;
    if (idx < n) off[idx] = off[idx] - count[idx] + wsum[idx >> 6];
}

// ---------------- bucket-sorted compaction (bilateral) ----------------
__global__ void assign_b(ulonglong2* hkid, const int* __restrict__ histOff,
                         int* histFill, unsigned long long* uk_b) {
    int s = blockIdx.x * blockDim.x + threadIdx.x;
    if (s >= TBS) return;
    unsigned long long k = hkid[s].x;
    if (k == EMPTY_KEY) return;
    int code = key_code(k);
    int id = histOff[code] + atomicAdd(&histFill[code], 1);
    hkid[s].y = (unsigned long long)id;
    uk_b[id] = k;
}

// spatial neighbors via dense grid reads — no hashing, no atomics.
__global__ void spatial_neighbors(const int* __restrict__ pres, const int* __restrict__ gid2id,
                                  int* __restrict__ n1s, int* __restrict__ n2s) {
    int gid = blockIdx.x * blockDim.x + threadIdx.x;
    if (gid >= GN) return;
    if (!pres[gid]) return;
    int id = gid2id[gid];
    const int d1[3] = {  2 * GS - 1, -GS + 2, -GS - 1 };
    const int d2[3] = { -2 * GS + 1,  GS - 2,  GS + 1 };
    #pragma unroll
    for (int j = 0; j < 3; j++) {
        int g1 = gid + d1[j], g2 = gid + d2[j];
        n1s[j * RS + id] = pres[g1] ? gid2id[g1] : -1;
        n2s[j * RS + id] = pres[g2] ? gid2id[g2] : -1;
    }
}

// unified os remap + cntr histogram + per-entry rank capture (wave-agg atomics).
__global__ void os_count_both(int* os, const ulonglong2* __restrict__ hkid,
                              const int* __restrict__ gid2id, int* cntr, int* rnk) {
    int i = blockIdx.x * blockDim.x + threadIdx.x;
    int lane = threadIdx.x & 63;
    int idg;
    if (i < RB) {
        int id = (int)hkid[os[i]].y;
        os[i] = id;
        idg = id;
    } else {
        int id = gid2id[os[i]];
        os[i] = id;
        idg = RB + id;
    }
    // 64-lane equal-id mask
    unsigned long long m = 0;
    #pragma unroll
    for (int l = 0; l < 64; l++) {
        int o = __shfl(idg, l);
        m |= (unsigned long long)(o == idg) << l;
    }
    int rless  = __popcll(m & ((1ULL << lane) - 1ULL));
    int leader = __ffsll(m) - 1;
    int gcnt   = __popcll(m);
    int base = 0;
    if (lane == leader) base = atomicAdd(&cntr[idg], gcnt);
    base = __shfl(base, leader);
    rnk[i] = base + rless;
}

// bilateral neighbors, (j,m) parallel; XCD-chunk swizzle for L2 locality.
__global__ void build_neighbors_b(const unsigned long long* __restrict__ uk,
                                  const ulonglong2* __restrict__ hkid,
                                  const int* cnt, int* n1, int* n2) {
    int Mb = cnt[0];
    int tot = DB1 * Mb;
    int nb = gridDim.x;                    // multiple of 8
    int swb = swz8(blockIdx.x, nb);
    int stride = nb * blockDim.x;
    for (int t = swb * blockDim.x + threadIdx.x; t < tot; t += stride) {
        int j = t / Mb, m = t - j * Mb;
        unsigned long long k = uk[m];
        unsigned long long p1 = 0, p2 = 0;
        #pragma unroll
        for (int i = 0; i < DB; i++) {
            int c = (int)((k >> (12 * i)) & 0xFFFULL) - 2048;
            int a = c + ((i == j) ? DB : -1);
            int b = c + ((i == j) ? -DB : 1);
            p1 |= ((unsigned long long)((unsigned)(a + 2048) & 0xFFFu)) << (12 * i);
            p2 |= ((unsigned long long)((unsigned)(b + 2048) & 0xFFFu)) << (12 * i);
        }
        n1[j * RB + m] = hash_lookup2(hkid, TBS - 1, p1);
        n2[j * RB + m] = hash_lookup2(hkid, TBS - 1, p2);
    }
}

// composed neighbor indices for fused blur pairs (later-pass neighbor first).
// bilateral: pair(0,1)->comp[0..3], pair(2,3)->comp[4..7], pair(4,5)->comp[8..11].
// comp through missing neighbor (-1) stays -1 (sink value is 0).
__global__ void compose_b(const int* __restrict__ n1, const int* __restrict__ n2,
                          const int* cnt, int* __restrict__ comp) {
    int Mb = cnt[0];
    int stride = gridDim.x * blockDim.x;
    for (int m = blockIdx.x * blockDim.x + threadIdx.x; m < Mb; m += stride) {
        int a = n1[RB + m], b = n2[RB + m];                // j=1
        comp[0 * RB + m] = (a < 0) ? -1 : n1[a];           // j=0 of a
        comp[1 * RB + m] = (a < 0) ? -1 : n2[a];
        comp[2 * RB + m] = (b < 0) ? -1 : n1[b];
        comp[3 * RB + m] = (b < 0) ? -1 : n2[b];
        int a2 = n1[3 * RB + m], b2 = n2[3 * RB + m];      // j=3
        comp[4 * RB + m] = (a2 < 0) ? -1 : n1[2 * RB + a2];// j=2 of a2
        comp[5 * RB + m] = (a2 < 0) ? -1 : n2[2 * RB + a2];
        comp[6 * RB + m] = (b2 < 0) ? -1 : n1[2 * RB + b2];
        comp[7 * RB + m] = (b2 < 0) ? -1 : n2[2 * RB + b2];
        int a3 = n1[5 * RB + m], b3 = n2[5 * RB + m];      // j=5
        comp[8 * RB + m]  = (a3 < 0) ? -1 : n1[4 * RB + a3];// j=4 of a3
        comp[9 * RB + m]  = (a3 < 0) ? -1 : n2[4 * RB + a3];
        comp[10 * RB + m] = (b3 < 0) ? -1 : n1[4 * RB + b3];
        comp[11 * RB + m] = (b3 < 0) ? -1 : n2[4 * RB + b3];
    }
}
// spatial: pair(0,1) only -> comp[0..3]*RS.
__global__ void compose_s(const int* __restrict__ n1, const int* __restrict__ n2,
                          const int* cnt, int* __restrict__ comp) {
    int Ms = cnt[1];
    int stride = gridDim.x * blockDim.x;
    for (int m = blockIdx.x * blockDim.x + threadIdx.x; m < Ms; m += stride) {
        int a = n1[RS + m], b = n2[RS + m];
        comp[0 * RS + m] = (a < 0) ? -1 : n1[a];
        comp[1 * RS + m] = (a < 0) ? -1 : n2[a];
        comp[2 * RS + m] = (b < 0) ? -1 : n1[b];
        comp[3 * RS + m] = (b < 0) ? -1 : n2[b];
    }
}

// unified fill: pos derived from precomputed rank — NO atomics
__global__ void fill_both(const int* __restrict__ os, const float* __restrict__ wsv,
                          const int* __restrict__ off, const int* __restrict__ rnk,
                          unsigned* epw) {
    int idx = blockIdx.x * blockDim.x + threadIdx.x;
    if (idx >= RB + RS) return;
    int slot, pix;
    if (idx < RB) { slot = os[idx];        pix = idx / DB1; }
    else          { slot = RB + os[idx];   pix = (idx - RB) / DS1; }
    int pos = off[slot] + rnk[idx];
    epw[pos] = pack_ew(pix, wsv[idx]);
}

// ---------------- batched filter kernels (fp16 storage, fp32 math) ----------------
// paired-lane gather + XCD swizzle. Pairing: idx parity == lane parity.
__global__ void gather_both_h(const uint4* __restrict__ Qh4, const int* __restrict__ off,
                              const int* __restrict__ cntr, const unsigned* __restrict__ epw,
                              uint4* __restrict__ buf4, const int* cnt) {
    int Mb = cnt[0], Ms = cnt[1];
    int totB = Mb + 1;
    int totR = totB + Ms + 1;
    int tot2 = totR * 2;
    int nb = gridDim.x;
    int swb = swz8(blockIdx.x, nb);
    int stride = nb * blockDim.x;
    for (int idx = swb * blockDim.x + threadIdx.x; idx < tot2; idx += stride) {
        int r = idx >> 1, ph = idx & 1;   // pair (2r,2r+1) is always lane-adjacent
        int orow, slot;
        if (r < totB) { orow = r; slot = r - 1; }
        else { int t = r - totB; orow = RB + 1 + t; slot = t ? (RB + t - 1) : -1; }
        float acc[24];
        #pragma unroll
        for (int t = 0; t < 24; t++) acc[t] = 0.f;
        if (slot >= 0) {
            int s = off[slot], e = s + cntr[slot];
            for (int t = s + ph; t < e; t += 2) {
                int pix; float w;
                unpack_ew(epw[t], pix, w);
                const uint4* q = Qh4 + (size_t)pix * 3;
                uint4 q0 = q[0], q1 = q[1], q2 = q[2];
                acc8(acc + 0,  w, q0);
                acc8(acc + 8,  w, q1);
                acc8(acc + 16, w, q2);
            }
        }
        #pragma unroll
        for (int t = 0; t < 24; t++) acc[t] += __shfl_xor(acc[t], 1);
        if (ph == 0) {
            size_t b = (size_t)orow * 3;
            #pragma unroll
            for (int t = 0; t < 3; t++)
                buf4[b + t] = pack8(acc + 8 * t);
        }
    }
}

// fused pair blur (j=0 then j=1), both chains, XCD swizzle. 9-point stencil:
// out = x + 0.5(x@n1p + x@n2p + x@a + x@b) + 0.25(x@c1..c4), a=n1q, b=n2q.
__global__ void fused_blur_both_h(const uint4* __restrict__ in4, uint4* __restrict__ out4,
                                  const int* __restrict__ n1b, const int* __restrict__ n2b,
                                  const int* __restrict__ compb,
                                  const int* __restrict__ n1s, const int* __restrict__ n2s,
                                  const int* __restrict__ comps, const int* cnt) {
    int Mb = cnt[0], Ms = cnt[1];
    int totB = (Mb + 1) * 3;
    int tot = totB + (Ms + 1) * 3;
    int nb = gridDim.x;
    int swb = swz8(blockIdx.x, nb);
    int stride = nb * blockDim.x;
    for (int idx = swb * blockDim.x + threadIdx.x; idx < tot; idx += stride) {
        int r, c, self = 0, i1 = 0, i2 = 0, ia = 0, ib = 0, ic1 = 0, ic2 = 0, ic3 = 0, ic4 = 0;
        bool sink;
        if (idx < totB) {
            r = idx / 3; c = idx - r * 3;
            sink = (r == 0);
            self = r;
            int m = r - 1;
            if (!sink) {
                i1 = n1b[m] + 1;             i2 = n2b[m] + 1;
                ia = n1b[RB + m] + 1;        ib = n2b[RB + m] + 1;
                ic1 = compb[m] + 1;          ic2 = compb[RB + m] + 1;
                ic3 = compb[2 * RB + m] + 1; ic4 = compb[3 * RB + m] + 1;
            }
        } else {
            int t = idx - totB;
            r = t / 3; c = t - r * 3;
            sink = (r == 0);
            self = RB + 1 + r;
            int m = r - 1;
            if (!sink) {
                i1 = RB + 2 + n1s[m];             i2 = RB + 2 + n2s[m];
                ia = RB + 2 + n1s[RS + m];        ib = RB + 2 + n2s[RS + m];
                ic1 = RB + 2 + comps[m];          ic2 = RB + 2 + comps[RS + m];
                ic3 = RB + 2 + comps[2 * RS + m]; ic4 = RB + 2 + comps[3 * RS + m];
            }
        }
        size_t o = (size_t)self * 3 + c;
        if (sink) { out4[o] = make_uint4(0u, 0u, 0u, 0u); continue; }
        float acc[8];
        #pragma unroll
        for (int t2 = 0; t2 < 8; t2++) acc[t2] = 0.f;
        acc8(acc, 1.0f,  in4[o]);
        acc8(acc, 0.5f,  in4[(size_t)i1 * 3 + c]);
        acc8(acc, 0.5f,  in4[(size_t)i2 * 3 + c]);
        acc8(acc, 0.5f,  in4[(size_t)ia * 3 + c]);
        acc8(acc, 0.5f,  in4[(size_t)ib * 3 + c]);
        acc8(acc, 0.25f, in4[(size_t)ic1 * 3 + c]);
        acc8(acc, 0.25f, in4[(size_t)ic2 * 3 + c]);
        acc8(acc, 0.25f, in4[(size_t)ic3 * 3 + c]);
        acc8(acc, 0.25f, in4[(size_t)ic4 * 3 + c]);
        out4[o] = pack8(acc);
    }
}

// mixed pass: bilateral fused pair(2,3) + spatial single j=2, XCD swizzle.
// Spatial final lands here; bilateral continues to pair(4,5).
__global__ void fused_blur_b23_s2_h(const uint4* __restrict__ in4, uint4* __restrict__ out4,
                                    const int* __restrict__ n1b, const int* __restrict__ n2b,
                                    const int* __restrict__ compb,
                                    const int* __restrict__ n1s2, const int* __restrict__ n2s2,
                                    const int* cnt) {
    int Mb = cnt[0], Ms = cnt[1];
    int totB = (Mb + 1) * 3;
    int tot = totB + (Ms + 1) * 3;
    int nb = gridDim.x;
    int swb = swz8(blockIdx.x, nb);
    int stride = nb * blockDim.x;
    for (int idx = swb * blockDim.x + threadIdx.x; idx < tot; idx += stride) {
        if (idx < totB) {
            int r = idx / 3, c = idx - r * 3;
            size_t o = (size_t)r * 3 + c;
            if (r == 0) { out4[o] = make_uint4(0u, 0u, 0u, 0u); continue; }
            int m = r - 1;
            int i1 = n1b[2 * RB + m] + 1,  i2 = n2b[2 * RB + m] + 1;   // j=2
            int ia = n1b[3 * RB + m] + 1,  ib = n2b[3 * RB + m] + 1;   // j=3
            int ic1 = compb[4 * RB + m] + 1, ic2 = compb[5 * RB + m] + 1;
            int ic3 = compb[6 * RB + m] + 1, ic4 = compb[7 * RB + m] + 1;
            float acc[8];
            #pragma unroll
            for (int t2 = 0; t2 < 8; t2++) acc[t2] = 0.f;
            acc8(acc, 1.0f,  in4[o]);
            acc8(acc, 0.5f,  in4[(size_t)i1 * 3 + c]);
            acc8(acc, 0.5f,  in4[(size_t)i2 * 3 + c]);
            acc8(acc, 0.5f,  in4[(size_t)ia * 3 + c]);
            acc8(acc, 0.5f,  in4[(size_t)ib * 3 + c]);
            acc8(acc, 0.25f, in4[(size_t)ic1 * 3 + c]);
            acc8(acc, 0.25f, in4[(size_t)ic2 * 3 + c]);
            acc8(acc, 0.25f, in4[(size_t)ic3 * 3 + c]);
            acc8(acc, 0.25f, in4[(size_t)ic4 * 3 + c]);
            out4[o] = pack8(acc);
        } else {
            int t = idx - totB;
            int r = t / 3, c = t - r * 3;
            size_t o = (size_t)(RB + 1 + r) * 3 + c;
            if (r == 0) { out4[o] = make_uint4(0u, 0u, 0u, 0u); continue; }
            int m = r - 1;
            int a1 = RB + 2 + n1s2[m];   // -1 -> sink RB+1
            int a2 = RB + 2 + n2s2[m];
            out4[o] = blur8(in4[o], in4[(size_t)a1 * 3 + c], in4[(size_t)a2 * 3 + c]);
        }
    }
}

// fused pair blur, bilateral only, pointer-parameterized (used for pair(4,5)).
__global__ void fused_blur_b_h(const uint4* __restrict__ in4, uint4* __restrict__ out4,
                               const int* __restrict__ n1p, const int* __restrict__ n2p,
                               const int* __restrict__ n1q, const int* __restrict__ n2q,
                               const int* __restrict__ comp, const int* cnt) {
    int M = cnt[0];
    int tot = (M + 1) * 3;
    int nb = gridDim.x;
    int swb = swz8(blockIdx.x, nb);
    int stride = nb * blockDim.x;
    for (int idx = swb * blockDim.x + threadIdx.x; idx < tot; idx += stride) {
        int r = idx / 3, c = idx - r * 3;
        size_t o = (size_t)r * 3 + c;
        if (r == 0) { out4[o] = make_uint4(0u, 0u, 0u, 0u); continue; }
        int m = r - 1;
        int i1 = n1p[m] + 1,  i2 = n2p[m] + 1;
        int ia = n1q[m] + 1,  ib = n2q[m] + 1;
        int ic1 = comp[m] + 1, ic2 = comp[RB + m] + 1;
        int ic3 = comp[2 * RB + m] + 1, ic4 = comp[3 * RB + m] + 1;
        float acc[8];
        #pragma unroll
        for (int t2 = 0; t2 < 8; t2++) acc[t2] = 0.f;
        acc8(acc, 1.0f,  in4[o]);
        acc8(acc, 0.5f,  in4[(size_t)i1 * 3 + c]);
        acc8(acc, 0.5f,  in4[(size_t)i2 * 3 + c]);
        acc8(acc, 0.5f,  in4[(size_t)ia * 3 + c]);
        acc8(acc, 0.5f,  in4[(size_t)ib * 3 + c]);
        acc8(acc, 0.25f, in4[(size_t)ic1 * 3 + c]);
        acc8(acc, 0.25f, in4[(size_t)ic2 * 3 + c]);
        acc8(acc, 0.25f, in4[(size_t)ic3 * 3 + c]);
        acc8(acc, 0.25f, in4[(size_t)ic4 * 3 + c]);
        out4[o] = pack8(acc);
    }
}

// ---- fp32 norm-chain versions (per-row threads) ----
__global__ void gather1_both(const int* __restrict__ off, const int* __restrict__ cntr,
                             const unsigned* __restrict__ epw, float* __restrict__ buf,
                             const int* cnt) {
    int Mb = cnt[0], Ms = cnt[1];
    int totB = Mb + 1;
    int tot = totB + Ms + 1;
    int stride = gridDim.x * blockDim.x;
    for (int r = blockIdx.x * blockDim.x + threadIdx.x; r < tot; r += stride) {
        int o, slot;
        if (r < totB) { o = r;              slot = r ? (r - 1) : -1; }
        else          { int t = r - totB; o = RB + 1 + t; slot = t ? (RB + t - 1) : -1; }
        float acc = 0.f;
        if (slot >= 0) {
            int s = off[slot], e = s + cntr[slot];
            for (int t = s; t < e; t++) acc += (float)(epw[t] >> 17) * (1.0f / 32767.0f);
        }
        buf[o] = acc;
    }
}

__global__ void fused1_both(const float* __restrict__ in, float* __restrict__ out,
                            const int* __restrict__ n1b, const int* __restrict__ n2b,
                            const int* __restrict__ compb,
                            const int* __restrict__ n1s, const int* __restrict__ n2s,
                            const int* __restrict__ comps, const int* cnt) {
    int Mb = cnt[0], Ms = cnt[1];
    int totB = Mb + 1;
    int tot = totB + Ms + 1;
    int stride = gridDim.x * blockDim.x;
    for (int r = blockIdx.x * blockDim.x + threadIdx.x; r < tot; r += stride) {
        if (r < totB) {
            if (r == 0) { out[0] = 0.f; continue; }
            int m = r - 1;
            out[r] = in[r]
                + 0.5f * (in[n1b[m] + 1] + in[n2b[m] + 1]
                        + in[n1b[RB + m] + 1] + in[n2b[RB + m] + 1])
                + 0.25f * (in[compb[m] + 1] + in[compb[RB + m] + 1]
                         + in[compb[2 * RB + m] + 1] + in[compb[3 * RB + m] + 1]);
        } else {
            int t = r - totB;
            int o = RB + 1 + t;
            if (t == 0) { out[o] = 0.f; continue; }
            int m = t - 1;
            out[o] = in[o]
                + 0.5f * (in[RB + 2 + n1s[m]] + in[RB + 2 + n2s[m]]
                        + in[RB + 2 + n1s[RS + m]] + in[RB + 2 + n2s[RS + m]])
                + 0.25f * (in[RB + 2 + comps[m]] + in[RB + 2 + comps[RS + m]]
                         + in[RB + 2 + comps[2 * RS + m]] + in[RB + 2 + comps[3 * RS + m]]);
        }
    }
}

// mixed norm pass: bilateral fused pair(2,3) + spatial single j=2.
__global__ void fused1_b23_s2(const float* __restrict__ in, float* __restrict__ out,
                              const int* __restrict__ n1b, const int* __restrict__ n2b,
                              const int* __restrict__ compb,
                              const int* __restrict__ n1s2, const int* __restrict__ n2s2,
                              const int* cnt) {
    int Mb = cnt[0], Ms = cnt[1];
    int totB = Mb + 1;
    int tot = totB + Ms + 1;
    int stride = gridDim.x * blockDim.x;
    for (int r = blockIdx.x * blockDim.x + threadIdx.x; r < tot; r += stride) {
        if (r < totB) {
            if (r == 0) { out[0] = 0.f; continue; }
            int m = r - 1;
            out[r] = in[r]
                + 0.5f * (in[n1b[2 * RB + m] + 1] + in[n2b[2 * RB + m] + 1]
                        + in[n1b[3 * RB + m] + 1] + in[n2b[3 * RB + m] + 1])
                + 0.25f * (in[compb[4 * RB + m] + 1] + in[compb[5 * RB + m] + 1]
                         + in[compb[6 * RB + m] + 1] + in[compb[7 * RB + m] + 1]);
        } else {
            int t = r - totB;
            int o = RB + 1 + t;
            if (t == 0) { out[o] = 0.f; continue; }
            int m = t - 1;
            out[o] = in[o] + 0.5f * (in[RB + 2 + n1s2[m]] + in[RB + 2 + n2s2[m]]);
        }
    }
}

// fused norm pair, bilateral only, pointer-parameterized (pair(4,5)).
__global__ void fused1_b(const float* __restrict__ in, float* __restrict__ out,
                         const int* __restrict__ n1p, const int* __restrict__ n2p,
                         const int* __restrict__ n1q, const int* __restrict__ n2q,
                         const int* __restrict__ comp, const int* cnt) {
    int M = cnt[0];
    int stride = gridDim.x * blockDim.x;
    for (int r = blockIdx.x * blockDim.x + threadIdx.x; r <= M; r += stride) {
        if (r == 0) { out[0] = 0.f; continue; }
        int m = r - 1;
        out[r] = in[r]
            + 0.5f * (in[n1p[m] + 1] + in[n2p[m] + 1]
                    + in[n1q[m] + 1] + in[n2q[m] + 1])
            + 0.25f * (in[comp[m] + 1] + in[comp[RB + m] + 1]
                     + in[comp[2 * RB + m] + 1] + in[comp[3 * RB + m] + 1]);
    }
}

// both norms in one pass (bilateral final in bufB, spatial final in bufS)
__global__ void slice_norm_both(const float* __restrict__ bufB, const float* __restrict__ bufS,
                                const int* __restrict__ osw, const float* __restrict__ wsv,
                                float* __restrict__ nbv, float* __restrict__ nsv,
                                float alphaB, float alphaS) {
    int i = blockIdx.x * blockDim.x + threadIdx.x;
    if (i >= NPIX) return;
    float sb = 0.f;
    #pragma unroll
    for (int r = 0; r < DB1; r++)
        sb += wsv[i * DB1 + r] * bufB[osw[i * DB1 + r] + 1];
    float ss = 0.f;
    #pragma unroll
    for (int r = 0; r < DS1; r++)
        ss += wsv[RB + i * DS1 + r] * bufS[RB + 2 + osw[RB + i * DS1 + r]];
    nbv[i] = alphaB * sb + 1e-20f;
    nsv[i] = alphaS * ss + 1e-20f;
}

// fused: slice(bilateral)+slice(spatial)+normalize+softmax -> Q (fp32) + Qh (fp16)
// bijective block remap so contiguous pixel ranges stay on one XCD.
// write_q: Q fp32 store only observable on the final iteration.
__global__ void slice_update(const float* __restrict__ U,
                             const uint4* __restrict__ bufB4, const uint4* __restrict__ bufS4,
                             const int* __restrict__ osw, const float* __restrict__ wsv,
                             const float* __restrict__ nbv, const float* __restrict__ nsv,
                             float* __restrict__ Q, uint4* __restrict__ Qh4,
                             float alphaB, float alphaS, int use_msg, int write_q) {
    int swb = swz8(blockIdx.x, (int)gridDim.x);
    int i = swb * blockDim.x + threadIdx.x;
    if (i >= NPIX) return;
    float msg[24];
    #pragma unroll
    for (int t = 0; t < 24; t++) msg[t] = 0.f;
    if (use_msg) {
        float ib = 10.0f * alphaB / nbv[i];
        float is = 3.0f * alphaS / nsv[i];
        #pragma unroll
        for (int r = 0; r < DB1; r++) {
            float w = ib * wsv[i * DB1 + r];
            size_t base = (size_t)(osw[i * DB1 + r] + 1) * 3;
            uint4 q0 = bufB4[base], q1 = bufB4[base + 1], q2 = bufB4[base + 2];
            acc8(msg + 0,  w, q0);
            acc8(msg + 8,  w, q1);
            acc8(msg + 16, w, q2);
        }
        #pragma unroll
        for (int r = 0; r < DS1; r++) {
            float w = is * wsv[RB + i * DS1 + r];
            size_t base = (size_t)(RB + 2 + osw[RB + i * DS1 + r]) * 3;
            uint4 q0 = bufS4[base], q1 = bufS4[base + 1], q2 = bufS4[base + 2];
            acc8(msg + 0,  w, q0);
            acc8(msg + 8,  w, q1);
            acc8(msg + 16, w, q2);
        }
    }
    float mx = -1e30f;
    #pragma unroll
    for (int c = 0; c < NC; c++) {
        msg[c] = -U[i * NC + c] + msg[c];
        mx = fmaxf(mx, msg[c]);
    }
    float s = 0.f;
    #pragma unroll
    for (int c = 0; c < NC; c++) { float e = expf(msg[c] - mx); msg[c] = e; s += e; }
    float inv = 1.0f / s;
    #pragma unroll
    for (int c = 0; c < NC; c++) msg[c] *= inv;
    if (write_q) {
        #pragma unroll
        for (int c = 0; c < NC; c++) Q[i * NC + c] = msg[c];
    }
    msg[21] = 0.f; msg[22] = 0.f; msg[23] = 0.f;
    #pragma unroll
    for (int t = 0; t < 3; t++)
        Qh4[i * 3 + t] = pack8(msg + 8 * t);
}

// ---------------- host orchestration ----------------
extern "C" void kernel_launch(void* const* d_in, const int* in_sizes, int n_in,
                              void* d_out, int out_size, void* d_ws, size_t ws_size,
                              hipStream_t stream) {
    const float* U     = (const float*)d_in[0];
    const float* image = (const float*)d_in[1];
    float* Q = (float*)d_out;

    char* base = (char*)d_ws;
    size_t off = 0;
    auto alloc = [&](size_t bytes) -> void* {
        off = (off + 255) & ~(size_t)255;
        void* p = base + off; off += bytes; return p;
    };
    // unified per-entry arrays: [0,RB) bilateral, [RB,RB+RS) spatial
    int*   osw  = (int*)  alloc((size_t)(RB + RS) * 4);
    float* wsv  = (float*)alloc((size_t)(RB + RS) * 4);
    int*   rnk  = (int*)  alloc((size_t)(RB + RS) * 4);
    int*   n1_b = (int*)  alloc((size_t)DB1 * RB * 4);
    int*   n2_b = (int*)  alloc((size_t)DB1 * RB * 4);
    int*   n1_s = (int*)  alloc((size_t)DS1 * RS * 4);
    int*   n2_s = (int*)  alloc((size_t)DS1 * RS * 4);
    int*   comp_b = (int*)alloc((size_t)12 * RB * 4);  // fused pairs (0,1),(2,3),(4,5)
    int*   comp_s = (int*)alloc((size_t)4 * RS * 4);   // fused pair (0,1)
    unsigned long long* uk_b = (unsigned long long*)alloc((size_t)RB * 8);
    ulonglong2* hkid = (ulonglong2*)alloc((size_t)TBS * 16);
    int*   gid2id = (int*)alloc((size_t)GN * 4);
    int*   cnt  = (int*)  alloc(256);   // [0]=M_b, [1]=M_s
    int*   histOff = (int*)alloc((size_t)NBUCK * 4);
    int*   wsums   = (int*)alloc((size_t)64 * 1024 * 4);
    int*   wsI     = (int*)alloc((size_t)16384 * 4);   // level-1 inclusive sums
    int*   ws2     = (int*)alloc((size_t)1024 * 4);    // level-2 sums
    int*   offv    = (int*)alloc((size_t)(RB + RS) * 4);
    // contiguous zero region: cntr | hist | histFill | pres
    char*  zreg  = (char*)alloc((size_t)(RB + RS) * 4 + (size_t)NBUCK * 8 + (size_t)GN * 4);
    int*   cntr     = (int*)zreg;
    int*   hist     = cntr + (RB + RS);
    int*   histFill = hist + NBUCK;
    int*   pres     = histFill + NBUCK;
    size_t zbytes = (size_t)(RB + RS) * 4 + (size_t)NBUCK * 8 + (size_t)GN * 4;
    unsigned* epw = (unsigned*)alloc((size_t)(RB + RS) * 4);   // packed 4B entries
    float* norm_b = (float*)alloc((size_t)NPIX * 4);
    float* norm_s = (float*)alloc((size_t)NPIX * 4);
    uint2* Qh   = (uint2*)alloc((size_t)NPIX * CP4 * 8);
    // combined lattice buffers: rows RB+RS+2 (bilateral [0,RB], spatial [RB+1,...])
    uint2* buf0 = (uint2*)alloc((size_t)(RB + RS + 2) * CP4 * 8);
    uint2* buf1 = (uint2*)alloc((size_t)(RB + RS + 2) * CP4 * 8);
    float* nbuf0 = (float*)alloc((size_t)(RB + RS + 2) * 4);
    float* nbuf1 = (float*)alloc((size_t)(RB + RS + 2) * 4);
    if (off > ws_size) return;

    const float ALPHA_B = (float)(1.0 / (1.0 + exp2(-(double)DB)));  // 32/33
    const float ALPHA_S = (float)(1.0 / (1.0 + exp2(-(double)DS)));  // 4/5

    constexpr int PGR = 2048;   // gather/blur grids (grid-stride, %8==0)

    // ---- 3 memsets ----
    hipMemsetAsync(cnt, 0, 16, stream);
    hipMemsetAsync(hkid, 0xFF, (size_t)TBS * 16, stream);
    hipMemsetAsync(zreg, 0, zbytes, stream);

    // ---- build both lattices ----
    build_both<<<(RB + RS) / 256, 256, 0, stream>>>(image, hkid, osw, wsv, pres);
    // bilateral compaction (bucket-sorted ids)
    hist_b<<<TBS / 256, 256, 0, stream>>>(hkid, hist);
    scan_wave_partial<<<NBUCK / 256, 256, 0, stream>>>(hist, histOff, wsums, NBUCK);
    scan_partials_excl<<<1, 256, 0, stream>>>(wsums, NBUCK / 64, cnt + 0);
    scan_finalize<<<NBUCK / 256, 256, 0, stream>>>(histOff, hist, wsums, NBUCK);
    assign_b<<<TBS / 256, 256, 0, stream>>>(hkid, histOff, histFill, uk_b);
    // spatial compaction (dense grid presence scan; ids row-major in (c0,c1))
    scan_wave_partial<<<GN / 256, 256, 0, stream>>>(pres, gid2id, wsums, GN);
    scan_partials_excl<<<1, 256, 0, stream>>>(wsums, GN / 64, cnt + 1);
    scan_finalize<<<GN / 256, 256, 0, stream>>>(gid2id, pres, wsums, GN);
    spatial_neighbors<<<GN / 256, 256, 0, stream>>>(pres, gid2id, n1_s, n2_s);
    compose_s<<<256, 256, 0, stream>>>(n1_s, n2_s, cnt, comp_s);
    os_count_both<<<(RB + RS) / 256, 256, 0, stream>>>(osw, hkid, gid2id, cntr, rnk);
    build_neighbors_b<<<2048, 256, 0, stream>>>(uk_b, hkid, cnt + 0, n1_b, n2_b);
    compose_b<<<1024, 256, 0, stream>>>(n1_b, n2_b, cnt, comp_b);
    // unified offset scan over RB+RS id slots — hierarchical
    scan_wave_partial<<<(RB + RS) / 256, 256, 0, stream>>>(cntr, offv, wsums, RB + RS);
    scan_wave_partial<<<(NW1 + 255) / 256, 256, 0, stream>>>(wsums, wsI, ws2, NW1);
    scan_partials_excl<<<1, 256, 0, stream>>>(ws2, (NW1 + 63) / 64, nullptr);
    scan_finalize<<<(NW1 + 255) / 256, 256, 0, stream>>>(wsI, wsums, ws2, NW1);
    scan_finalize<<<(RB + RS) / 256, 256, 0, stream>>>(offv, cntr, wsI, RB + RS);
    fill_both<<<(RB + RS + 255) / 256, 256, 0, stream>>>(osw, wsv, offv, rnk, epw);

    // ---- norm filters (C=1, fp32): 4 fused passes ----
    {
        gather1_both<<<1024, 256, 0, stream>>>(offv, cntr, epw, nbuf0, cnt);
        // pair (0,1) both chains: nbuf0 -> nbuf1
        fused1_both<<<1024, 256, 0, stream>>>(nbuf0, nbuf1, n1_b, n2_b, comp_b,
                                              n1_s, n2_s, comp_s, cnt);
        // bilateral pair (2,3) + spatial j=2: nbuf1 -> nbuf0 (spatial final in nbuf0)
        fused1_b23_s2<<<1024, 256, 0, stream>>>(nbuf1, nbuf0, n1_b, n2_b, comp_b,
                                                n1_s + (size_t)2 * RS, n2_s + (size_t)2 * RS, cnt);
        // bilateral pair (4,5): nbuf0 -> nbuf1 (bilateral final in nbuf1)
        fused1_b<<<1024, 256, 0, stream>>>(nbuf0, nbuf1,
            n1_b + (size_t)4 * RB, n2_b + (size_t)4 * RB,
            n1_b + (size_t)5 * RB, n2_b + (size_t)5 * RB,
            comp_b + (size_t)8 * RB, cnt);
        slice_norm_both<<<(NPIX + 255) / 256, 256, 0, stream>>>(
            nbuf1, nbuf0, osw, wsv, norm_b, norm_s, ALPHA_B, ALPHA_S);
    }

    // ---- Q0 = softmax(-U) (Q write dead — overwritten by final iteration) ----
    slice_update<<<(NPIX + 255) / 256, 256, 0, stream>>>(
        U, (const uint4*)buf0, (const uint4*)buf1, osw, wsv, norm_b, norm_s,
        Q, (uint4*)Qh, ALPHA_B, ALPHA_S, 0, 0);

    // ---- 5 mean-field iterations (3 fused blur passes each) ----
    for (int it = 0; it < 5; it++) {
        gather_both_h<<<PGR, 256, 0, stream>>>((const uint4*)Qh, offv, cntr, epw,
                                               (uint4*)buf0, cnt);
        // pair (0,1) both chains: buf0 -> buf1
        fused_blur_both_h<<<PGR, 256, 0, stream>>>((const uint4*)buf0, (uint4*)buf1,
            n1_b, n2_b, comp_b, n1_s, n2_s, comp_s, cnt);
        // bilateral pair (2,3) + spatial j=2: buf1 -> buf0 (spatial final in buf0)
        fused_blur_b23_s2_h<<<PGR, 256, 0, stream>>>((const uint4*)buf1, (uint4*)buf0,
            n1_b, n2_b, comp_b,
            n1_s + (size_t)2 * RS, n2_s + (size_t)2 * RS, cnt);
        // bilateral pair (4,5): buf0 -> buf1 (bilateral final in buf1)
        fused_blur_b_h<<<PGR, 256, 0, stream>>>((const uint4*)buf0, (uint4*)buf1,
            n1_b + (size_t)4 * RB, n2_b + (size_t)4 * RB,
            n1_b + (size_t)5 * RB, n2_b + (size_t)5 * RB,
            comp_b + (size_t)8 * RB, cnt);
        // bilateral final in buf1, spatial final in buf0
        slice_update<<<(NPIX + 255) / 256, 256, 0, stream>>>(
            U, (const uint4*)buf1, (const uint4*)buf0, osw, wsv, norm_b, norm_s,
            Q, (uint4*)Qh, ALPHA_B, ALPHA_S, 1, (it == 4) ? 1 : 0);
    }
}